// Round 1
// baseline (302.979 us; speedup 1.0000x reference)
//
#include <hip/hip_runtime.h>
#include <math.h>

#define B_ 2
#define L_ 2048
#define D_ 256
#define P_ 32
#define NC_ 64
#define CL_ 32

#define INV_SQRT_P 0.17677669529663687f   // 1/sqrt(32)
#define PI_F 3.14159265358979323846f

__device__ __forceinline__ float gelu_exact(float x){
    return 0.5f * x * (1.0f + erff(x * 0.70710678118654752f));
}

// ---------------- K0: sincos of pos_phases (L,P) ----------------
__global__ void k_sincos(const float* __restrict__ ph, float* __restrict__ cpos,
                         float* __restrict__ spos){
    int idx = blockIdx.x * 256 + threadIdx.x;   // L_*P_ = 65536 total
    float s, c;
    sincosf(ph[idx], &s, &c);
    cpos[idx] = c;
    spos[idx] = s;
}

// ---------------- K1: fused projections, 16 tokens per block ----------------
__global__ __launch_bounds__(256) void k_proj(
    const float* __restrict__ x,
    const float* __restrict__ w_pv, const float* __restrict__ b_pv,
    const float* __restrict__ w_key, const float* __restrict__ b_key,
    const float* __restrict__ w_kv, const float* __restrict__ b_kv,
    const float* __restrict__ w_vg1, const float* __restrict__ b_vg1,
    const float* __restrict__ w_vg2, const float* __restrict__ b_vg2,
    const float* __restrict__ w_bg1, const float* __restrict__ b_bg1,
    const float* __restrict__ w_bg2, const float* __restrict__ b_bg2,
    float* __restrict__ pv, float* __restrict__ kvv,
    float* __restrict__ ck, float* __restrict__ sk,
    float* __restrict__ vg, float* __restrict__ blend0, float* __restrict__ blend1)
{
    __shared__ float xsT[256][20];   // [k][t], padded stride 20 (80B, 16B-aligned rows)
    __shared__ float xpT[256][20];   // shifted rows
    __shared__ float hbuf[16][256];  // gelu(vg1) activations
    __shared__ float bhbuf[16][128]; // gelu(bg1) activations
    __shared__ float red[16][17];
    __shared__ float red2[16][17];

    const int i  = threadIdx.x;
    const int b  = blockIdx.x >> 7;          // 128 blocks per batch
    const int l0 = (blockIdx.x & 127) * 16;
    const int d  = i;

    for (int t = 0; t < 16; ++t){
        xsT[d][t] = x[(size_t)(b * L_ + l0 + t) * D_ + d];
        int lp = l0 + t - 1;
        xpT[d][t] = (lp >= 0) ? x[(size_t)(b * L_ + lp) * D_ + d] : 0.0f;
    }
    __syncthreads();

    // --- pos_value, kv_value, value-gate hidden (all 256-col outputs) ---
    float accPV[16], accKV[16], accVG[16];
    #pragma unroll
    for (int t = 0; t < 16; ++t){ accPV[t] = 0.f; accKV[t] = 0.f; accVG[t] = 0.f; }

    for (int k = 0; k < 256; ++k){
        float xa[16], xp[16];
        *(float4*)&xa[0]  = *(const float4*)&xsT[k][0];
        *(float4*)&xa[4]  = *(const float4*)&xsT[k][4];
        *(float4*)&xa[8]  = *(const float4*)&xsT[k][8];
        *(float4*)&xa[12] = *(const float4*)&xsT[k][12];
        *(float4*)&xp[0]  = *(const float4*)&xpT[k][0];
        *(float4*)&xp[4]  = *(const float4*)&xpT[k][4];
        *(float4*)&xp[8]  = *(const float4*)&xpT[k][8];
        *(float4*)&xp[12] = *(const float4*)&xpT[k][12];
        float w0 = w_pv [k * 256 + d];
        float w1 = w_kv [k * 256 + d];
        float w2 = w_vg1[k * 256 + d];
        float w3 = w_vg1[(256 + k) * 256 + d];
        #pragma unroll
        for (int t = 0; t < 16; ++t){
            accPV[t] = fmaf(xa[t], w0, accPV[t]);
            accKV[t] = fmaf(xa[t], w1, accKV[t]);
            accVG[t] = fmaf(xa[t], w2, accVG[t]);
            accVG[t] = fmaf(xp[t], w3, accVG[t]);
        }
    }
    {
        float bpv = b_pv[d], bkv = b_kv[d], bvg = b_vg1[d];
        for (int t = 0; t < 16; ++t){
            pv [(size_t)(b * L_ + l0 + t) * D_ + d] = accPV[t] + bpv;
            kvv[(size_t)(b * L_ + l0 + t) * D_ + d] = accKV[t] + bkv;
            hbuf[t][d] = gelu_exact(accVG[t] + bvg);
        }
    }
    __syncthreads();

    // --- value gate: sigmoid(h @ w_vg2 + b) ---
    {
        int t = i >> 4, c = i & 15;
        float s = 0.f;
        #pragma unroll
        for (int m = 0; m < 16; ++m){ int dd = c + 16 * m; s += hbuf[t][dd] * w_vg2[dd]; }
        red[t][c] = s;
    }
    __syncthreads();
    if (i < 16){
        float s = 0.f;
        #pragma unroll
        for (int c = 0; c < 16; ++c) s += red[i][c];
        s += b_vg2[0];
        vg[b * L_ + l0 + i] = 1.0f / (1.0f + expf(-s));
    }

    // --- key phases -> phasors ---
    {
        int p = i & 31, tt = i >> 5;           // tt in 0..7, covers t=tt and t=tt+8
        float a1 = 0.f, a2 = 0.f;
        for (int k = 0; k < 256; ++k){
            float wk = w_key[k * 32 + p];
            a1 = fmaf(xsT[k][tt],     wk, a1);
            a2 = fmaf(xsT[k][tt + 8], wk, a2);
        }
        float bk = b_key[p];
        a1 = tanhf(a1 + bk) * PI_F;
        a2 = tanhf(a2 + bk) * PI_F;
        float s, c;
        sincosf(a1, &s, &c);
        ck[(size_t)(b * L_ + l0 + tt) * P_ + p] = c;
        sk[(size_t)(b * L_ + l0 + tt) * P_ + p] = s;
        sincosf(a2, &s, &c);
        ck[(size_t)(b * L_ + l0 + tt + 8) * P_ + p] = c;
        sk[(size_t)(b * L_ + l0 + tt + 8) * P_ + p] = s;
    }

    // --- blend gate hidden: gelu(x @ w_bg1 + b), 128 cols ---
    {
        int j = i & 127, tg = i >> 7;          // tg in 0..1, 8 tokens each
        float accB[8];
        #pragma unroll
        for (int m = 0; m < 8; ++m) accB[m] = 0.f;
        for (int k = 0; k < 256; ++k){
            float wb = w_bg1[k * 128 + j];
            float q[8];
            *(float4*)&q[0] = *(const float4*)&xsT[k][tg * 8];
            *(float4*)&q[4] = *(const float4*)&xsT[k][tg * 8 + 4];
            #pragma unroll
            for (int m = 0; m < 8; ++m) accB[m] = fmaf(q[m], wb, accB[m]);
        }
        float bb = b_bg1[j];
        #pragma unroll
        for (int m = 0; m < 8; ++m) bhbuf[tg * 8 + m][j] = gelu_exact(accB[m] + bb);
    }
    __syncthreads();

    // --- blend logits + softmax(2) ---
    {
        int t = i >> 4, c = i & 15;
        float s0 = 0.f, s1 = 0.f;
        #pragma unroll
        for (int m = 0; m < 8; ++m){
            int jj = c + 16 * m;
            float v = bhbuf[t][jj];
            s0 += v * w_bg2[jj * 2 + 0];
            s1 += v * w_bg2[jj * 2 + 1];
        }
        red[t][c] = s0; red2[t][c] = s1;
    }
    __syncthreads();
    if (i < 16){
        float s0 = 0.f, s1 = 0.f;
        #pragma unroll
        for (int c = 0; c < 16; ++c){ s0 += red[i][c]; s1 += red2[i][c]; }
        s0 += b_bg2[0]; s1 += b_bg2[1];
        float mx = fmaxf(s0, s1);
        float e0 = expf(s0 - mx), e1 = expf(s1 - mx);
        float inv = 1.0f / (e0 + e1);
        blend0[b * L_ + l0 + i] = e0 * inv;
        blend1[b * L_ + l0 + i] = e1 * inv;
    }
}

// ---------------- K5: gate cumsum -> rnorm = rsqrt(max(cumsum,1))/sqrt(P) ----------------
__global__ __launch_bounds__(256) void k_gatecum(const float* __restrict__ vg,
                                                 float* __restrict__ rnorm){
    int b = blockIdx.x, i = threadIdx.x;
    float loc[8];
    float run = 0.f;
    #pragma unroll
    for (int m = 0; m < 8; ++m){ run += vg[b * L_ + i * 8 + m]; loc[m] = run; }
    __shared__ float part[256];
    part[i] = run;
    __syncthreads();
    for (int off = 1; off < 256; off <<= 1){
        float t = (i >= off) ? part[i - off] : 0.0f;
        __syncthreads();
        part[i] += t;
        __syncthreads();
    }
    float excl = part[i] - run;
    #pragma unroll
    for (int m = 0; m < 8; ++m){
        float gc = fmaxf(excl + loc[m], 1.0f);
        rnorm[b * L_ + i * 8 + m] = rsqrtf(gc) * INV_SQRT_P;
    }
}

// ---------------- K2a: pos-memory chunk sums ----------------
__global__ __launch_bounds__(256) void k_pos_chunksum(
    const float* __restrict__ cpos, const float* __restrict__ spos,
    const float* __restrict__ pv, float* __restrict__ Sr_, float* __restrict__ Si_)
{
    __shared__ float cp[CL_][32], sp[CL_][32];
    int c = blockIdx.x, b = blockIdx.y, d = threadIdx.x;
    #pragma unroll
    for (int m = 0; m < 4; ++m){
        int idx = threadIdx.x + 256 * m;
        int ll = idx >> 5, pp = idx & 31;
        cp[ll][pp] = cpos[(c * CL_ + ll) * P_ + pp];
        sp[ll][pp] = spos[(c * CL_ + ll) * P_ + pp];
    }
    __syncthreads();
    float Sr[32], Si[32];
    #pragma unroll
    for (int p = 0; p < 32; ++p){ Sr[p] = 0.f; Si[p] = 0.f; }
    for (int l = 0; l < CL_; ++l){
        float v = pv[(size_t)(b * L_ + c * CL_ + l) * D_ + d];
        #pragma unroll
        for (int pq = 0; pq < 8; ++pq){
            float4 cc = *(const float4*)&cp[l][pq * 4];
            float4 ss = *(const float4*)&sp[l][pq * 4];
            Sr[pq*4+0] = fmaf(cc.x, v, Sr[pq*4+0]); Si[pq*4+0] = fmaf(ss.x, v, Si[pq*4+0]);
            Sr[pq*4+1] = fmaf(cc.y, v, Sr[pq*4+1]); Si[pq*4+1] = fmaf(ss.y, v, Si[pq*4+1]);
            Sr[pq*4+2] = fmaf(cc.z, v, Sr[pq*4+2]); Si[pq*4+2] = fmaf(ss.z, v, Si[pq*4+2]);
            Sr[pq*4+3] = fmaf(cc.w, v, Sr[pq*4+3]); Si[pq*4+3] = fmaf(ss.w, v, Si[pq*4+3]);
        }
    }
    #pragma unroll
    for (int p = 0; p < 32; ++p){
        size_t o = (size_t)((b * NC_ + c) * P_ + p) * D_ + d;
        Sr_[o] = Sr[p]; Si_[o] = Si[p];
    }
}

// ---------------- K3: in-place exclusive prefix over chunks ----------------
__global__ __launch_bounds__(256) void k_prefix(float* __restrict__ Ar, float* __restrict__ Ai){
    int gid = blockIdx.x * 256 + threadIdx.x;   // 0 .. 2*B*P*D-1
    const int NPD = B_ * P_ * D_;
    float* A = (gid < NPD) ? Ar : Ai;
    int g = (gid < NPD) ? gid : gid - NPD;
    int b = g >> 13;          // P_*D_ = 8192
    int pd = g & 8191;
    float run = 0.f;
    for (int c = 0; c < NC_; ++c){
        size_t idx = (size_t)(b * NC_ + c) * (P_ * D_) + pd;
        float t = A[idx];
        A[idx] = run;
        run += t;
    }
}

// ---------------- K4a: pos-memory retrieve ----------------
__global__ __launch_bounds__(256) void k_pos_retrieve(
    const float* __restrict__ cpos, const float* __restrict__ spos,
    const float* __restrict__ pv,
    const float* __restrict__ Sr_, const float* __restrict__ Si_,
    float* __restrict__ pos_ret)
{
    __shared__ float cp[CL_][32], sp[CL_][32];
    int c = blockIdx.x, b = blockIdx.y, d = threadIdx.x;
    #pragma unroll
    for (int m = 0; m < 4; ++m){
        int idx = threadIdx.x + 256 * m;
        int ll = idx >> 5, pp = idx & 31;
        cp[ll][pp] = cpos[(c * CL_ + ll) * P_ + pp];
        sp[ll][pp] = spos[(c * CL_ + ll) * P_ + pp];
    }
    __syncthreads();
    float Sr[32], Si[32];
    #pragma unroll
    for (int p = 0; p < 32; ++p){
        size_t o = (size_t)((b * NC_ + c) * P_ + p) * D_ + d;
        Sr[p] = Sr_[o]; Si[p] = Si_[o];
    }
    for (int l = 0; l < CL_; ++l){
        float v = pv[(size_t)(b * L_ + c * CL_ + l) * D_ + d];
        float ret = 0.f;
        #pragma unroll
        for (int pq = 0; pq < 8; ++pq){
            float4 cc = *(const float4*)&cp[l][pq * 4];
            float4 ss = *(const float4*)&sp[l][pq * 4];
            Sr[pq*4+0] = fmaf(cc.x, v, Sr[pq*4+0]); ret = fmaf(cc.x, Sr[pq*4+0], ret);
            Si[pq*4+0] = fmaf(ss.x, v, Si[pq*4+0]); ret = fmaf(ss.x, Si[pq*4+0], ret);
            Sr[pq*4+1] = fmaf(cc.y, v, Sr[pq*4+1]); ret = fmaf(cc.y, Sr[pq*4+1], ret);
            Si[pq*4+1] = fmaf(ss.y, v, Si[pq*4+1]); ret = fmaf(ss.y, Si[pq*4+1], ret);
            Sr[pq*4+2] = fmaf(cc.z, v, Sr[pq*4+2]); ret = fmaf(cc.z, Sr[pq*4+2], ret);
            Si[pq*4+2] = fmaf(ss.z, v, Si[pq*4+2]); ret = fmaf(ss.z, Si[pq*4+2], ret);
            Sr[pq*4+3] = fmaf(cc.w, v, Sr[pq*4+3]); ret = fmaf(cc.w, Sr[pq*4+3], ret);
            Si[pq*4+3] = fmaf(ss.w, v, Si[pq*4+3]); ret = fmaf(ss.w, Si[pq*4+3], ret);
        }
        pos_ret[(size_t)(b * L_ + c * CL_ + l) * D_ + d] = ret * INV_SQRT_P;
    }
}

// ---------------- K2b: kv-memory chunk sums (shifted phasors, gated values) ----------------
__global__ __launch_bounds__(256) void k_kv_chunksum(
    const float* __restrict__ ck, const float* __restrict__ sk,
    const float* __restrict__ kvv, const float* __restrict__ vg,
    float* __restrict__ Sr_, float* __restrict__ Si_)
{
    __shared__ float cs[CL_][32], ss_[CL_][32];
    __shared__ float gb[CL_];
    int c = blockIdx.x, b = blockIdx.y, d = threadIdx.x;
    #pragma unroll
    for (int m = 0; m < 4; ++m){
        int idx = threadIdx.x + 256 * m;
        int ll = idx >> 5, pp = idx & 31;
        int srow = c * CL_ + ll - 1;
        cs [ll][pp] = (srow >= 0) ? ck[(size_t)(b * L_ + srow) * P_ + pp] : 0.0f;
        ss_[ll][pp] = (srow >= 0) ? sk[(size_t)(b * L_ + srow) * P_ + pp] : 0.0f;
    }
    if (threadIdx.x < CL_) gb[threadIdx.x] = vg[b * L_ + c * CL_ + threadIdx.x];
    __syncthreads();
    float Sr[32], Si[32];
    #pragma unroll
    for (int p = 0; p < 32; ++p){ Sr[p] = 0.f; Si[p] = 0.f; }
    for (int l = 0; l < CL_; ++l){
        float vv = kvv[(size_t)(b * L_ + c * CL_ + l) * D_ + d] * gb[l];
        #pragma unroll
        for (int pq = 0; pq < 8; ++pq){
            float4 cc = *(const float4*)&cs [l][pq * 4];
            float4 ss = *(const float4*)&ss_[l][pq * 4];
            Sr[pq*4+0] = fmaf(cc.x, vv, Sr[pq*4+0]); Si[pq*4+0] = fmaf(ss.x, vv, Si[pq*4+0]);
            Sr[pq*4+1] = fmaf(cc.y, vv, Sr[pq*4+1]); Si[pq*4+1] = fmaf(ss.y, vv, Si[pq*4+1]);
            Sr[pq*4+2] = fmaf(cc.z, vv, Sr[pq*4+2]); Si[pq*4+2] = fmaf(ss.z, vv, Si[pq*4+2]);
            Sr[pq*4+3] = fmaf(cc.w, vv, Sr[pq*4+3]); Si[pq*4+3] = fmaf(ss.w, vv, Si[pq*4+3]);
        }
    }
    #pragma unroll
    for (int p = 0; p < 32; ++p){
        size_t o = (size_t)((b * NC_ + c) * P_ + p) * D_ + d;
        Sr_[o] = Sr[p]; Si_[o] = Si[p];
    }
}

// ---------------- K4b: kv-memory retrieve + blend (in place into pos_ret) ----------------
__global__ __launch_bounds__(256) void k_kv_retrieve(
    const float* __restrict__ ck, const float* __restrict__ sk,
    const float* __restrict__ kvv, const float* __restrict__ vg,
    const float* __restrict__ rnorm,
    const float* __restrict__ Sr_, const float* __restrict__ Si_,
    const float* __restrict__ blend0, const float* __restrict__ blend1,
    float* __restrict__ blended)
{
    __shared__ float cs[CL_][32], ss_[CL_][32], cq[CL_][32], sq[CL_][32];
    __shared__ float gb[CL_], rn[CL_], w0[CL_], w1[CL_];
    int c = blockIdx.x, b = blockIdx.y, d = threadIdx.x;
    #pragma unroll
    for (int m = 0; m < 4; ++m){
        int idx = threadIdx.x + 256 * m;
        int ll = idx >> 5, pp = idx & 31;
        int srow = c * CL_ + ll - 1;
        cs [ll][pp] = (srow >= 0) ? ck[(size_t)(b * L_ + srow) * P_ + pp] : 0.0f;
        ss_[ll][pp] = (srow >= 0) ? sk[(size_t)(b * L_ + srow) * P_ + pp] : 0.0f;
        cq [ll][pp] = ck[(size_t)(b * L_ + c * CL_ + ll) * P_ + pp];
        sq [ll][pp] = sk[(size_t)(b * L_ + c * CL_ + ll) * P_ + pp];
    }
    if (threadIdx.x < CL_){
        int gl = b * L_ + c * CL_ + threadIdx.x;
        gb[threadIdx.x] = vg[gl];
        rn[threadIdx.x] = rnorm[gl];
        w0[threadIdx.x] = blend0[gl];
        w1[threadIdx.x] = blend1[gl];
    }
    __syncthreads();
    float Sr[32], Si[32];
    #pragma unroll
    for (int p = 0; p < 32; ++p){
        size_t o = (size_t)((b * NC_ + c) * P_ + p) * D_ + d;
        Sr[p] = Sr_[o]; Si[p] = Si_[o];
    }
    for (int l = 0; l < CL_; ++l){
        float vv = kvv[(size_t)(b * L_ + c * CL_ + l) * D_ + d] * gb[l];
        float ret = 0.f;
        #pragma unroll
        for (int pq = 0; pq < 8; ++pq){
            float4 cc = *(const float4*)&cs [l][pq * 4];
            float4 ss = *(const float4*)&ss_[l][pq * 4];
            float4 qc = *(const float4*)&cq [l][pq * 4];
            float4 qs = *(const float4*)&sq [l][pq * 4];
            Sr[pq*4+0] = fmaf(cc.x, vv, Sr[pq*4+0]); ret = fmaf(qc.x, Sr[pq*4+0], ret);
            Si[pq*4+0] = fmaf(ss.x, vv, Si[pq*4+0]); ret = fmaf(qs.x, Si[pq*4+0], ret);
            Sr[pq*4+1] = fmaf(cc.y, vv, Sr[pq*4+1]); ret = fmaf(qc.y, Sr[pq*4+1], ret);
            Si[pq*4+1] = fmaf(ss.y, vv, Si[pq*4+1]); ret = fmaf(qs.y, Si[pq*4+1], ret);
            Sr[pq*4+2] = fmaf(cc.z, vv, Sr[pq*4+2]); ret = fmaf(qc.z, Sr[pq*4+2], ret);
            Si[pq*4+2] = fmaf(ss.z, vv, Si[pq*4+2]); ret = fmaf(qs.z, Si[pq*4+2], ret);
            Sr[pq*4+3] = fmaf(cc.w, vv, Sr[pq*4+3]); ret = fmaf(qc.w, Sr[pq*4+3], ret);
            Si[pq*4+3] = fmaf(ss.w, vv, Si[pq*4+3]); ret = fmaf(qs.w, Si[pq*4+3], ret);
        }
        ret *= rn[l];
        size_t o = (size_t)(b * L_ + c * CL_ + l) * D_ + d;
        blended[o] = w0[l] * blended[o] + w1[l] * ret;
    }
}

// ---------------- K9: blend -> LN -> r1(gelu) -> r2 -> LN -> out, 16 tokens/block ----------------
__global__ __launch_bounds__(256) void k_final(
    const float* __restrict__ x, const float* __restrict__ blended,
    const float* __restrict__ ln_r_g, const float* __restrict__ ln_r_b,
    const float* __restrict__ w_r1, const float* __restrict__ b_r1,
    const float* __restrict__ w_r2, const float* __restrict__ b_r2,
    const float* __restrict__ ln_o_g, const float* __restrict__ ln_o_b,
    const float* __restrict__ w_out, const float* __restrict__ b_out,
    float* __restrict__ out)
{
    __shared__ float zT[256][20];
    __shared__ float h2T[512][20];
    __shared__ float red[16][17], red2[16][17];
    __shared__ float mu[16], rs[16];

    const int i  = threadIdx.x;
    const int b  = blockIdx.x >> 7;
    const int l0 = (blockIdx.x & 127) * 16;
    const int d  = i;

    for (int t = 0; t < 16; ++t)
        zT[d][t] = blended[(size_t)(b * L_ + l0 + t) * D_ + d];
    __syncthreads();

    // LN1 stats
    {
        int t = i >> 4, c = i & 15;
        float s = 0.f, s2 = 0.f;
        #pragma unroll
        for (int m = 0; m < 16; ++m){ float v = zT[c + 16 * m][t]; s += v; s2 += v * v; }
        red[t][c] = s; red2[t][c] = s2;
    }
    __syncthreads();
    if (i < 16){
        float s = 0.f, s2 = 0.f;
        #pragma unroll
        for (int c = 0; c < 16; ++c){ s += red[i][c]; s2 += red2[i][c]; }
        float mean = s * (1.0f / 256.0f);
        float var  = s2 * (1.0f / 256.0f) - mean * mean;
        mu[i] = mean; rs[i] = rsqrtf(var + 1e-5f);
    }
    __syncthreads();
    {
        float g = ln_r_g[d], bb = ln_r_b[d];
        for (int t = 0; t < 16; ++t)
            zT[d][t] = (zT[d][t] - mu[t]) * rs[t] * g + bb;
    }
    __syncthreads();

    // r1: 512 columns, each thread does j=i and j=i+256
    {
        float h0[16], h1[16];
        #pragma unroll
        for (int t = 0; t < 16; ++t){ h0[t] = 0.f; h1[t] = 0.f; }
        for (int k = 0; k < 256; ++k){
            float za[16];
            *(float4*)&za[0]  = *(const float4*)&zT[k][0];
            *(float4*)&za[4]  = *(const float4*)&zT[k][4];
            *(float4*)&za[8]  = *(const float4*)&zT[k][8];
            *(float4*)&za[12] = *(const float4*)&zT[k][12];
            float wa = w_r1[k * 512 + i];
            float wb = w_r1[k * 512 + i + 256];
            #pragma unroll
            for (int t = 0; t < 16; ++t){
                h0[t] = fmaf(za[t], wa, h0[t]);
                h1[t] = fmaf(za[t], wb, h1[t]);
            }
        }
        float ba = b_r1[i], bb = b_r1[i + 256];
        #pragma unroll
        for (int t = 0; t < 16; ++t){
            h2T[i][t]       = gelu_exact(h0[t] + ba);
            h2T[i + 256][t] = gelu_exact(h1[t] + bb);
        }
    }
    __syncthreads();

    // r2 -> refined (reuse zT)
    {
        float acc[16];
        #pragma unroll
        for (int t = 0; t < 16; ++t) acc[t] = 0.f;
        for (int j = 0; j < 512; ++j){
            float ha[16];
            *(float4*)&ha[0]  = *(const float4*)&h2T[j][0];
            *(float4*)&ha[4]  = *(const float4*)&h2T[j][4];
            *(float4*)&ha[8]  = *(const float4*)&h2T[j][8];
            *(float4*)&ha[12] = *(const float4*)&h2T[j][12];
            float w = w_r2[j * 256 + d];
            #pragma unroll
            for (int t = 0; t < 16; ++t) acc[t] = fmaf(ha[t], w, acc[t]);
        }
        float bb = b_r2[d];
        #pragma unroll
        for (int t = 0; t < 16; ++t) zT[d][t] = acc[t] + bb;
    }
    __syncthreads();

    // LN2 stats
    {
        int t = i >> 4, c = i & 15;
        float s = 0.f, s2 = 0.f;
        #pragma unroll
        for (int m = 0; m < 16; ++m){ float v = zT[c + 16 * m][t]; s += v; s2 += v * v; }
        red[t][c] = s; red2[t][c] = s2;
    }
    __syncthreads();
    if (i < 16){
        float s = 0.f, s2 = 0.f;
        #pragma unroll
        for (int c = 0; c < 16; ++c){ s += red[i][c]; s2 += red2[i][c]; }
        float mean = s * (1.0f / 256.0f);
        float var  = s2 * (1.0f / 256.0f) - mean * mean;
        mu[i] = mean; rs[i] = rsqrtf(var + 1e-5f);
    }
    __syncthreads();
    {
        float g = ln_o_g[d], bb = ln_o_b[d];
        for (int t = 0; t < 16; ++t)
            zT[d][t] = (zT[d][t] - mu[t]) * rs[t] * g + bb;
    }
    __syncthreads();

    // out = x + z @ w_out + b_out
    {
        float acc[16];
        #pragma unroll
        for (int t = 0; t < 16; ++t) acc[t] = 0.f;
        for (int k = 0; k < 256; ++k){
            float za[16];
            *(float4*)&za[0]  = *(const float4*)&zT[k][0];
            *(float4*)&za[4]  = *(const float4*)&zT[k][4];
            *(float4*)&za[8]  = *(const float4*)&zT[k][8];
            *(float4*)&za[12] = *(const float4*)&zT[k][12];
            float w = w_out[k * 256 + d];
            #pragma unroll
            for (int t = 0; t < 16; ++t) acc[t] = fmaf(za[t], w, acc[t]);
        }
        float bo = b_out[d];
        #pragma unroll
        for (int t = 0; t < 16; ++t){
            size_t o = (size_t)(b * L_ + l0 + t) * D_ + d;
            out[o] = x[o] + acc[t] + bo;
        }
    }
}

extern "C" void kernel_launch(void* const* d_in, const int* in_sizes, int n_in,
                              void* d_out, int out_size, void* d_ws, size_t ws_size,
                              hipStream_t stream) {
    const float* x          = (const float*)d_in[0];
    const float* pos_phases = (const float*)d_in[1];
    const float* w_pv       = (const float*)d_in[2];
    const float* b_pv       = (const float*)d_in[3];
    const float* w_key      = (const float*)d_in[4];
    const float* b_key      = (const float*)d_in[5];
    const float* w_kv       = (const float*)d_in[6];
    const float* b_kv       = (const float*)d_in[7];
    const float* w_vg1      = (const float*)d_in[8];
    const float* b_vg1      = (const float*)d_in[9];
    const float* w_vg2      = (const float*)d_in[10];
    const float* b_vg2      = (const float*)d_in[11];
    const float* w_bg1      = (const float*)d_in[12];
    const float* b_bg1      = (const float*)d_in[13];
    const float* w_bg2      = (const float*)d_in[14];
    const float* b_bg2      = (const float*)d_in[15];
    const float* ln_r_g     = (const float*)d_in[16];
    const float* ln_r_b     = (const float*)d_in[17];
    const float* w_r1       = (const float*)d_in[18];
    const float* b_r1       = (const float*)d_in[19];
    const float* w_r2       = (const float*)d_in[20];
    const float* b_r2       = (const float*)d_in[21];
    const float* ln_o_g     = (const float*)d_in[22];
    const float* ln_o_b     = (const float*)d_in[23];
    const float* w_out      = (const float*)d_in[24];
    const float* b_out      = (const float*)d_in[25];
    float* out = (float*)d_out;

    float* ws = (float*)d_ws;
    size_t off = 0;
    float* cpos   = ws + off; off += (size_t)L_ * P_;
    float* spos   = ws + off; off += (size_t)L_ * P_;
    float* pv     = ws + off; off += (size_t)B_ * L_ * D_;
    float* kvv    = ws + off; off += (size_t)B_ * L_ * D_;
    float* ck     = ws + off; off += (size_t)B_ * L_ * P_;
    float* sk     = ws + off; off += (size_t)B_ * L_ * P_;
    float* vg     = ws + off; off += (size_t)B_ * L_;
    float* rnorm  = ws + off; off += (size_t)B_ * L_;
    float* blend0 = ws + off; off += (size_t)B_ * L_;
    float* blend1 = ws + off; off += (size_t)B_ * L_;
    float* blended= ws + off; off += (size_t)B_ * L_ * D_;   // pos_ret, then blended in place
    float* posSr  = ws + off; off += (size_t)B_ * NC_ * P_ * D_;
    float* posSi  = ws + off; off += (size_t)B_ * NC_ * P_ * D_;
    float* kvSr   = ws + off; off += (size_t)B_ * NC_ * P_ * D_;
    float* kvSi   = ws + off; off += (size_t)B_ * NC_ * P_ * D_;

    k_sincos<<<(L_ * P_) / 256, 256, 0, stream>>>(pos_phases, cpos, spos);
    k_proj<<<(B_ * L_) / 16, 256, 0, stream>>>(x,
        w_pv, b_pv, w_key, b_key, w_kv, b_kv, w_vg1, b_vg1, w_vg2, b_vg2,
        w_bg1, b_bg1, w_bg2, b_bg2,
        pv, kvv, ck, sk, vg, blend0, blend1);
    k_gatecum<<<B_, 256, 0, stream>>>(vg, rnorm);

    dim3 gs(NC_, B_);
    k_pos_chunksum<<<gs, 256, 0, stream>>>(cpos, spos, pv, posSr, posSi);
    k_prefix<<<(2 * B_ * P_ * D_) / 256, 256, 0, stream>>>(posSr, posSi);
    k_pos_retrieve<<<gs, 256, 0, stream>>>(cpos, spos, pv, posSr, posSi, blended);

    k_kv_chunksum<<<gs, 256, 0, stream>>>(ck, sk, kvv, vg, kvSr, kvSi);
    k_prefix<<<(2 * B_ * P_ * D_) / 256, 256, 0, stream>>>(kvSr, kvSi);
    k_kv_retrieve<<<gs, 256, 0, stream>>>(ck, sk, kvv, vg, rnorm, kvSr, kvSi,
                                          blend0, blend1, blended);

    k_final<<<(B_ * L_) / 16, 256, 0, stream>>>(x, blended,
        ln_r_g, ln_r_b, w_r1, b_r1, w_r2, b_r2, ln_o_g, ln_o_b, w_out, b_out, out);
}

// Round 2
// 299.700 us; speedup vs baseline: 1.0109x; 1.0109x over previous
//
#include <hip/hip_runtime.h>
#include <math.h>

#define B_ 2
#define L_ 2048
#define D_ 256
#define P_ 32
#define NC_ 64
#define CL_ 32

#define INV_SQRT_P 0.17677669529663687f   // 1/sqrt(32)
#define PI_F 3.14159265358979323846f

__device__ __forceinline__ float gelu_exact(float x){
    return 0.5f * x * (1.0f + erff(x * 0.70710678118654752f));
}

// ---------------- K0: sincos of pos_phases (L,P) ----------------
__global__ void k_sincos(const float* __restrict__ ph, float* __restrict__ cpos,
                         float* __restrict__ spos){
    int idx = blockIdx.x * 256 + threadIdx.x;   // L_*P_ = 65536 total
    float s, c;
    sincosf(ph[idx], &s, &c);
    cpos[idx] = c;
    spos[idx] = s;
}

// ---------------- K1: fused projections, 8 tokens/block, 1024 threads ----------------
// groups of 256 threads: g0=pos_value, g1=kv_value(+key phasors), g2=vg1(x half),
// g3=vg1(shifted half). bg1 spread over all 1024 threads.
__global__ __launch_bounds__(1024) void k_proj(
    const float* __restrict__ x,
    const float* __restrict__ w_pv, const float* __restrict__ b_pv,
    const float* __restrict__ w_key, const float* __restrict__ b_key,
    const float* __restrict__ w_kv, const float* __restrict__ b_kv,
    const float* __restrict__ w_vg1, const float* __restrict__ b_vg1,
    const float* __restrict__ w_vg2, const float* __restrict__ b_vg2,
    const float* __restrict__ w_bg1, const float* __restrict__ b_bg1,
    const float* __restrict__ w_bg2, const float* __restrict__ b_bg2,
    float* __restrict__ pv, float* __restrict__ kvv,
    float* __restrict__ ck, float* __restrict__ sk,
    float* __restrict__ vg, float* __restrict__ blend0, float* __restrict__ blend1)
{
    __shared__ float xsT[256][12];    // [k][t], stride 12 floats (48B, 16B-aligned)
    __shared__ float xpT[256][12];    // shifted rows
    __shared__ float vgpart[8][256];  // partial vg1 (x half)
    __shared__ float hbuf[8][256];    // gelu(vg1) activations
    __shared__ float bhbuf[8][128];   // gelu(bg1) activations
    __shared__ float red[8][17], red2[8][17], red3[8][17];

    const int i  = threadIdx.x;
    const int b  = blockIdx.x >> 8;          // 256 blocks per batch
    const int l0 = (blockIdx.x & 255) * 8;
    const int g  = i >> 8;                   // 0..3
    const int d  = i & 255;

    #pragma unroll
    for (int m = 0; m < 2; ++m){
        int e = i + 1024 * m;
        int t = e >> 8, d2 = e & 255;
        xsT[d2][t] = x[(size_t)(b * L_ + l0 + t) * D_ + d2];
        int lp = l0 + t - 1;
        xpT[d2][t] = (lp >= 0) ? x[(size_t)(b * L_ + lp) * D_ + d2] : 0.0f;
    }
    __syncthreads();

    // --- main 256-k GEMM loop, one output matrix per group ---
    const float* Wg = (g == 0) ? w_pv : (g == 1) ? w_kv : (g == 2) ? w_vg1
                                                        : (w_vg1 + 256 * 256);
    const float (*X)[12] = (g == 3) ? xpT : xsT;
    float acc[8];
    #pragma unroll
    for (int t = 0; t < 8; ++t) acc[t] = 0.f;
    for (int k = 0; k < 256; ++k){
        float w = Wg[k * 256 + d];
        float xa[8];
        *(float4*)&xa[0] = *(const float4*)&X[k][0];
        *(float4*)&xa[4] = *(const float4*)&X[k][4];
        #pragma unroll
        for (int t = 0; t < 8; ++t) acc[t] = fmaf(xa[t], w, acc[t]);
    }
    if (g == 0){
        float bb = b_pv[d];
        #pragma unroll
        for (int t = 0; t < 8; ++t) pv[(size_t)(b * L_ + l0 + t) * D_ + d] = acc[t] + bb;
    } else if (g == 1){
        float bb = b_kv[d];
        #pragma unroll
        for (int t = 0; t < 8; ++t) kvv[(size_t)(b * L_ + l0 + t) * D_ + d] = acc[t] + bb;
    } else if (g == 2){
        #pragma unroll
        for (int t = 0; t < 8; ++t) vgpart[t][d] = acc[t];
    }
    __syncthreads();
    if (g == 3){
        float bb = b_vg1[d];
        #pragma unroll
        for (int t = 0; t < 8; ++t) hbuf[t][d] = gelu_exact(vgpart[t][d] + acc[t] + bb);
    }

    // --- key phases -> phasors (group 1: 256 threads = 32 p x 8 t) ---
    if (g == 1){
        int p = d & 31, tt = d >> 5;
        float a = 0.f;
        for (int k = 0; k < 256; ++k)
            a = fmaf(xsT[k][tt], w_key[k * 32 + p], a);
        a = tanhf(a + b_key[p]) * PI_F;
        float s, c;
        sincosf(a, &s, &c);
        ck[(size_t)(b * L_ + l0 + tt) * P_ + p] = c;
        sk[(size_t)(b * L_ + l0 + tt) * P_ + p] = s;
    }

    // --- blend gate hidden: gelu(x @ w_bg1 + b), 128 cols x 8 tokens = 1024 dots ---
    {
        int j = i & 127, tg = i >> 7;    // tg 0..7
        float a = 0.f;
        for (int k = 0; k < 256; ++k)
            a = fmaf(xsT[k][tg], w_bg1[k * 128 + j], a);
        bhbuf[tg][j] = gelu_exact(a + b_bg1[j]);
    }
    __syncthreads();

    // --- value gate reduce + blend logits ---
    if (i < 128){
        int t = i >> 4, c = i & 15;
        float s = 0.f;
        #pragma unroll
        for (int m = 0; m < 16; ++m){ int dd = c + 16 * m; s += hbuf[t][dd] * w_vg2[dd]; }
        red[t][c] = s;
    } else if (i < 256){
        int ii = i - 128;
        int t = ii >> 4, c = ii & 15;
        float s0 = 0.f, s1 = 0.f;
        #pragma unroll
        for (int m = 0; m < 8; ++m){
            int jj = c + 16 * m;
            float v = bhbuf[t][jj];
            s0 += v * w_bg2[jj * 2 + 0];
            s1 += v * w_bg2[jj * 2 + 1];
        }
        red2[t][c] = s0; red3[t][c] = s1;
    }
    __syncthreads();
    if (i < 8){
        float s = 0.f;
        #pragma unroll
        for (int c = 0; c < 16; ++c) s += red[i][c];
        s += b_vg2[0];
        vg[b * L_ + l0 + i] = 1.0f / (1.0f + expf(-s));
    } else if (i < 16){
        int t = i - 8;
        float s0 = 0.f, s1 = 0.f;
        #pragma unroll
        for (int c = 0; c < 16; ++c){ s0 += red2[t][c]; s1 += red3[t][c]; }
        s0 += b_bg2[0]; s1 += b_bg2[1];
        float mx = fmaxf(s0, s1);
        float e0 = expf(s0 - mx), e1 = expf(s1 - mx);
        float inv = 1.0f / (e0 + e1);
        blend0[b * L_ + l0 + t] = e0 * inv;
        blend1[b * L_ + l0 + t] = e1 * inv;
    }
}

// ---------------- K5: gate cumsum -> rnorm = rsqrt(max(cumsum,1))/sqrt(P) ----------------
__global__ __launch_bounds__(256) void k_gatecum(const float* __restrict__ vg,
                                                 float* __restrict__ rnorm){
    int b = blockIdx.x, i = threadIdx.x;
    float loc[8];
    float run = 0.f;
    #pragma unroll
    for (int m = 0; m < 8; ++m){ run += vg[b * L_ + i * 8 + m]; loc[m] = run; }
    __shared__ float part[256];
    part[i] = run;
    __syncthreads();
    for (int off = 1; off < 256; off <<= 1){
        float t = (i >= off) ? part[i - off] : 0.0f;
        __syncthreads();
        part[i] += t;
        __syncthreads();
    }
    float excl = part[i] - run;
    #pragma unroll
    for (int m = 0; m < 8; ++m){
        float gc = fmaxf(excl + loc[m], 1.0f);
        rnorm[b * L_ + i * 8 + m] = rsqrtf(gc) * INV_SQRT_P;
    }
}

// ---------------- K2a: pos-memory chunk sums ----------------
__global__ __launch_bounds__(256) void k_pos_chunksum(
    const float* __restrict__ cpos, const float* __restrict__ spos,
    const float* __restrict__ pv, float* __restrict__ Sr_, float* __restrict__ Si_)
{
    __shared__ float cp[CL_][32], sp[CL_][32];
    int c = blockIdx.x, b = blockIdx.y, d = threadIdx.x;
    #pragma unroll
    for (int m = 0; m < 4; ++m){
        int idx = threadIdx.x + 256 * m;
        int ll = idx >> 5, pp = idx & 31;
        cp[ll][pp] = cpos[(c * CL_ + ll) * P_ + pp];
        sp[ll][pp] = spos[(c * CL_ + ll) * P_ + pp];
    }
    __syncthreads();
    float Sr[32], Si[32];
    #pragma unroll
    for (int p = 0; p < 32; ++p){ Sr[p] = 0.f; Si[p] = 0.f; }
    for (int l = 0; l < CL_; ++l){
        float v = pv[(size_t)(b * L_ + c * CL_ + l) * D_ + d];
        #pragma unroll
        for (int pq = 0; pq < 8; ++pq){
            float4 cc = *(const float4*)&cp[l][pq * 4];
            float4 ss = *(const float4*)&sp[l][pq * 4];
            Sr[pq*4+0] = fmaf(cc.x, v, Sr[pq*4+0]); Si[pq*4+0] = fmaf(ss.x, v, Si[pq*4+0]);
            Sr[pq*4+1] = fmaf(cc.y, v, Sr[pq*4+1]); Si[pq*4+1] = fmaf(ss.y, v, Si[pq*4+1]);
            Sr[pq*4+2] = fmaf(cc.z, v, Sr[pq*4+2]); Si[pq*4+2] = fmaf(ss.z, v, Si[pq*4+2]);
            Sr[pq*4+3] = fmaf(cc.w, v, Sr[pq*4+3]); Si[pq*4+3] = fmaf(ss.w, v, Si[pq*4+3]);
        }
    }
    #pragma unroll
    for (int p = 0; p < 32; ++p){
        size_t o = (size_t)((b * NC_ + c) * P_ + p) * D_ + d;
        Sr_[o] = Sr[p]; Si_[o] = Si[p];
    }
}

// ---------------- K3: in-place exclusive prefix over chunks ----------------
__global__ __launch_bounds__(256) void k_prefix(float* __restrict__ Ar, float* __restrict__ Ai){
    int gid = blockIdx.x * 256 + threadIdx.x;   // 0 .. 2*B*P*D-1
    const int NPD = B_ * P_ * D_;
    float* A = (gid < NPD) ? Ar : Ai;
    int g = (gid < NPD) ? gid : gid - NPD;
    int b = g >> 13;          // P_*D_ = 8192
    int pd = g & 8191;
    float run = 0.f;
    for (int c = 0; c < NC_; ++c){
        size_t idx = (size_t)(b * NC_ + c) * (P_ * D_) + pd;
        float t = A[idx];
        A[idx] = run;
        run += t;
    }
}

// ---------------- K4a: pos-memory retrieve ----------------
__global__ __launch_bounds__(256) void k_pos_retrieve(
    const float* __restrict__ cpos, const float* __restrict__ spos,
    const float* __restrict__ pv,
    const float* __restrict__ Sr_, const float* __restrict__ Si_,
    float* __restrict__ pos_ret)
{
    __shared__ float cp[CL_][32], sp[CL_][32];
    int c = blockIdx.x, b = blockIdx.y, d = threadIdx.x;
    #pragma unroll
    for (int m = 0; m < 4; ++m){
        int idx = threadIdx.x + 256 * m;
        int ll = idx >> 5, pp = idx & 31;
        cp[ll][pp] = cpos[(c * CL_ + ll) * P_ + pp];
        sp[ll][pp] = spos[(c * CL_ + ll) * P_ + pp];
    }
    __syncthreads();
    float Sr[32], Si[32];
    #pragma unroll
    for (int p = 0; p < 32; ++p){
        size_t o = (size_t)((b * NC_ + c) * P_ + p) * D_ + d;
        Sr[p] = Sr_[o]; Si[p] = Si_[o];
    }
    for (int l = 0; l < CL_; ++l){
        float v = pv[(size_t)(b * L_ + c * CL_ + l) * D_ + d];
        float ret = 0.f;
        #pragma unroll
        for (int pq = 0; pq < 8; ++pq){
            float4 cc = *(const float4*)&cp[l][pq * 4];
            float4 ss = *(const float4*)&sp[l][pq * 4];
            Sr[pq*4+0] = fmaf(cc.x, v, Sr[pq*4+0]); ret = fmaf(cc.x, Sr[pq*4+0], ret);
            Si[pq*4+0] = fmaf(ss.x, v, Si[pq*4+0]); ret = fmaf(ss.x, Si[pq*4+0], ret);
            Sr[pq*4+1] = fmaf(cc.y, v, Sr[pq*4+1]); ret = fmaf(cc.y, Sr[pq*4+1], ret);
            Si[pq*4+1] = fmaf(ss.y, v, Si[pq*4+1]); ret = fmaf(ss.y, Si[pq*4+1], ret);
            Sr[pq*4+2] = fmaf(cc.z, v, Sr[pq*4+2]); ret = fmaf(cc.z, Sr[pq*4+2], ret);
            Si[pq*4+2] = fmaf(ss.z, v, Si[pq*4+2]); ret = fmaf(ss.z, Si[pq*4+2], ret);
            Sr[pq*4+3] = fmaf(cc.w, v, Sr[pq*4+3]); ret = fmaf(cc.w, Sr[pq*4+3], ret);
            Si[pq*4+3] = fmaf(ss.w, v, Si[pq*4+3]); ret = fmaf(ss.w, Si[pq*4+3], ret);
        }
        pos_ret[(size_t)(b * L_ + c * CL_ + l) * D_ + d] = ret * INV_SQRT_P;
    }
}

// ---------------- K2b: kv-memory chunk sums (shifted phasors, gated values) ----------------
__global__ __launch_bounds__(256) void k_kv_chunksum(
    const float* __restrict__ ck, const float* __restrict__ sk,
    const float* __restrict__ kvv, const float* __restrict__ vg,
    float* __restrict__ Sr_, float* __restrict__ Si_)
{
    __shared__ float cs[CL_][32], ss_[CL_][32];
    __shared__ float gb[CL_];
    int c = blockIdx.x, b = blockIdx.y, d = threadIdx.x;
    #pragma unroll
    for (int m = 0; m < 4; ++m){
        int idx = threadIdx.x + 256 * m;
        int ll = idx >> 5, pp = idx & 31;
        int srow = c * CL_ + ll - 1;
        cs [ll][pp] = (srow >= 0) ? ck[(size_t)(b * L_ + srow) * P_ + pp] : 0.0f;
        ss_[ll][pp] = (srow >= 0) ? sk[(size_t)(b * L_ + srow) * P_ + pp] : 0.0f;
    }
    if (threadIdx.x < CL_) gb[threadIdx.x] = vg[b * L_ + c * CL_ + threadIdx.x];
    __syncthreads();
    float Sr[32], Si[32];
    #pragma unroll
    for (int p = 0; p < 32; ++p){ Sr[p] = 0.f; Si[p] = 0.f; }
    for (int l = 0; l < CL_; ++l){
        float vv = kvv[(size_t)(b * L_ + c * CL_ + l) * D_ + d] * gb[l];
        #pragma unroll
        for (int pq = 0; pq < 8; ++pq){
            float4 cc = *(const float4*)&cs [l][pq * 4];
            float4 ss = *(const float4*)&ss_[l][pq * 4];
            Sr[pq*4+0] = fmaf(cc.x, vv, Sr[pq*4+0]); Si[pq*4+0] = fmaf(ss.x, vv, Si[pq*4+0]);
            Sr[pq*4+1] = fmaf(cc.y, vv, Sr[pq*4+1]); Si[pq*4+1] = fmaf(ss.y, vv, Si[pq*4+1]);
            Sr[pq*4+2] = fmaf(cc.z, vv, Sr[pq*4+2]); Si[pq*4+2] = fmaf(ss.z, vv, Si[pq*4+2]);
            Sr[pq*4+3] = fmaf(cc.w, vv, Sr[pq*4+3]); Si[pq*4+3] = fmaf(ss.w, vv, Si[pq*4+3]);
        }
    }
    #pragma unroll
    for (int p = 0; p < 32; ++p){
        size_t o = (size_t)((b * NC_ + c) * P_ + p) * D_ + d;
        Sr_[o] = Sr[p]; Si_[o] = Si[p];
    }
}

// ---------------- K4b: kv-memory retrieve + blend (in place) ----------------
__global__ __launch_bounds__(256) void k_kv_retrieve(
    const float* __restrict__ ck, const float* __restrict__ sk,
    const float* __restrict__ kvv, const float* __restrict__ vg,
    const float* __restrict__ rnorm,
    const float* __restrict__ Sr_, const float* __restrict__ Si_,
    const float* __restrict__ blend0, const float* __restrict__ blend1,
    float* __restrict__ blended)
{
    __shared__ float cs[CL_][32], ss_[CL_][32], cq[CL_][32], sq[CL_][32];
    __shared__ float gb[CL_], rn[CL_], w0[CL_], w1[CL_];
    int c = blockIdx.x, b = blockIdx.y, d = threadIdx.x;
    #pragma unroll
    for (int m = 0; m < 4; ++m){
        int idx = threadIdx.x + 256 * m;
        int ll = idx >> 5, pp = idx & 31;
        int srow = c * CL_ + ll - 1;
        cs [ll][pp] = (srow >= 0) ? ck[(size_t)(b * L_ + srow) * P_ + pp] : 0.0f;
        ss_[ll][pp] = (srow >= 0) ? sk[(size_t)(b * L_ + srow) * P_ + pp] : 0.0f;
        cq [ll][pp] = ck[(size_t)(b * L_ + c * CL_ + ll) * P_ + pp];
        sq [ll][pp] = sk[(size_t)(b * L_ + c * CL_ + ll) * P_ + pp];
    }
    if (threadIdx.x < CL_){
        int gl = b * L_ + c * CL_ + threadIdx.x;
        gb[threadIdx.x] = vg[gl];
        rn[threadIdx.x] = rnorm[gl];
        w0[threadIdx.x] = blend0[gl];
        w1[threadIdx.x] = blend1[gl];
    }
    __syncthreads();
    float Sr[32], Si[32];
    #pragma unroll
    for (int p = 0; p < 32; ++p){
        size_t o = (size_t)((b * NC_ + c) * P_ + p) * D_ + d;
        Sr[p] = Sr_[o]; Si[p] = Si_[o];
    }
    for (int l = 0; l < CL_; ++l){
        float vv = kvv[(size_t)(b * L_ + c * CL_ + l) * D_ + d] * gb[l];
        float ret = 0.f;
        #pragma unroll
        for (int pq = 0; pq < 8; ++pq){
            float4 cc = *(const float4*)&cs [l][pq * 4];
            float4 ss = *(const float4*)&ss_[l][pq * 4];
            float4 qc = *(const float4*)&cq [l][pq * 4];
            float4 qs = *(const float4*)&sq [l][pq * 4];
            Sr[pq*4+0] = fmaf(cc.x, vv, Sr[pq*4+0]); ret = fmaf(qc.x, Sr[pq*4+0], ret);
            Si[pq*4+0] = fmaf(ss.x, vv, Si[pq*4+0]); ret = fmaf(qs.x, Si[pq*4+0], ret);
            Sr[pq*4+1] = fmaf(cc.y, vv, Sr[pq*4+1]); ret = fmaf(qc.y, Sr[pq*4+1], ret);
            Si[pq*4+1] = fmaf(ss.y, vv, Si[pq*4+1]); ret = fmaf(qs.y, Si[pq*4+1], ret);
            Sr[pq*4+2] = fmaf(cc.z, vv, Sr[pq*4+2]); ret = fmaf(qc.z, Sr[pq*4+2], ret);
            Si[pq*4+2] = fmaf(ss.z, vv, Si[pq*4+2]); ret = fmaf(qs.z, Si[pq*4+2], ret);
            Sr[pq*4+3] = fmaf(cc.w, vv, Sr[pq*4+3]); ret = fmaf(qc.w, Sr[pq*4+3], ret);
            Si[pq*4+3] = fmaf(ss.w, vv, Si[pq*4+3]); ret = fmaf(qs.w, Si[pq*4+3], ret);
        }
        ret *= rn[l];
        size_t o = (size_t)(b * L_ + c * CL_ + l) * D_ + d;
        blended[o] = w0[l] * blended[o] + w1[l] * ret;
    }
}

// ---------------- K9: LN -> r1(gelu) -> r2 -> LN -> out, 8 tokens/block, 1024 threads ----
__global__ __launch_bounds__(1024) void k_final(
    const float* __restrict__ x, const float* __restrict__ blended,
    const float* __restrict__ ln_r_g, const float* __restrict__ ln_r_b,
    const float* __restrict__ w_r1, const float* __restrict__ b_r1,
    const float* __restrict__ w_r2, const float* __restrict__ b_r2,
    const float* __restrict__ ln_o_g, const float* __restrict__ ln_o_b,
    const float* __restrict__ w_out, const float* __restrict__ b_out,
    float* __restrict__ out)
{
    __shared__ float zT[256][12];       // [k][t]
    __shared__ float h2T[512][12];      // [j][t]
    __shared__ float pbuf[3 * 256 * 9]; // padded partial-sum buffer (reused)
    __shared__ float red[8][17], red2[8][17];
    __shared__ float mu[8], rs[8];

    const int i  = threadIdx.x;
    const int b  = blockIdx.x >> 8;
    const int l0 = (blockIdx.x & 255) * 8;

    #pragma unroll
    for (int m = 0; m < 2; ++m){
        int e = i + 1024 * m;
        int t = e >> 8, d2 = e & 255;
        zT[d2][t] = blended[(size_t)(b * L_ + l0 + t) * D_ + d2];
    }
    __syncthreads();

    // ---- LN1 stats ----
    if (i < 128){
        int t = i >> 4, c = i & 15;
        float s = 0.f, s2 = 0.f;
        #pragma unroll
        for (int m = 0; m < 16; ++m){ float v = zT[c + 16 * m][t]; s += v; s2 += v * v; }
        red[t][c] = s; red2[t][c] = s2;
    }
    __syncthreads();
    if (i < 8){
        float s = 0.f, s2 = 0.f;
        #pragma unroll
        for (int c = 0; c < 16; ++c){ s += red[i][c]; s2 += red2[i][c]; }
        float mean = s * (1.0f / 256.0f);
        float var  = s2 * (1.0f / 256.0f) - mean * mean;
        mu[i] = mean; rs[i] = rsqrtf(var + 1e-5f);
    }
    __syncthreads();
    {
        int d2 = i & 255;
        float g = ln_r_g[d2], bb = ln_r_b[d2];
        #pragma unroll
        for (int m = 0; m < 2; ++m){
            int e = i + 1024 * m;
            int t = e >> 8;
            zT[d2][t] = (zT[d2][t] - mu[t]) * rs[t] * g + bb;
        }
    }
    __syncthreads();

    // ---- r1: 512 cols, 2-way k-split ----
    {
        int half = i >> 9, j = i & 511;
        int k0 = half * 128;
        float h[8];
        #pragma unroll
        for (int t = 0; t < 8; ++t) h[t] = 0.f;
        for (int k = k0; k < k0 + 128; ++k){
            float za[8];
            *(float4*)&za[0] = *(const float4*)&zT[k][0];
            *(float4*)&za[4] = *(const float4*)&zT[k][4];
            float w = w_r1[k * 512 + j];
            #pragma unroll
            for (int t = 0; t < 8; ++t) h[t] = fmaf(za[t], w, h[t]);
        }
        if (half == 1){
            #pragma unroll
            for (int t = 0; t < 8; ++t) pbuf[j * 9 + t] = h[t];
        }
        __syncthreads();
        if (half == 0){
            float bb = b_r1[j];
            #pragma unroll
            for (int t = 0; t < 8; ++t) h2T[j][t] = gelu_exact(h[t] + pbuf[j * 9 + t] + bb);
        }
    }
    __syncthreads();

    // ---- r2: 256 cols, 4-way j-split ----
    {
        int q = i >> 8, dcol = i & 255;
        int j0 = q * 128;
        float a[8];
        #pragma unroll
        for (int t = 0; t < 8; ++t) a[t] = 0.f;
        for (int j = j0; j < j0 + 128; ++j){
            float ha[8];
            *(float4*)&ha[0] = *(const float4*)&h2T[j][0];
            *(float4*)&ha[4] = *(const float4*)&h2T[j][4];
            float w = w_r2[j * 256 + dcol];
            #pragma unroll
            for (int t = 0; t < 8; ++t) a[t] = fmaf(ha[t], w, a[t]);
        }
        if (q > 0){
            #pragma unroll
            for (int t = 0; t < 8; ++t) pbuf[((q - 1) * 256 + dcol) * 9 + t] = a[t];
        }
        __syncthreads();
        if (q == 0){
            float bb = b_r2[dcol];
            #pragma unroll
            for (int t = 0; t < 8; ++t){
                float s = a[t] + bb;
                s += pbuf[(0 * 256 + dcol) * 9 + t];
                s += pbuf[(1 * 256 + dcol) * 9 + t];
                s += pbuf[(2 * 256 + dcol) * 9 + t];
                zT[dcol][t] = s;
            }
        }
    }
    __syncthreads();

    // ---- LN2 stats ----
    if (i < 128){
        int t = i >> 4, c = i & 15;
        float s = 0.f, s2 = 0.f;
        #pragma unroll
        for (int m = 0; m < 16; ++m){ float v = zT[c + 16 * m][t]; s += v; s2 += v * v; }
        red[t][c] = s; red2[t][c] = s2;
    }
    __syncthreads();
    if (i < 8){
        float s = 0.f, s2 = 0.f;
        #pragma unroll
        for (int c = 0; c < 16; ++c){ s += red[i][c]; s2 += red2[i][c]; }
        float mean = s * (1.0f / 256.0f);
        float var  = s2 * (1.0f / 256.0f) - mean * mean;
        mu[i] = mean; rs[i] = rsqrtf(var + 1e-5f);
    }
    __syncthreads();
    {
        int d2 = i & 255;
        float g = ln_o_g[d2], bb = ln_o_b[d2];
        #pragma unroll
        for (int m = 0; m < 2; ++m){
            int e = i + 1024 * m;
            int t = e >> 8;
            zT[d2][t] = (zT[d2][t] - mu[t]) * rs[t] * g + bb;
        }
    }
    __syncthreads();

    // ---- out: 256 cols, 4-way k-split + residual ----
    {
        int q = i >> 8, dcol = i & 255;
        int k0 = q * 64;
        float a[8];
        #pragma unroll
        for (int t = 0; t < 8; ++t) a[t] = 0.f;
        for (int k = k0; k < k0 + 64; ++k){
            float za[8];
            *(float4*)&za[0] = *(const float4*)&zT[k][0];
            *(float4*)&za[4] = *(const float4*)&zT[k][4];
            float w = w_out[k * 256 + dcol];
            #pragma unroll
            for (int t = 0; t < 8; ++t) a[t] = fmaf(za[t], w, a[t]);
        }
        if (q > 0){
            #pragma unroll
            for (int t = 0; t < 8; ++t) pbuf[((q - 1) * 256 + dcol) * 9 + t] = a[t];
        }
        __syncthreads();
        if (q == 0){
            float bo = b_out[dcol];
            #pragma unroll
            for (int t = 0; t < 8; ++t){
                float s = a[t] + bo;
                s += pbuf[(0 * 256 + dcol) * 9 + t];
                s += pbuf[(1 * 256 + dcol) * 9 + t];
                s += pbuf[(2 * 256 + dcol) * 9 + t];
                size_t o = (size_t)(b * L_ + l0 + t) * D_ + dcol;
                out[o] = x[o] + s;
            }
        }
    }
}

extern "C" void kernel_launch(void* const* d_in, const int* in_sizes, int n_in,
                              void* d_out, int out_size, void* d_ws, size_t ws_size,
                              hipStream_t stream) {
    const float* x          = (const float*)d_in[0];
    const float* pos_phases = (const float*)d_in[1];
    const float* w_pv       = (const float*)d_in[2];
    const float* b_pv       = (const float*)d_in[3];
    const float* w_key      = (const float*)d_in[4];
    const float* b_key      = (const float*)d_in[5];
    const float* w_kv       = (const float*)d_in[6];
    const float* b_kv       = (const float*)d_in[7];
    const float* w_vg1      = (const float*)d_in[8];
    const float* b_vg1      = (const float*)d_in[9];
    const float* w_vg2      = (const float*)d_in[10];
    const float* b_vg2      = (const float*)d_in[11];
    const float* w_bg1      = (const float*)d_in[12];
    const float* b_bg1      = (const float*)d_in[13];
    const float* w_bg2      = (const float*)d_in[14];
    const float* b_bg2      = (const float*)d_in[15];
    const float* ln_r_g     = (const float*)d_in[16];
    const float* ln_r_b     = (const float*)d_in[17];
    const float* w_r1       = (const float*)d_in[18];
    const float* b_r1       = (const float*)d_in[19];
    const float* w_r2       = (const float*)d_in[20];
    const float* b_r2       = (const float*)d_in[21];
    const float* ln_o_g     = (const float*)d_in[22];
    const float* ln_o_b     = (const float*)d_in[23];
    const float* w_out      = (const float*)d_in[24];
    const float* b_out      = (const float*)d_in[25];
    float* out = (float*)d_out;

    float* ws = (float*)d_ws;
    size_t off = 0;
    float* cpos   = ws + off; off += (size_t)L_ * P_;
    float* spos   = ws + off; off += (size_t)L_ * P_;
    float* pv     = ws + off; off += (size_t)B_ * L_ * D_;
    float* kvv    = ws + off; off += (size_t)B_ * L_ * D_;
    float* ck     = ws + off; off += (size_t)B_ * L_ * P_;
    float* sk     = ws + off; off += (size_t)B_ * L_ * P_;
    float* vg     = ws + off; off += (size_t)B_ * L_;
    float* rnorm  = ws + off; off += (size_t)B_ * L_;
    float* blend0 = ws + off; off += (size_t)B_ * L_;
    float* blend1 = ws + off; off += (size_t)B_ * L_;
    float* blended= ws + off; off += (size_t)B_ * L_ * D_;   // pos_ret, then blended in place
    float* posSr  = ws + off; off += (size_t)B_ * NC_ * P_ * D_;
    float* posSi  = ws + off; off += (size_t)B_ * NC_ * P_ * D_;
    float* kvSr   = ws + off; off += (size_t)B_ * NC_ * P_ * D_;
    float* kvSi   = ws + off; off += (size_t)B_ * NC_ * P_ * D_;

    k_sincos<<<(L_ * P_) / 256, 256, 0, stream>>>(pos_phases, cpos, spos);
    k_proj<<<B_ * 256, 1024, 0, stream>>>(x,
        w_pv, b_pv, w_key, b_key, w_kv, b_kv, w_vg1, b_vg1, w_vg2, b_vg2,
        w_bg1, b_bg1, w_bg2, b_bg2,
        pv, kvv, ck, sk, vg, blend0, blend1);
    k_gatecum<<<B_, 256, 0, stream>>>(vg, rnorm);

    dim3 gs(NC_, B_);
    k_pos_chunksum<<<gs, 256, 0, stream>>>(cpos, spos, pv, posSr, posSi);
    k_prefix<<<(2 * B_ * P_ * D_) / 256, 256, 0, stream>>>(posSr, posSi);
    k_pos_retrieve<<<gs, 256, 0, stream>>>(cpos, spos, pv, posSr, posSi, blended);

    k_kv_chunksum<<<gs, 256, 0, stream>>>(ck, sk, kvv, vg, kvSr, kvSi);
    k_prefix<<<(2 * B_ * P_ * D_) / 256, 256, 0, stream>>>(kvSr, kvSi);
    k_kv_retrieve<<<gs, 256, 0, stream>>>(ck, sk, kvv, vg, rnorm, kvSr, kvSi,
                                          blend0, blend1, blended);

    k_final<<<B_ * 256, 1024, 0, stream>>>(x, blended,
        ln_r_g, ln_r_b, w_r1, b_r1, w_r2, b_r2, ln_o_g, ln_o_b, w_out, b_out, out);
}

// Round 3
// 175.363 us; speedup vs baseline: 1.7277x; 1.7090x over previous
//
#include <hip/hip_runtime.h>
#include <math.h>

#define B_ 2
#define L_ 2048
#define D_ 256
#define P_ 32
#define NC_ 64
#define CL_ 32

#define INV_SQRT_P 0.17677669529663687f   // 1/sqrt(32)
#define PI_F 3.14159265358979323846f

typedef __attribute__((ext_vector_type(8))) short bf16x8;
typedef __attribute__((ext_vector_type(4))) float f32x4;

__device__ __forceinline__ float gelu_exact(float x){
    return 0.5f * x * (1.0f + erff(x * 0.70710678118654752f));
}

__device__ __forceinline__ unsigned short f2bf(float f){
    unsigned int u = __float_as_uint(f);
    u += 0x7FFFu + ((u >> 16) & 1u);     // round-to-nearest-even
    return (unsigned short)(u >> 16);
}

// ---------------- K0: sincos of pos_phases (L,P) ----------------
__global__ void k_sincos(const float* __restrict__ ph, float* __restrict__ cpos,
                         float* __restrict__ spos){
    int idx = blockIdx.x * 256 + threadIdx.x;
    float s, c;
    sincosf(ph[idx], &s, &c);
    cpos[idx] = c;
    spos[idx] = s;
}

// ---------------- prep: weights -> bf16 MFMA-B fragment order ----------------
// dst layout per matrix: ((kt*NT + nt)*64 + lane)*8 + j
// element = W[kt*32 + 8*(lane>>4) + j][nt*16 + (lane&15)]
// segments (ushort offsets): wpv 0, wkv 65536, wvg1 131072, wbg1 262144,
//                            wr1 294912, wr2 425984, wout 557056 ; total 622592
__global__ __launch_bounds__(256) void k_prep_w(
    const float* __restrict__ w_pv, const float* __restrict__ w_kv,
    const float* __restrict__ w_vg1, const float* __restrict__ w_bg1,
    const float* __restrict__ w_r1, const float* __restrict__ w_r2,
    const float* __restrict__ w_out, unsigned short* __restrict__ dst)
{
    int id = blockIdx.x * 256 + threadIdx.x;   // 0..622591
    const float* src; int N; int local;
    if (id < 65536)       { src = w_pv;  N = 256; local = id; }
    else if (id < 131072) { src = w_kv;  N = 256; local = id - 65536; }
    else if (id < 262144) { src = w_vg1; N = 256; local = id - 131072; }
    else if (id < 294912) { src = w_bg1; N = 128; local = id - 262144; }
    else if (id < 425984) { src = w_r1;  N = 512; local = id - 294912; }
    else if (id < 557056) { src = w_r2;  N = 256; local = id - 425984; }
    else                  { src = w_out; N = 256; local = id - 557056; }
    int j = local & 7, lane = (local >> 3) & 63, tile = local >> 9;
    int NT = N >> 4;
    int nt = tile % NT, kt = tile / NT;
    int row = kt * 32 + ((lane >> 4) << 3) + j;
    int col = nt * 16 + (lane & 15);
    dst[id] = f2bf(src[(size_t)row * N + col]);
}

// ---------------- prep: x (and shifted x) -> bf16 MFMA-A fragment order ------
// layout: (((b*128 + lt)*8 + kt)*64 + lane)*8 + j
// element = x[b, lt*16 + (lane&15) (-1 if shifted), kt*32 + 8*(lane>>4) + j]
__global__ __launch_bounds__(256) void k_prep_x(const float* __restrict__ x,
                                                unsigned short* __restrict__ xbf,
                                                unsigned short* __restrict__ xsbf)
{
    int id = blockIdx.x * 256 + threadIdx.x;   // 0..2*2^20-1
    int shifted = id >> 20;
    int local = id & 1048575;
    int j = local & 7, lane = (local >> 3) & 63;
    int kt = (local >> 9) & 7, lt = (local >> 12) & 127, b = local >> 19;
    int k = kt * 32 + ((lane >> 4) << 3) + j;
    int l = lt * 16 + (lane & 15);
    float v;
    if (shifted) v = (l >= 1) ? x[(size_t)(b * L_ + l - 1) * D_ + k] : 0.0f;
    else         v = x[(size_t)(b * L_ + l) * D_ + k];
    (shifted ? xsbf : xbf)[local] = f2bf(v);
}

// ---------------- K1: fused projections via MFMA, 16 tokens/block, 8 waves ----
__global__ __launch_bounds__(512) void k_proj(
    const float* __restrict__ x,
    const unsigned short* __restrict__ wq,
    const float* __restrict__ b_pv, const float* __restrict__ b_kv,
    const float* __restrict__ b_vg1,
    const float* __restrict__ w_vg2, const float* __restrict__ b_vg2,
    const float* __restrict__ b_bg1,
    const float* __restrict__ w_bg2, const float* __restrict__ b_bg2,
    const float* __restrict__ w_key, const float* __restrict__ b_key,
    const unsigned short* __restrict__ xbf, const unsigned short* __restrict__ xsbf,
    float* __restrict__ pv, float* __restrict__ kvv,
    float* __restrict__ ck, float* __restrict__ sk,
    float* __restrict__ vg, float* __restrict__ blend0, float* __restrict__ blend1)
{
    __shared__ float hbuf[16][257];
    __shared__ float bhbuf[16][129];
    __shared__ float red[16][17], red2[16][17], red3[16][17];

    const int i = threadIdx.x;
    const int lane = i & 63, w = i >> 6;
    const int b = blockIdx.x >> 7, lt = blockIdx.x & 127, l0 = lt * 16;
    const int g = lane >> 4, c = lane & 15;

    // preload A fragments (x and shifted-x), 8 K-steps each
    bf16x8 xa[8], xs[8];
    {
        const unsigned short* base  = xbf  + (size_t)((b * 128 + lt) * 8) * 512 + lane * 8;
        const unsigned short* bases = xsbf + (size_t)((b * 128 + lt) * 8) * 512 + lane * 8;
        #pragma unroll
        for (int kt = 0; kt < 8; ++kt){
            xa[kt] = *(const bf16x8*)(base  + kt * 512);
            xs[kt] = *(const bf16x8*)(bases + kt * 512);
        }
    }

    const unsigned short* wpv  = wq;
    const unsigned short* wkv  = wq + 65536;
    const unsigned short* wvg1 = wq + 131072;
    const unsigned short* wbg1 = wq + 262144;

    // 56 tile jobs: [0,16) pv, [16,32) kv, [32,48) vg1 (K=512), [48,56) bg1
    for (int jb = w; jb < 56; jb += 8){
        f32x4 acc = {0.f, 0.f, 0.f, 0.f};
        if (jb < 16){
            int nt = jb;
            #pragma unroll
            for (int kt = 0; kt < 8; ++kt){
                bf16x8 bf = *(const bf16x8*)(wpv + (kt * 16 + nt) * 512 + lane * 8);
                acc = __builtin_amdgcn_mfma_f32_16x16x32_bf16(xa[kt], bf, acc, 0, 0, 0);
            }
            float bb = b_pv[nt * 16 + c];
            #pragma unroll
            for (int r = 0; r < 4; ++r)
                pv[(size_t)(b * L_ + l0 + 4 * g + r) * D_ + nt * 16 + c] = acc[r] + bb;
        } else if (jb < 32){
            int nt = jb - 16;
            #pragma unroll
            for (int kt = 0; kt < 8; ++kt){
                bf16x8 bf = *(const bf16x8*)(wkv + (kt * 16 + nt) * 512 + lane * 8);
                acc = __builtin_amdgcn_mfma_f32_16x16x32_bf16(xa[kt], bf, acc, 0, 0, 0);
            }
            float bb = b_kv[nt * 16 + c];
            #pragma unroll
            for (int r = 0; r < 4; ++r)
                kvv[(size_t)(b * L_ + l0 + 4 * g + r) * D_ + nt * 16 + c] = acc[r] + bb;
        } else if (jb < 48){
            int nt = jb - 32;
            #pragma unroll
            for (int kt = 0; kt < 8; ++kt){
                bf16x8 bf = *(const bf16x8*)(wvg1 + (kt * 16 + nt) * 512 + lane * 8);
                acc = __builtin_amdgcn_mfma_f32_16x16x32_bf16(xa[kt], bf, acc, 0, 0, 0);
            }
            #pragma unroll
            for (int kt = 8; kt < 16; ++kt){
                bf16x8 bf = *(const bf16x8*)(wvg1 + (kt * 16 + nt) * 512 + lane * 8);
                acc = __builtin_amdgcn_mfma_f32_16x16x32_bf16(xs[kt - 8], bf, acc, 0, 0, 0);
            }
            float bb = b_vg1[nt * 16 + c];
            #pragma unroll
            for (int r = 0; r < 4; ++r)
                hbuf[4 * g + r][nt * 16 + c] = gelu_exact(acc[r] + bb);
        } else {
            int nt = jb - 48;
            #pragma unroll
            for (int kt = 0; kt < 8; ++kt){
                bf16x8 bf = *(const bf16x8*)(wbg1 + (kt * 8 + nt) * 512 + lane * 8);
                acc = __builtin_amdgcn_mfma_f32_16x16x32_bf16(xa[kt], bf, acc, 0, 0, 0);
            }
            float bb = b_bg1[nt * 16 + c];
            #pragma unroll
            for (int r = 0; r < 4; ++r)
                bhbuf[4 * g + r][nt * 16 + c] = gelu_exact(acc[r] + bb);
        }
    }

    // key phases -> phasors (fp32 path; 16 tokens x 32 p = 512 threads)
    {
        int t = i >> 5, p = i & 31;
        const float* xrow = x + (size_t)(b * L_ + l0 + t) * D_;
        float a = 0.f;
        for (int k = 0; k < 256; ++k)
            a = fmaf(xrow[k], w_key[k * 32 + p], a);
        a = tanhf(a + b_key[p]) * PI_F;
        float s, cc;
        sincosf(a, &s, &cc);
        ck[(size_t)(b * L_ + l0 + t) * P_ + p] = cc;
        sk[(size_t)(b * L_ + l0 + t) * P_ + p] = s;
    }
    __syncthreads();

    // vg2 (threads 0..255) and bg2 (threads 256..511) partial reductions
    if (i < 256){
        int t = i >> 4, c2 = i & 15;
        float s = 0.f;
        #pragma unroll
        for (int m = 0; m < 16; ++m){ int dd = c2 + 16 * m; s += hbuf[t][dd] * w_vg2[dd]; }
        red[t][c2] = s;
    } else {
        int ii = i - 256;
        int t = ii >> 4, c2 = ii & 15;
        float s0 = 0.f, s1 = 0.f;
        #pragma unroll
        for (int m = 0; m < 8; ++m){
            int jj = c2 + 16 * m;
            float v = bhbuf[t][jj];
            s0 += v * w_bg2[jj * 2 + 0];
            s1 += v * w_bg2[jj * 2 + 1];
        }
        red2[t][c2] = s0; red3[t][c2] = s1;
    }
    __syncthreads();
    if (i < 16){
        float s = 0.f;
        #pragma unroll
        for (int c2 = 0; c2 < 16; ++c2) s += red[i][c2];
        s += b_vg2[0];
        vg[b * L_ + l0 + i] = 1.0f / (1.0f + expf(-s));
    } else if (i < 32){
        int t = i - 16;
        float s0 = 0.f, s1 = 0.f;
        #pragma unroll
        for (int c2 = 0; c2 < 16; ++c2){ s0 += red2[t][c2]; s1 += red3[t][c2]; }
        s0 += b_bg2[0]; s1 += b_bg2[1];
        float mx = fmaxf(s0, s1);
        float e0 = expf(s0 - mx), e1 = expf(s1 - mx);
        float inv = 1.0f / (e0 + e1);
        blend0[b * L_ + l0 + t] = e0 * inv;
        blend1[b * L_ + l0 + t] = e1 * inv;
    }
}

// ---------------- K5: gate cumsum -> rnorm ----------------
__global__ __launch_bounds__(256) void k_gatecum(const float* __restrict__ vg,
                                                 float* __restrict__ rnorm){
    int b = blockIdx.x, i = threadIdx.x;
    float loc[8];
    float run = 0.f;
    #pragma unroll
    for (int m = 0; m < 8; ++m){ run += vg[b * L_ + i * 8 + m]; loc[m] = run; }
    __shared__ float part[256];
    part[i] = run;
    __syncthreads();
    for (int off = 1; off < 256; off <<= 1){
        float t = (i >= off) ? part[i - off] : 0.0f;
        __syncthreads();
        part[i] += t;
        __syncthreads();
    }
    float excl = part[i] - run;
    #pragma unroll
    for (int m = 0; m < 8; ++m){
        float gc = fmaxf(excl + loc[m], 1.0f);
        rnorm[b * L_ + i * 8 + m] = rsqrtf(gc) * INV_SQRT_P;
    }
}

// ---------------- K2a: pos-memory chunk sums ----------------
__global__ __launch_bounds__(256) void k_pos_chunksum(
    const float* __restrict__ cpos, const float* __restrict__ spos,
    const float* __restrict__ pv, float* __restrict__ Sr_, float* __restrict__ Si_)
{
    __shared__ float cp[CL_][32], sp[CL_][32];
    int c = blockIdx.x, b = blockIdx.y, d = threadIdx.x;
    #pragma unroll
    for (int m = 0; m < 4; ++m){
        int idx = threadIdx.x + 256 * m;
        int ll = idx >> 5, pp = idx & 31;
        cp[ll][pp] = cpos[(c * CL_ + ll) * P_ + pp];
        sp[ll][pp] = spos[(c * CL_ + ll) * P_ + pp];
    }
    __syncthreads();
    float Sr[32], Si[32];
    #pragma unroll
    for (int p = 0; p < 32; ++p){ Sr[p] = 0.f; Si[p] = 0.f; }
    for (int l = 0; l < CL_; ++l){
        float v = pv[(size_t)(b * L_ + c * CL_ + l) * D_ + d];
        #pragma unroll
        for (int pq = 0; pq < 8; ++pq){
            float4 cc = *(const float4*)&cp[l][pq * 4];
            float4 ss = *(const float4*)&sp[l][pq * 4];
            Sr[pq*4+0] = fmaf(cc.x, v, Sr[pq*4+0]); Si[pq*4+0] = fmaf(ss.x, v, Si[pq*4+0]);
            Sr[pq*4+1] = fmaf(cc.y, v, Sr[pq*4+1]); Si[pq*4+1] = fmaf(ss.y, v, Si[pq*4+1]);
            Sr[pq*4+2] = fmaf(cc.z, v, Sr[pq*4+2]); Si[pq*4+2] = fmaf(ss.z, v, Si[pq*4+2]);
            Sr[pq*4+3] = fmaf(cc.w, v, Sr[pq*4+3]); Si[pq*4+3] = fmaf(ss.w, v, Si[pq*4+3]);
        }
    }
    #pragma unroll
    for (int p = 0; p < 32; ++p){
        size_t o = (size_t)((b * NC_ + c) * P_ + p) * D_ + d;
        Sr_[o] = Sr[p]; Si_[o] = Si[p];
    }
}

// ---------------- K3: in-place exclusive prefix over chunks ----------------
__global__ __launch_bounds__(256) void k_prefix(float* __restrict__ Ar, float* __restrict__ Ai){
    int gid = blockIdx.x * 256 + threadIdx.x;
    const int NPD = B_ * P_ * D_;
    float* A = (gid < NPD) ? Ar : Ai;
    int g = (gid < NPD) ? gid : gid - NPD;
    int b = g >> 13;
    int pd = g & 8191;
    float run = 0.f;
    for (int c = 0; c < NC_; ++c){
        size_t idx = (size_t)(b * NC_ + c) * (P_ * D_) + pd;
        float t = A[idx];
        A[idx] = run;
        run += t;
    }
}

// ---------------- K4a: pos-memory retrieve ----------------
__global__ __launch_bounds__(256) void k_pos_retrieve(
    const float* __restrict__ cpos, const float* __restrict__ spos,
    const float* __restrict__ pv,
    const float* __restrict__ Sr_, const float* __restrict__ Si_,
    float* __restrict__ pos_ret)
{
    __shared__ float cp[CL_][32], sp[CL_][32];
    int c = blockIdx.x, b = blockIdx.y, d = threadIdx.x;
    #pragma unroll
    for (int m = 0; m < 4; ++m){
        int idx = threadIdx.x + 256 * m;
        int ll = idx >> 5, pp = idx & 31;
        cp[ll][pp] = cpos[(c * CL_ + ll) * P_ + pp];
        sp[ll][pp] = spos[(c * CL_ + ll) * P_ + pp];
    }
    __syncthreads();
    float Sr[32], Si[32];
    #pragma unroll
    for (int p = 0; p < 32; ++p){
        size_t o = (size_t)((b * NC_ + c) * P_ + p) * D_ + d;
        Sr[p] = Sr_[o]; Si[p] = Si_[o];
    }
    for (int l = 0; l < CL_; ++l){
        float v = pv[(size_t)(b * L_ + c * CL_ + l) * D_ + d];
        float ret = 0.f;
        #pragma unroll
        for (int pq = 0; pq < 8; ++pq){
            float4 cc = *(const float4*)&cp[l][pq * 4];
            float4 ss = *(const float4*)&sp[l][pq * 4];
            Sr[pq*4+0] = fmaf(cc.x, v, Sr[pq*4+0]); ret = fmaf(cc.x, Sr[pq*4+0], ret);
            Si[pq*4+0] = fmaf(ss.x, v, Si[pq*4+0]); ret = fmaf(ss.x, Si[pq*4+0], ret);
            Sr[pq*4+1] = fmaf(cc.y, v, Sr[pq*4+1]); ret = fmaf(cc.y, Sr[pq*4+1], ret);
            Si[pq*4+1] = fmaf(ss.y, v, Si[pq*4+1]); ret = fmaf(ss.y, Si[pq*4+1], ret);
            Sr[pq*4+2] = fmaf(cc.z, v, Sr[pq*4+2]); ret = fmaf(cc.z, Sr[pq*4+2], ret);
            Si[pq*4+2] = fmaf(ss.z, v, Si[pq*4+2]); ret = fmaf(ss.z, Si[pq*4+2], ret);
            Sr[pq*4+3] = fmaf(cc.w, v, Sr[pq*4+3]); ret = fmaf(cc.w, Sr[pq*4+3], ret);
            Si[pq*4+3] = fmaf(ss.w, v, Si[pq*4+3]); ret = fmaf(ss.w, Si[pq*4+3], ret);
        }
        pos_ret[(size_t)(b * L_ + c * CL_ + l) * D_ + d] = ret * INV_SQRT_P;
    }
}

// ---------------- K2b: kv-memory chunk sums ----------------
__global__ __launch_bounds__(256) void k_kv_chunksum(
    const float* __restrict__ ck, const float* __restrict__ sk,
    const float* __restrict__ kvv, const float* __restrict__ vg,
    float* __restrict__ Sr_, float* __restrict__ Si_)
{
    __shared__ float cs[CL_][32], ss_[CL_][32];
    __shared__ float gb[CL_];
    int c = blockIdx.x, b = blockIdx.y, d = threadIdx.x;
    #pragma unroll
    for (int m = 0; m < 4; ++m){
        int idx = threadIdx.x + 256 * m;
        int ll = idx >> 5, pp = idx & 31;
        int srow = c * CL_ + ll - 1;
        cs [ll][pp] = (srow >= 0) ? ck[(size_t)(b * L_ + srow) * P_ + pp] : 0.0f;
        ss_[ll][pp] = (srow >= 0) ? sk[(size_t)(b * L_ + srow) * P_ + pp] : 0.0f;
    }
    if (threadIdx.x < CL_) gb[threadIdx.x] = vg[b * L_ + c * CL_ + threadIdx.x];
    __syncthreads();
    float Sr[32], Si[32];
    #pragma unroll
    for (int p = 0; p < 32; ++p){ Sr[p] = 0.f; Si[p] = 0.f; }
    for (int l = 0; l < CL_; ++l){
        float vv = kvv[(size_t)(b * L_ + c * CL_ + l) * D_ + d] * gb[l];
        #pragma unroll
        for (int pq = 0; pq < 8; ++pq){
            float4 cc = *(const float4*)&cs [l][pq * 4];
            float4 ss = *(const float4*)&ss_[l][pq * 4];
            Sr[pq*4+0] = fmaf(cc.x, vv, Sr[pq*4+0]); Si[pq*4+0] = fmaf(ss.x, vv, Si[pq*4+0]);
            Sr[pq*4+1] = fmaf(cc.y, vv, Sr[pq*4+1]); Si[pq*4+1] = fmaf(ss.y, vv, Si[pq*4+1]);
            Sr[pq*4+2] = fmaf(cc.z, vv, Sr[pq*4+2]); Si[pq*4+2] = fmaf(ss.z, vv, Si[pq*4+2]);
            Sr[pq*4+3] = fmaf(cc.w, vv, Sr[pq*4+3]); Si[pq*4+3] = fmaf(ss.w, vv, Si[pq*4+3]);
        }
    }
    #pragma unroll
    for (int p = 0; p < 32; ++p){
        size_t o = (size_t)((b * NC_ + c) * P_ + p) * D_ + d;
        Sr_[o] = Sr[p]; Si_[o] = Si[p];
    }
}

// ---------------- K4b: kv-memory retrieve + blend (in place) ----------------
__global__ __launch_bounds__(256) void k_kv_retrieve(
    const float* __restrict__ ck, const float* __restrict__ sk,
    const float* __restrict__ kvv, const float* __restrict__ vg,
    const float* __restrict__ rnorm,
    const float* __restrict__ Sr_, const float* __restrict__ Si_,
    const float* __restrict__ blend0, const float* __restrict__ blend1,
    float* __restrict__ blended)
{
    __shared__ float cs[CL_][32], ss_[CL_][32], cq[CL_][32], sq[CL_][32];
    __shared__ float gb[CL_], rn[CL_], w0[CL_], w1[CL_];
    int c = blockIdx.x, b = blockIdx.y, d = threadIdx.x;
    #pragma unroll
    for (int m = 0; m < 4; ++m){
        int idx = threadIdx.x + 256 * m;
        int ll = idx >> 5, pp = idx & 31;
        int srow = c * CL_ + ll - 1;
        cs [ll][pp] = (srow >= 0) ? ck[(size_t)(b * L_ + srow) * P_ + pp] : 0.0f;
        ss_[ll][pp] = (srow >= 0) ? sk[(size_t)(b * L_ + srow) * P_ + pp] : 0.0f;
        cq [ll][pp] = ck[(size_t)(b * L_ + c * CL_ + ll) * P_ + pp];
        sq [ll][pp] = sk[(size_t)(b * L_ + c * CL_ + ll) * P_ + pp];
    }
    if (threadIdx.x < CL_){
        int gl = b * L_ + c * CL_ + threadIdx.x;
        gb[threadIdx.x] = vg[gl];
        rn[threadIdx.x] = rnorm[gl];
        w0[threadIdx.x] = blend0[gl];
        w1[threadIdx.x] = blend1[gl];
    }
    __syncthreads();
    float Sr[32], Si[32];
    #pragma unroll
    for (int p = 0; p < 32; ++p){
        size_t o = (size_t)((b * NC_ + c) * P_ + p) * D_ + d;
        Sr[p] = Sr_[o]; Si[p] = Si_[o];
    }
    for (int l = 0; l < CL_; ++l){
        float vv = kvv[(size_t)(b * L_ + c * CL_ + l) * D_ + d] * gb[l];
        float ret = 0.f;
        #pragma unroll
        for (int pq = 0; pq < 8; ++pq){
            float4 cc = *(const float4*)&cs [l][pq * 4];
            float4 ss = *(const float4*)&ss_[l][pq * 4];
            float4 qc = *(const float4*)&cq [l][pq * 4];
            float4 qs = *(const float4*)&sq [l][pq * 4];
            Sr[pq*4+0] = fmaf(cc.x, vv, Sr[pq*4+0]); ret = fmaf(qc.x, Sr[pq*4+0], ret);
            Si[pq*4+0] = fmaf(ss.x, vv, Si[pq*4+0]); ret = fmaf(qs.x, Si[pq*4+0], ret);
            Sr[pq*4+1] = fmaf(cc.y, vv, Sr[pq*4+1]); ret = fmaf(qc.y, Sr[pq*4+1], ret);
            Si[pq*4+1] = fmaf(ss.y, vv, Si[pq*4+1]); ret = fmaf(qs.y, Si[pq*4+1], ret);
            Sr[pq*4+2] = fmaf(cc.z, vv, Sr[pq*4+2]); ret = fmaf(qc.z, Sr[pq*4+2], ret);
            Si[pq*4+2] = fmaf(ss.z, vv, Si[pq*4+2]); ret = fmaf(qs.z, Si[pq*4+2], ret);
            Sr[pq*4+3] = fmaf(cc.w, vv, Sr[pq*4+3]); ret = fmaf(qc.w, Sr[pq*4+3], ret);
            Si[pq*4+3] = fmaf(ss.w, vv, Si[pq*4+3]); ret = fmaf(qs.w, Si[pq*4+3], ret);
        }
        ret *= rn[l];
        size_t o = (size_t)(b * L_ + c * CL_ + l) * D_ + d;
        blended[o] = w0[l] * blended[o] + w1[l] * ret;
    }
}

// ---------------- K9: LN -> r1 -> r2 -> LN -> out via MFMA, 16 tok/block -----
__global__ __launch_bounds__(512) void k_final(
    const float* __restrict__ x, const float* __restrict__ blended,
    const unsigned short* __restrict__ wq,
    const float* __restrict__ ln_r_g, const float* __restrict__ ln_r_b,
    const float* __restrict__ b_r1, const float* __restrict__ b_r2,
    const float* __restrict__ ln_o_g, const float* __restrict__ ln_o_b,
    const float* __restrict__ b_out,
    float* __restrict__ out)
{
    __shared__ float zbuf[16][257];
    __shared__ __align__(16) unsigned short aA[8][512];
    __shared__ __align__(16) unsigned short aH[16][512];
    __shared__ float red[16][17], red2[16][17];
    __shared__ float mu[16], rs[16];

    const int i = threadIdx.x, lane = i & 63, w = i >> 6;
    const int b = blockIdx.x >> 7, l0 = (blockIdx.x & 127) * 16;
    const int g = lane >> 4, c = lane & 15;
    const unsigned short* wr1  = wq + 294912;
    const unsigned short* wr2  = wq + 425984;
    const unsigned short* wout = wq + 557056;

    // load blended tile 16x256
    {
        int t = i >> 5, c0 = (i & 31) * 8;
        const float* src = blended + (size_t)(b * L_ + l0 + t) * D_ + c0;
        #pragma unroll
        for (int m = 0; m < 8; ++m) zbuf[t][c0 + m] = src[m];
    }
    __syncthreads();

    // LN1 stats
    if (i < 256){
        int t = i >> 4, c2 = i & 15;
        float s = 0.f, s2 = 0.f;
        #pragma unroll
        for (int m = 0; m < 16; ++m){ float v = zbuf[t][c2 + 16 * m]; s += v; s2 += v * v; }
        red[t][c2] = s; red2[t][c2] = s2;
    }
    __syncthreads();
    if (i < 16){
        float s = 0.f, s2 = 0.f;
        #pragma unroll
        for (int c2 = 0; c2 < 16; ++c2){ s += red[i][c2]; s2 += red2[i][c2]; }
        float mean = s * (1.0f / 256.0f);
        float var  = s2 * (1.0f / 256.0f) - mean * mean;
        mu[i] = mean; rs[i] = rsqrtf(var + 1e-5f);
    }
    __syncthreads();

    // repack LN1(z) into bf16 A-frags
    {
        int kt = i >> 6;
        int t2 = lane & 15, kb = kt * 32 + ((lane >> 4) << 3);
        float m_ = mu[t2], r_ = rs[t2];
        bf16x8 v8;
        #pragma unroll
        for (int j = 0; j < 8; ++j){
            int k = kb + j;
            float v = (zbuf[t2][k] - m_) * r_ * ln_r_g[k] + ln_r_b[k];
            v8[j] = (short)f2bf(v);
        }
        *(bf16x8*)&aA[kt][lane * 8] = v8;
    }
    __syncthreads();

    // r1: 32 N-tiles x 8 K-steps; gelu -> aH (A-frags for r2, K=512)
    {
        bf16x8 afr[8];
        #pragma unroll
        for (int kt = 0; kt < 8; ++kt) afr[kt] = *(const bf16x8*)&aA[kt][lane * 8];
        for (int q = 0; q < 4; ++q){
            int nt = w + 8 * q;
            f32x4 acc = {0.f, 0.f, 0.f, 0.f};
            #pragma unroll
            for (int kt = 0; kt < 8; ++kt){
                bf16x8 bf = *(const bf16x8*)(wr1 + (kt * 32 + nt) * 512 + lane * 8);
                acc = __builtin_amdgcn_mfma_f32_16x16x32_bf16(afr[kt], bf, acc, 0, 0, 0);
            }
            float bb = b_r1[nt * 16 + c];
            #pragma unroll
            for (int r = 0; r < 4; ++r){
                float hv = gelu_exact(acc[r] + bb);
                int t = 4 * g + r, hcol = nt * 16 + c;
                int kt2 = hcol >> 5, kk = hcol & 31;
                int lane2 = ((kk >> 3) << 4) + t, j2 = kk & 7;
                aH[kt2][lane2 * 8 + j2] = f2bf(hv);
            }
        }
    }
    __syncthreads();

    // r2: 16 N-tiles x 16 K-steps -> zbuf (fp32, pre-LN2)
    {
        bf16x8 hfr[16];
        #pragma unroll
        for (int kt = 0; kt < 16; ++kt) hfr[kt] = *(const bf16x8*)&aH[kt][lane * 8];
        for (int q = 0; q < 2; ++q){
            int nt = w + 8 * q;
            f32x4 acc = {0.f, 0.f, 0.f, 0.f};
            #pragma unroll
            for (int kt = 0; kt < 16; ++kt){
                bf16x8 bf = *(const bf16x8*)(wr2 + (kt * 16 + nt) * 512 + lane * 8);
                acc = __builtin_amdgcn_mfma_f32_16x16x32_bf16(hfr[kt], bf, acc, 0, 0, 0);
            }
            float bb = b_r2[nt * 16 + c];
            #pragma unroll
            for (int r = 0; r < 4; ++r)
                zbuf[4 * g + r][nt * 16 + c] = acc[r] + bb;
        }
    }
    __syncthreads();

    // LN2 stats
    if (i < 256){
        int t = i >> 4, c2 = i & 15;
        float s = 0.f, s2 = 0.f;
        #pragma unroll
        for (int m = 0; m < 16; ++m){ float v = zbuf[t][c2 + 16 * m]; s += v; s2 += v * v; }
        red[t][c2] = s; red2[t][c2] = s2;
    }
    __syncthreads();
    if (i < 16){
        float s = 0.f, s2 = 0.f;
        #pragma unroll
        for (int c2 = 0; c2 < 16; ++c2){ s += red[i][c2]; s2 += red2[i][c2]; }
        float mean = s * (1.0f / 256.0f);
        float var  = s2 * (1.0f / 256.0f) - mean * mean;
        mu[i] = mean; rs[i] = rsqrtf(var + 1e-5f);
    }
    __syncthreads();

    // repack LN2(refined) into bf16 A-frags (reuse aA)
    {
        int kt = i >> 6;
        int t2 = lane & 15, kb = kt * 32 + ((lane >> 4) << 3);
        float m_ = mu[t2], r_ = rs[t2];
        bf16x8 v8;
        #pragma unroll
        for (int j = 0; j < 8; ++j){
            int k = kb + j;
            float v = (zbuf[t2][k] - m_) * r_ * ln_o_g[k] + ln_o_b[k];
            v8[j] = (short)f2bf(v);
        }
        *(bf16x8*)&aA[kt][lane * 8] = v8;
    }
    __syncthreads();

    // out: 16 N-tiles x 8 K-steps + residual
    {
        bf16x8 azr[8];
        #pragma unroll
        for (int kt = 0; kt < 8; ++kt) azr[kt] = *(const bf16x8*)&aA[kt][lane * 8];
        for (int q = 0; q < 2; ++q){
            int nt = w + 8 * q;
            f32x4 acc = {0.f, 0.f, 0.f, 0.f};
            #pragma unroll
            for (int kt = 0; kt < 8; ++kt){
                bf16x8 bf = *(const bf16x8*)(wout + (kt * 16 + nt) * 512 + lane * 8);
                acc = __builtin_amdgcn_mfma_f32_16x16x32_bf16(azr[kt], bf, acc, 0, 0, 0);
            }
            float bb = b_out[nt * 16 + c];
            #pragma unroll
            for (int r = 0; r < 4; ++r){
                size_t o = (size_t)(b * L_ + l0 + 4 * g + r) * D_ + nt * 16 + c;
                out[o] = x[o] + acc[r] + bb;
            }
        }
    }
}

extern "C" void kernel_launch(void* const* d_in, const int* in_sizes, int n_in,
                              void* d_out, int out_size, void* d_ws, size_t ws_size,
                              hipStream_t stream) {
    const float* x          = (const float*)d_in[0];
    const float* pos_phases = (const float*)d_in[1];
    const float* w_pv       = (const float*)d_in[2];
    const float* b_pv       = (const float*)d_in[3];
    const float* w_key      = (const float*)d_in[4];
    const float* b_key      = (const float*)d_in[5];
    const float* w_kv       = (const float*)d_in[6];
    const float* b_kv       = (const float*)d_in[7];
    const float* w_vg1      = (const float*)d_in[8];
    const float* b_vg1      = (const float*)d_in[9];
    const float* w_vg2      = (const float*)d_in[10];
    const float* b_vg2      = (const float*)d_in[11];
    const float* w_bg1      = (const float*)d_in[12];
    const float* b_bg1      = (const float*)d_in[13];
    const float* w_bg2      = (const float*)d_in[14];
    const float* b_bg2      = (const float*)d_in[15];
    const float* ln_r_g     = (const float*)d_in[16];
    const float* ln_r_b     = (const float*)d_in[17];
    const float* w_r1       = (const float*)d_in[18];
    const float* b_r1       = (const float*)d_in[19];
    const float* w_r2       = (const float*)d_in[20];
    const float* b_r2       = (const float*)d_in[21];
    const float* ln_o_g     = (const float*)d_in[22];
    const float* ln_o_b     = (const float*)d_in[23];
    const float* w_out      = (const float*)d_in[24];
    const float* b_out      = (const float*)d_in[25];
    float* out = (float*)d_out;

    float* ws = (float*)d_ws;
    size_t off = 0;
    float* cpos   = ws + off; off += (size_t)L_ * P_;
    float* spos   = ws + off; off += (size_t)L_ * P_;
    float* pv     = ws + off; off += (size_t)B_ * L_ * D_;
    float* kvv    = ws + off; off += (size_t)B_ * L_ * D_;
    float* ck     = ws + off; off += (size_t)B_ * L_ * P_;
    float* sk     = ws + off; off += (size_t)B_ * L_ * P_;
    float* vg     = ws + off; off += (size_t)B_ * L_;
    float* rnorm  = ws + off; off += (size_t)B_ * L_;
    float* blend0 = ws + off; off += (size_t)B_ * L_;
    float* blend1 = ws + off; off += (size_t)B_ * L_;
    float* blended= ws + off; off += (size_t)B_ * L_ * D_;
    float* posSr  = ws + off; off += (size_t)B_ * NC_ * P_ * D_;
    float* posSi  = ws + off; off += (size_t)B_ * NC_ * P_ * D_;
    float* kvSr   = ws + off; off += (size_t)B_ * NC_ * P_ * D_;
    float* kvSi   = ws + off; off += (size_t)B_ * NC_ * P_ * D_;
    unsigned short* wq   = (unsigned short*)(ws + off); off += 622592 / 2;
    unsigned short* xbf  = (unsigned short*)(ws + off); off += 1048576 / 2;
    unsigned short* xsbf = (unsigned short*)(ws + off); off += 1048576 / 2;

    k_sincos<<<(L_ * P_) / 256, 256, 0, stream>>>(pos_phases, cpos, spos);
    k_prep_w<<<2432, 256, 0, stream>>>(w_pv, w_kv, w_vg1, w_bg1, w_r1, w_r2, w_out, wq);
    k_prep_x<<<8192, 256, 0, stream>>>(x, xbf, xsbf);

    k_proj<<<B_ * 128, 512, 0, stream>>>(x, wq,
        b_pv, b_kv, b_vg1, w_vg2, b_vg2, b_bg1, w_bg2, b_bg2, w_key, b_key,
        xbf, xsbf,
        pv, kvv, ck, sk, vg, blend0, blend1);
    k_gatecum<<<B_, 256, 0, stream>>>(vg, rnorm);

    dim3 gs(NC_, B_);
    k_pos_chunksum<<<gs, 256, 0, stream>>>(cpos, spos, pv, posSr, posSi);
    k_prefix<<<(2 * B_ * P_ * D_) / 256, 256, 0, stream>>>(posSr, posSi);
    k_pos_retrieve<<<gs, 256, 0, stream>>>(cpos, spos, pv, posSr, posSi, blended);

    k_kv_chunksum<<<gs, 256, 0, stream>>>(ck, sk, kvv, vg, kvSr, kvSi);
    k_prefix<<<(2 * B_ * P_ * D_) / 256, 256, 0, stream>>>(kvSr, kvSi);
    k_kv_retrieve<<<gs, 256, 0, stream>>>(ck, sk, kvv, vg, rnorm, kvSr, kvSi,
                                          blend0, blend1, blended);

    k_final<<<B_ * 128, 512, 0, stream>>>(x, blended, wq,
        ln_r_g, ln_r_b, b_r1, b_r2, ln_o_g, ln_o_b, b_out, out);
}

// Round 4
// 116.835 us; speedup vs baseline: 2.5932x; 1.5009x over previous
//
#include <hip/hip_runtime.h>
#include <math.h>

#define B_ 2
#define L_ 2048
#define D_ 256
#define P_ 32
#define NC_ 64
#define CL_ 32

#define INV_SQRT_P 0.17677669529663687f   // 1/sqrt(32)
#define PI_F 3.14159265358979323846f

typedef __attribute__((ext_vector_type(8))) short bf16x8;
typedef __attribute__((ext_vector_type(4))) float f32x4;

__device__ __forceinline__ float gelu_exact(float x){
    return 0.5f * x * (1.0f + erff(x * 0.70710678118654752f));
}

__device__ __forceinline__ unsigned short f2bf(float f){
    unsigned int u = __float_as_uint(f);
    u += 0x7FFFu + ((u >> 16) & 1u);     // round-to-nearest-even
    return (unsigned short)(u >> 16);
}

// ---------------- K_prep: all bf16 repacks + pos sincos, one launch ----------
// wq segments (ushort offsets):
//   wpv 0, wkv 65536, wvg1 131072, wbg1 262144, wr1 294912, wr2 425984,
//   wout 557056, wkey 622592 ; total 630784
// B-frag layout per matrix: ((kt*NT + nt)*64 + lane)*8 + j
//   element = W[kt*32 + 8*(lane>>4) + j][nt*16 + (lane&15)]
// A-frag layout (x / shifted x): (((b*128+lt)*8 + kt)*64 + lane)*8 + j
__global__ __launch_bounds__(256) void k_prep(
    const float* __restrict__ x, const float* __restrict__ pos_phases,
    const float* __restrict__ w_pv, const float* __restrict__ w_kv,
    const float* __restrict__ w_vg1, const float* __restrict__ w_bg1,
    const float* __restrict__ w_r1, const float* __restrict__ w_r2,
    const float* __restrict__ w_out, const float* __restrict__ w_key,
    unsigned short* __restrict__ wq, unsigned short* __restrict__ xbf,
    unsigned short* __restrict__ xsbf,
    float* __restrict__ cpos, float* __restrict__ spos)
{
    int id = blockIdx.x * 256 + threadIdx.x;   // 0..2793471
    if (id < 630784){
        const float* src; int N; int local;
        if (id < 65536)       { src = w_pv;  N = 256; local = id; }
        else if (id < 131072) { src = w_kv;  N = 256; local = id - 65536; }
        else if (id < 262144) { src = w_vg1; N = 256; local = id - 131072; }
        else if (id < 294912) { src = w_bg1; N = 128; local = id - 262144; }
        else if (id < 425984) { src = w_r1;  N = 512; local = id - 294912; }
        else if (id < 557056) { src = w_r2;  N = 256; local = id - 425984; }
        else if (id < 622592) { src = w_out; N = 256; local = id - 557056; }
        else                  { src = w_key; N = 32;  local = id - 622592; }
        int j = local & 7, lane = (local >> 3) & 63, tile = local >> 9;
        int NT = N >> 4;
        int nt = tile % NT, kt = tile / NT;
        int row = kt * 32 + ((lane >> 4) << 3) + j;
        int col = nt * 16 + (lane & 15);
        wq[id] = f2bf(src[(size_t)row * N + col]);
    } else if (id < 2727936){
        int id2 = id - 630784;
        int shifted = id2 >> 20;
        int local = id2 & 1048575;
        int j = local & 7, lane = (local >> 3) & 63;
        int kt = (local >> 9) & 7, lt = (local >> 12) & 127, b = local >> 19;
        int k = kt * 32 + ((lane >> 4) << 3) + j;
        int l = lt * 16 + (lane & 15);
        float v;
        if (shifted) v = (l >= 1) ? x[(size_t)(b * L_ + l - 1) * D_ + k] : 0.0f;
        else         v = x[(size_t)(b * L_ + l) * D_ + k];
        (shifted ? xsbf : xbf)[local] = f2bf(v);
    } else {
        int idx = id - 2727936;                // 0..65535 = L*P
        float s, c;
        sincosf(pos_phases[idx], &s, &c);
        cpos[idx] = c;
        spos[idx] = s;
    }
}

// ---------------- K1: fused projections via MFMA, 16 tokens/block, 8 waves ----
// 58 tile jobs: [0,2) key, [2,18) pv, [18,34) kv, [34,50) vg1(K=512), [50,58) bg1
__global__ __launch_bounds__(512) void k_proj(
    const unsigned short* __restrict__ wq,
    const float* __restrict__ b_pv, const float* __restrict__ b_kv,
    const float* __restrict__ b_vg1,
    const float* __restrict__ w_vg2, const float* __restrict__ b_vg2,
    const float* __restrict__ b_bg1,
    const float* __restrict__ w_bg2, const float* __restrict__ b_bg2,
    const float* __restrict__ b_key,
    const unsigned short* __restrict__ xbf, const unsigned short* __restrict__ xsbf,
    float* __restrict__ pv, float* __restrict__ kvv,
    float* __restrict__ ck, float* __restrict__ sk,
    float* __restrict__ vg, float* __restrict__ blend0, float* __restrict__ blend1)
{
    __shared__ float hbuf[16][257];
    __shared__ float bhbuf[16][129];
    __shared__ float kph[16][33];
    __shared__ float red[16][17], red2[16][17], red3[16][17];

    const int i = threadIdx.x;
    const int lane = i & 63, w = i >> 6;
    const int b = blockIdx.x >> 7, lt = blockIdx.x & 127, l0 = lt * 16;
    const int g = lane >> 4, c = lane & 15;

    // preload A fragments (x and shifted-x), 8 K-steps each
    bf16x8 xa[8], xs[8];
    {
        const unsigned short* base  = xbf  + (size_t)((b * 128 + lt) * 8) * 512 + lane * 8;
        const unsigned short* bases = xsbf + (size_t)((b * 128 + lt) * 8) * 512 + lane * 8;
        #pragma unroll
        for (int kt = 0; kt < 8; ++kt){
            xa[kt] = *(const bf16x8*)(base  + kt * 512);
            xs[kt] = *(const bf16x8*)(bases + kt * 512);
        }
    }

    const unsigned short* wpv  = wq;
    const unsigned short* wkv  = wq + 65536;
    const unsigned short* wvg1 = wq + 131072;
    const unsigned short* wbg1 = wq + 262144;
    const unsigned short* wkey = wq + 622592;

    for (int jb = w; jb < 58; jb += 8){
        f32x4 acc = {0.f, 0.f, 0.f, 0.f};
        if (jb < 2){
            int nt = jb;
            #pragma unroll
            for (int kt = 0; kt < 8; ++kt){
                bf16x8 bf = *(const bf16x8*)(wkey + (kt * 2 + nt) * 512 + lane * 8);
                acc = __builtin_amdgcn_mfma_f32_16x16x32_bf16(xa[kt], bf, acc, 0, 0, 0);
            }
            float bb = b_key[nt * 16 + c];
            #pragma unroll
            for (int r = 0; r < 4; ++r)
                kph[4 * g + r][nt * 16 + c] = acc[r] + bb;
        } else if (jb < 18){
            int nt = jb - 2;
            #pragma unroll
            for (int kt = 0; kt < 8; ++kt){
                bf16x8 bf = *(const bf16x8*)(wpv + (kt * 16 + nt) * 512 + lane * 8);
                acc = __builtin_amdgcn_mfma_f32_16x16x32_bf16(xa[kt], bf, acc, 0, 0, 0);
            }
            float bb = b_pv[nt * 16 + c];
            #pragma unroll
            for (int r = 0; r < 4; ++r)
                pv[(size_t)(b * L_ + l0 + 4 * g + r) * D_ + nt * 16 + c] = acc[r] + bb;
        } else if (jb < 34){
            int nt = jb - 18;
            #pragma unroll
            for (int kt = 0; kt < 8; ++kt){
                bf16x8 bf = *(const bf16x8*)(wkv + (kt * 16 + nt) * 512 + lane * 8);
                acc = __builtin_amdgcn_mfma_f32_16x16x32_bf16(xa[kt], bf, acc, 0, 0, 0);
            }
            float bb = b_kv[nt * 16 + c];
            #pragma unroll
            for (int r = 0; r < 4; ++r)
                kvv[(size_t)(b * L_ + l0 + 4 * g + r) * D_ + nt * 16 + c] = acc[r] + bb;
        } else if (jb < 50){
            int nt = jb - 34;
            #pragma unroll
            for (int kt = 0; kt < 8; ++kt){
                bf16x8 bf = *(const bf16x8*)(wvg1 + (kt * 16 + nt) * 512 + lane * 8);
                acc = __builtin_amdgcn_mfma_f32_16x16x32_bf16(xa[kt], bf, acc, 0, 0, 0);
            }
            #pragma unroll
            for (int kt = 8; kt < 16; ++kt){
                bf16x8 bf = *(const bf16x8*)(wvg1 + (kt * 16 + nt) * 512 + lane * 8);
                acc = __builtin_amdgcn_mfma_f32_16x16x32_bf16(xs[kt - 8], bf, acc, 0, 0, 0);
            }
            float bb = b_vg1[nt * 16 + c];
            #pragma unroll
            for (int r = 0; r < 4; ++r)
                hbuf[4 * g + r][nt * 16 + c] = gelu_exact(acc[r] + bb);
        } else {
            int nt = jb - 50;
            #pragma unroll
            for (int kt = 0; kt < 8; ++kt){
                bf16x8 bf = *(const bf16x8*)(wbg1 + (kt * 8 + nt) * 512 + lane * 8);
                acc = __builtin_amdgcn_mfma_f32_16x16x32_bf16(xa[kt], bf, acc, 0, 0, 0);
            }
            float bb = b_bg1[nt * 16 + c];
            #pragma unroll
            for (int r = 0; r < 4; ++r)
                bhbuf[4 * g + r][nt * 16 + c] = gelu_exact(acc[r] + bb);
        }
    }
    __syncthreads();

    // key phases -> phasors (16 tokens x 32 p = 512 threads)
    {
        int t = i >> 5, p = i & 31;
        float a = tanhf(kph[t][p]) * PI_F;
        float s, cc;
        sincosf(a, &s, &cc);
        ck[(size_t)(b * L_ + l0 + t) * P_ + p] = cc;
        sk[(size_t)(b * L_ + l0 + t) * P_ + p] = s;
    }

    // vg2 (threads 0..255) and bg2 (threads 256..511) partial reductions
    if (i < 256){
        int t = i >> 4, c2 = i & 15;
        float s = 0.f;
        #pragma unroll
        for (int m = 0; m < 16; ++m){ int dd = c2 + 16 * m; s += hbuf[t][dd] * w_vg2[dd]; }
        red[t][c2] = s;
    } else {
        int ii = i - 256;
        int t = ii >> 4, c2 = ii & 15;
        float s0 = 0.f, s1 = 0.f;
        #pragma unroll
        for (int m = 0; m < 8; ++m){
            int jj = c2 + 16 * m;
            float v = bhbuf[t][jj];
            s0 += v * w_bg2[jj * 2 + 0];
            s1 += v * w_bg2[jj * 2 + 1];
        }
        red2[t][c2] = s0; red3[t][c2] = s1;
    }
    __syncthreads();
    if (i < 16){
        float s = 0.f;
        #pragma unroll
        for (int c2 = 0; c2 < 16; ++c2) s += red[i][c2];
        s += b_vg2[0];
        vg[b * L_ + l0 + i] = 1.0f / (1.0f + expf(-s));
    } else if (i < 32){
        int t = i - 16;
        float s0 = 0.f, s1 = 0.f;
        #pragma unroll
        for (int c2 = 0; c2 < 16; ++c2){ s0 += red2[t][c2]; s1 += red3[t][c2]; }
        s0 += b_bg2[0]; s1 += b_bg2[1];
        float mx = fmaxf(s0, s1);
        float e0 = expf(s0 - mx), e1 = expf(s1 - mx);
        float inv = 1.0f / (e0 + e1);
        blend0[b * L_ + l0 + t] = e0 * inv;
        blend1[b * L_ + l0 + t] = e1 * inv;
    }
}

// ---------------- K_scan1: chunk sums (pos z=0,1 / kv z=2,3) + gatecum (z=4) --
__global__ __launch_bounds__(128) void k_scan1(
    const float* __restrict__ cpos, const float* __restrict__ spos,
    const float* __restrict__ ck, const float* __restrict__ sk,
    const float* __restrict__ pv, const float* __restrict__ kvv,
    const float* __restrict__ vg,
    float* __restrict__ posSr, float* __restrict__ posSi,
    float* __restrict__ kvSr, float* __restrict__ kvSi,
    float* __restrict__ rnorm)
{
    const int z = blockIdx.z;
    const int c = blockIdx.x, b = blockIdx.y;
    const int i = threadIdx.x;
    if (z == 4){
        if (c != 0) return;
        // gate cumsum for batch b: 128 threads x 16 elems
        float loc[16];
        float run = 0.f;
        #pragma unroll
        for (int m = 0; m < 16; ++m){ run += vg[b * L_ + i * 16 + m]; loc[m] = run; }
        __shared__ float part[128];
        part[i] = run;
        __syncthreads();
        for (int off = 1; off < 128; off <<= 1){
            float t = (i >= off) ? part[i - off] : 0.0f;
            __syncthreads();
            part[i] += t;
            __syncthreads();
        }
        float excl = part[i] - run;
        #pragma unroll
        for (int m = 0; m < 16; ++m){
            float gc = fmaxf(excl + loc[m], 1.0f);
            rnorm[b * L_ + i * 16 + m] = rsqrtf(gc) * INV_SQRT_P;
        }
        return;
    }
    const int which = z >> 1;
    const int d = (z & 1) * 128 + i;
    float Sr[32], Si[32];
    #pragma unroll
    for (int p = 0; p < 32; ++p){ Sr[p] = 0.f; Si[p] = 0.f; }

    if (which == 0){
        for (int l = 0; l < CL_; ++l){
            float v = pv[(size_t)(b * L_ + c * CL_ + l) * D_ + d];
            const float* cp = cpos + (c * CL_ + l) * P_;
            const float* sp = spos + (c * CL_ + l) * P_;
            #pragma unroll
            for (int pq = 0; pq < 8; ++pq){
                float4 cc = *(const float4*)(cp + pq * 4);
                float4 ss = *(const float4*)(sp + pq * 4);
                Sr[pq*4+0] = fmaf(cc.x, v, Sr[pq*4+0]); Si[pq*4+0] = fmaf(ss.x, v, Si[pq*4+0]);
                Sr[pq*4+1] = fmaf(cc.y, v, Sr[pq*4+1]); Si[pq*4+1] = fmaf(ss.y, v, Si[pq*4+1]);
                Sr[pq*4+2] = fmaf(cc.z, v, Sr[pq*4+2]); Si[pq*4+2] = fmaf(ss.z, v, Si[pq*4+2]);
                Sr[pq*4+3] = fmaf(cc.w, v, Sr[pq*4+3]); Si[pq*4+3] = fmaf(ss.w, v, Si[pq*4+3]);
            }
        }
        #pragma unroll
        for (int p = 0; p < 32; ++p){
            size_t o = (size_t)((b * NC_ + c) * P_ + p) * D_ + d;
            posSr[o] = Sr[p]; posSi[o] = Si[p];
        }
    } else {
        for (int l = 0; l < CL_; ++l){
            float gb = vg[b * L_ + c * CL_ + l];
            float vv = kvv[(size_t)(b * L_ + c * CL_ + l) * D_ + d] * gb;
            int srow = c * CL_ + l - 1;
            if (srow >= 0){
                const float* cs = ck + ((size_t)b * L_ + srow) * P_;
                const float* ss = sk + ((size_t)b * L_ + srow) * P_;
                #pragma unroll
                for (int pq = 0; pq < 8; ++pq){
                    float4 cc = *(const float4*)(cs + pq * 4);
                    float4 sv = *(const float4*)(ss + pq * 4);
                    Sr[pq*4+0] = fmaf(cc.x, vv, Sr[pq*4+0]); Si[pq*4+0] = fmaf(sv.x, vv, Si[pq*4+0]);
                    Sr[pq*4+1] = fmaf(cc.y, vv, Sr[pq*4+1]); Si[pq*4+1] = fmaf(sv.y, vv, Si[pq*4+1]);
                    Sr[pq*4+2] = fmaf(cc.z, vv, Sr[pq*4+2]); Si[pq*4+2] = fmaf(sv.z, vv, Si[pq*4+2]);
                    Sr[pq*4+3] = fmaf(cc.w, vv, Sr[pq*4+3]); Si[pq*4+3] = fmaf(sv.w, vv, Si[pq*4+3]);
                }
            }
        }
        #pragma unroll
        for (int p = 0; p < 32; ++p){
            size_t o = (size_t)((b * NC_ + c) * P_ + p) * D_ + d;
            kvSr[o] = Sr[p]; kvSi[o] = Si[p];
        }
    }
}

// ---------------- K_prefix: in-place exclusive prefix over chunks, 4 arrays ---
__global__ __launch_bounds__(256) void k_prefix(
    float* __restrict__ posSr, float* __restrict__ posSi,
    float* __restrict__ kvSr, float* __restrict__ kvSi)
{
    int gid = blockIdx.x * 256 + threadIdx.x;   // 0..65535
    float* A = (gid < 16384) ? posSr : (gid < 32768) ? posSi
             : (gid < 49152) ? kvSr : kvSi;
    int g = gid & 16383;
    int b = g >> 13;
    int pd = g & 8191;
    float run = 0.f;
    #pragma unroll 4
    for (int cc = 0; cc < NC_; ++cc){
        size_t idx = (size_t)(b * NC_ + cc) * (P_ * D_) + pd;
        float t = A[idx];
        A[idx] = run;
        run += t;
    }
}

// ---------------- K_retrieve: pos (z=0,1) / kv (z=2,3) ----------------
__global__ __launch_bounds__(128) void k_retrieve(
    const float* __restrict__ cpos, const float* __restrict__ spos,
    const float* __restrict__ ck, const float* __restrict__ sk,
    const float* __restrict__ pv, const float* __restrict__ kvv,
    const float* __restrict__ vg, const float* __restrict__ rnorm,
    const float* __restrict__ posSr, const float* __restrict__ posSi,
    const float* __restrict__ kvSr, const float* __restrict__ kvSi,
    float* __restrict__ posret, float* __restrict__ kvret)
{
    const int z = blockIdx.z;
    const int c = blockIdx.x, b = blockIdx.y;
    const int which = z >> 1;
    const int d = (z & 1) * 128 + threadIdx.x;
    float Sr[32], Si[32];

    if (which == 0){
        #pragma unroll
        for (int p = 0; p < 32; ++p){
            size_t o = (size_t)((b * NC_ + c) * P_ + p) * D_ + d;
            Sr[p] = posSr[o]; Si[p] = posSi[o];
        }
        for (int l = 0; l < CL_; ++l){
            float v = pv[(size_t)(b * L_ + c * CL_ + l) * D_ + d];
            const float* cp = cpos + (c * CL_ + l) * P_;
            const float* sp = spos + (c * CL_ + l) * P_;
            float r0 = 0.f, r1 = 0.f, r2 = 0.f, r3 = 0.f;
            #pragma unroll
            for (int pq = 0; pq < 8; ++pq){
                float4 cc = *(const float4*)(cp + pq * 4);
                float4 ss = *(const float4*)(sp + pq * 4);
                Sr[pq*4+0] = fmaf(cc.x, v, Sr[pq*4+0]); r0 = fmaf(cc.x, Sr[pq*4+0], r0);
                Si[pq*4+0] = fmaf(ss.x, v, Si[pq*4+0]); r0 = fmaf(ss.x, Si[pq*4+0], r0);
                Sr[pq*4+1] = fmaf(cc.y, v, Sr[pq*4+1]); r1 = fmaf(cc.y, Sr[pq*4+1], r1);
                Si[pq*4+1] = fmaf(ss.y, v, Si[pq*4+1]); r1 = fmaf(ss.y, Si[pq*4+1], r1);
                Sr[pq*4+2] = fmaf(cc.z, v, Sr[pq*4+2]); r2 = fmaf(cc.z, Sr[pq*4+2], r2);
                Si[pq*4+2] = fmaf(ss.z, v, Si[pq*4+2]); r2 = fmaf(ss.z, Si[pq*4+2], r2);
                Sr[pq*4+3] = fmaf(cc.w, v, Sr[pq*4+3]); r3 = fmaf(cc.w, Sr[pq*4+3], r3);
                Si[pq*4+3] = fmaf(ss.w, v, Si[pq*4+3]); r3 = fmaf(ss.w, Si[pq*4+3], r3);
            }
            posret[(size_t)(b * L_ + c * CL_ + l) * D_ + d] =
                ((r0 + r1) + (r2 + r3)) * INV_SQRT_P;
        }
    } else {
        #pragma unroll
        for (int p = 0; p < 32; ++p){
            size_t o = (size_t)((b * NC_ + c) * P_ + p) * D_ + d;
            Sr[p] = kvSr[o]; Si[p] = kvSi[o];
        }
        for (int l = 0; l < CL_; ++l){
            int row = c * CL_ + l;
            float gb = vg[b * L_ + row];
            float rn = rnorm[b * L_ + row];
            float vv = kvv[(size_t)(b * L_ + row) * D_ + d] * gb;
            const float* cq = ck + ((size_t)b * L_ + row) * P_;
            const float* sq = sk + ((size_t)b * L_ + row) * P_;
            int srow = row - 1;
            float r0 = 0.f, r1 = 0.f, r2 = 0.f, r3 = 0.f;
            if (srow >= 0){
                const float* cs = ck + ((size_t)b * L_ + srow) * P_;
                const float* ss = sk + ((size_t)b * L_ + srow) * P_;
                #pragma unroll
                for (int pq = 0; pq < 8; ++pq){
                    float4 cc = *(const float4*)(cs + pq * 4);
                    float4 sv = *(const float4*)(ss + pq * 4);
                    float4 qc = *(const float4*)(cq + pq * 4);
                    float4 qs = *(const float4*)(sq + pq * 4);
                    Sr[pq*4+0] = fmaf(cc.x, vv, Sr[pq*4+0]); r0 = fmaf(qc.x, Sr[pq*4+0], r0);
                    Si[pq*4+0] = fmaf(sv.x, vv, Si[pq*4+0]); r0 = fmaf(qs.x, Si[pq*4+0], r0);
                    Sr[pq*4+1] = fmaf(cc.y, vv, Sr[pq*4+1]); r1 = fmaf(qc.y, Sr[pq*4+1], r1);
                    Si[pq*4+1] = fmaf(sv.y, vv, Si[pq*4+1]); r1 = fmaf(qs.y, Si[pq*4+1], r1);
                    Sr[pq*4+2] = fmaf(cc.z, vv, Sr[pq*4+2]); r2 = fmaf(qc.z, Sr[pq*4+2], r2);
                    Si[pq*4+2] = fmaf(sv.z, vv, Si[pq*4+2]); r2 = fmaf(qs.z, Si[pq*4+2], r2);
                    Sr[pq*4+3] = fmaf(cc.w, vv, Sr[pq*4+3]); r3 = fmaf(qc.w, Sr[pq*4+3], r3);
                    Si[pq*4+3] = fmaf(sv.w, vv, Si[pq*4+3]); r3 = fmaf(qs.w, Si[pq*4+3], r3);
                }
            } else {
                #pragma unroll
                for (int pq = 0; pq < 8; ++pq){
                    float4 qc = *(const float4*)(cq + pq * 4);
                    float4 qs = *(const float4*)(sq + pq * 4);
                    r0 = fmaf(qc.x, Sr[pq*4+0], r0); r0 = fmaf(qs.x, Si[pq*4+0], r0);
                    r1 = fmaf(qc.y, Sr[pq*4+1], r1); r1 = fmaf(qs.y, Si[pq*4+1], r1);
                    r2 = fmaf(qc.z, Sr[pq*4+2], r2); r2 = fmaf(qs.z, Si[pq*4+2], r2);
                    r3 = fmaf(qc.w, Sr[pq*4+3], r3); r3 = fmaf(qs.w, Si[pq*4+3], r3);
                }
            }
            kvret[(size_t)(b * L_ + row) * D_ + d] = ((r0 + r1) + (r2 + r3)) * rn;
        }
    }
}

// ---------------- K9: blend -> LN -> r1 -> r2 -> LN -> out via MFMA ----------
__global__ __launch_bounds__(512) void k_final(
    const float* __restrict__ x,
    const float* __restrict__ posret, const float* __restrict__ kvret,
    const float* __restrict__ blend0, const float* __restrict__ blend1,
    const unsigned short* __restrict__ wq,
    const float* __restrict__ ln_r_g, const float* __restrict__ ln_r_b,
    const float* __restrict__ b_r1, const float* __restrict__ b_r2,
    const float* __restrict__ ln_o_g, const float* __restrict__ ln_o_b,
    const float* __restrict__ b_out,
    float* __restrict__ out)
{
    __shared__ float zbuf[16][257];
    __shared__ __align__(16) unsigned short aA[8][512];
    __shared__ __align__(16) unsigned short aH[16][512];
    __shared__ float red[16][17], red2[16][17];
    __shared__ float mu[16], rs[16];

    const int i = threadIdx.x, lane = i & 63, w = i >> 6;
    const int b = blockIdx.x >> 7, l0 = (blockIdx.x & 127) * 16;
    const int g = lane >> 4, c = lane & 15;
    const unsigned short* wr1  = wq + 294912;
    const unsigned short* wr2  = wq + 425984;
    const unsigned short* wout = wq + 557056;

    // load + blend tile 16x256
    {
        int t = i >> 5, c0 = (i & 31) * 8;
        size_t base = (size_t)(b * L_ + l0 + t) * D_ + c0;
        float w0 = blend0[b * L_ + l0 + t], w1 = blend1[b * L_ + l0 + t];
        #pragma unroll
        for (int m = 0; m < 8; ++m)
            zbuf[t][c0 + m] = w0 * posret[base + m] + w1 * kvret[base + m];
    }
    __syncthreads();

    // LN1 stats
    if (i < 256){
        int t = i >> 4, c2 = i & 15;
        float s = 0.f, s2 = 0.f;
        #pragma unroll
        for (int m = 0; m < 16; ++m){ float v = zbuf[t][c2 + 16 * m]; s += v; s2 += v * v; }
        red[t][c2] = s; red2[t][c2] = s2;
    }
    __syncthreads();
    if (i < 16){
        float s = 0.f, s2 = 0.f;
        #pragma unroll
        for (int c2 = 0; c2 < 16; ++c2){ s += red[i][c2]; s2 += red2[i][c2]; }
        float mean = s * (1.0f / 256.0f);
        float var  = s2 * (1.0f / 256.0f) - mean * mean;
        mu[i] = mean; rs[i] = rsqrtf(var + 1e-5f);
    }
    __syncthreads();

    // repack LN1(z) into bf16 A-frags
    {
        int kt = i >> 6;
        int t2 = lane & 15, kb = kt * 32 + ((lane >> 4) << 3);
        float m_ = mu[t2], r_ = rs[t2];
        bf16x8 v8;
        #pragma unroll
        for (int j = 0; j < 8; ++j){
            int k = kb + j;
            float v = (zbuf[t2][k] - m_) * r_ * ln_r_g[k] + ln_r_b[k];
            v8[j] = (short)f2bf(v);
        }
        *(bf16x8*)&aA[kt][lane * 8] = v8;
    }
    __syncthreads();

    // r1: 32 N-tiles x 8 K-steps; gelu -> aH (A-frags for r2, K=512)
    {
        bf16x8 afr[8];
        #pragma unroll
        for (int kt = 0; kt < 8; ++kt) afr[kt] = *(const bf16x8*)&aA[kt][lane * 8];
        for (int q = 0; q < 4; ++q){
            int nt = w + 8 * q;
            f32x4 acc = {0.f, 0.f, 0.f, 0.f};
            #pragma unroll
            for (int kt = 0; kt < 8; ++kt){
                bf16x8 bf = *(const bf16x8*)(wr1 + (kt * 32 + nt) * 512 + lane * 8);
                acc = __builtin_amdgcn_mfma_f32_16x16x32_bf16(afr[kt], bf, acc, 0, 0, 0);
            }
            float bb = b_r1[nt * 16 + c];
            #pragma unroll
            for (int r = 0; r < 4; ++r){
                float hv = gelu_exact(acc[r] + bb);
                int t = 4 * g + r, hcol = nt * 16 + c;
                int kt2 = hcol >> 5, kk = hcol & 31;
                int lane2 = ((kk >> 3) << 4) + t, j2 = kk & 7;
                aH[kt2][lane2 * 8 + j2] = f2bf(hv);
            }
        }
    }
    __syncthreads();

    // r2: 16 N-tiles x 16 K-steps -> zbuf (fp32, pre-LN2)
    {
        bf16x8 hfr[16];
        #pragma unroll
        for (int kt = 0; kt < 16; ++kt) hfr[kt] = *(const bf16x8*)&aH[kt][lane * 8];
        for (int q = 0; q < 2; ++q){
            int nt = w + 8 * q;
            f32x4 acc = {0.f, 0.f, 0.f, 0.f};
            #pragma unroll
            for (int kt = 0; kt < 16; ++kt){
                bf16x8 bf = *(const bf16x8*)(wr2 + (kt * 16 + nt) * 512 + lane * 8);
                acc = __builtin_amdgcn_mfma_f32_16x16x32_bf16(hfr[kt], bf, acc, 0, 0, 0);
            }
            float bb = b_r2[nt * 16 + c];
            #pragma unroll
            for (int r = 0; r < 4; ++r)
                zbuf[4 * g + r][nt * 16 + c] = acc[r] + bb;
        }
    }
    __syncthreads();

    // LN2 stats
    if (i < 256){
        int t = i >> 4, c2 = i & 15;
        float s = 0.f, s2 = 0.f;
        #pragma unroll
        for (int m = 0; m < 16; ++m){ float v = zbuf[t][c2 + 16 * m]; s += v; s2 += v * v; }
        red[t][c2] = s; red2[t][c2] = s2;
    }
    __syncthreads();
    if (i < 16){
        float s = 0.f, s2 = 0.f;
        #pragma unroll
        for (int c2 = 0; c2 < 16; ++c2){ s += red[i][c2]; s2 += red2[i][c2]; }
        float mean = s * (1.0f / 256.0f);
        float var  = s2 * (1.0f / 256.0f) - mean * mean;
        mu[i] = mean; rs[i] = rsqrtf(var + 1e-5f);
    }
    __syncthreads();

    // repack LN2(refined) into bf16 A-frags (reuse aA)
    {
        int kt = i >> 6;
        int t2 = lane & 15, kb = kt * 32 + ((lane >> 4) << 3);
        float m_ = mu[t2], r_ = rs[t2];
        bf16x8 v8;
        #pragma unroll
        for (int j = 0; j < 8; ++j){
            int k = kb + j;
            float v = (zbuf[t2][k] - m_) * r_ * ln_o_g[k] + ln_o_b[k];
            v8[j] = (short)f2bf(v);
        }
        *(bf16x8*)&aA[kt][lane * 8] = v8;
    }
    __syncthreads();

    // out: 16 N-tiles x 8 K-steps + residual
    {
        bf16x8 azr[8];
        #pragma unroll
        for (int kt = 0; kt < 8; ++kt) azr[kt] = *(const bf16x8*)&aA[kt][lane * 8];
        for (int q = 0; q < 2; ++q){
            int nt = w + 8 * q;
            f32x4 acc = {0.f, 0.f, 0.f, 0.f};
            #pragma unroll
            for (int kt = 0; kt < 8; ++kt){
                bf16x8 bf = *(const bf16x8*)(wout + (kt * 16 + nt) * 512 + lane * 8);
                acc = __builtin_amdgcn_mfma_f32_16x16x32_bf16(azr[kt], bf, acc, 0, 0, 0);
            }
            float bb = b_out[nt * 16 + c];
            #pragma unroll
            for (int r = 0; r < 4; ++r){
                size_t o = (size_t)(b * L_ + l0 + 4 * g + r) * D_ + nt * 16 + c;
                out[o] = x[o] + acc[r] + bb;
            }
        }
    }
}

extern "C" void kernel_launch(void* const* d_in, const int* in_sizes, int n_in,
                              void* d_out, int out_size, void* d_ws, size_t ws_size,
                              hipStream_t stream) {
    const float* x          = (const float*)d_in[0];
    const float* pos_phases = (const float*)d_in[1];
    const float* w_pv       = (const float*)d_in[2];
    const float* b_pv       = (const float*)d_in[3];
    const float* w_key      = (const float*)d_in[4];
    const float* b_key      = (const float*)d_in[5];
    const float* w_kv       = (const float*)d_in[6];
    const float* b_kv       = (const float*)d_in[7];
    const float* w_vg1      = (const float*)d_in[8];
    const float* b_vg1      = (const float*)d_in[9];
    const float* w_vg2      = (const float*)d_in[10];
    const float* b_vg2      = (const float*)d_in[11];
    const float* w_bg1      = (const float*)d_in[12];
    const float* b_bg1      = (const float*)d_in[13];
    const float* w_bg2      = (const float*)d_in[14];
    const float* b_bg2      = (const float*)d_in[15];
    const float* ln_r_g     = (const float*)d_in[16];
    const float* ln_r_b     = (const float*)d_in[17];
    const float* w_r1       = (const float*)d_in[18];
    const float* b_r1       = (const float*)d_in[19];
    const float* w_r2       = (const float*)d_in[20];
    const float* b_r2       = (const float*)d_in[21];
    const float* ln_o_g     = (const float*)d_in[22];
    const float* ln_o_b     = (const float*)d_in[23];
    const float* w_out      = (const float*)d_in[24];
    const float* b_out      = (const float*)d_in[25];
    float* out = (float*)d_out;

    float* ws = (float*)d_ws;
    size_t off = 0;
    float* cpos   = ws + off; off += (size_t)L_ * P_;
    float* spos   = ws + off; off += (size_t)L_ * P_;
    float* pv     = ws + off; off += (size_t)B_ * L_ * D_;
    float* kvv    = ws + off; off += (size_t)B_ * L_ * D_;
    float* ck     = ws + off; off += (size_t)B_ * L_ * P_;
    float* sk     = ws + off; off += (size_t)B_ * L_ * P_;
    float* vg     = ws + off; off += (size_t)B_ * L_;
    float* rnorm  = ws + off; off += (size_t)B_ * L_;
    float* blend0 = ws + off; off += (size_t)B_ * L_;
    float* blend1 = ws + off; off += (size_t)B_ * L_;
    float* posret = ws + off; off += (size_t)B_ * L_ * D_;
    float* kvret  = ws + off; off += (size_t)B_ * L_ * D_;
    float* posSr  = ws + off; off += (size_t)B_ * NC_ * P_ * D_;
    float* posSi  = ws + off; off += (size_t)B_ * NC_ * P_ * D_;
    float* kvSr   = ws + off; off += (size_t)B_ * NC_ * P_ * D_;
    float* kvSi   = ws + off; off += (size_t)B_ * NC_ * P_ * D_;
    unsigned short* wq   = (unsigned short*)(ws + off); off += 630784 / 2;
    unsigned short* xbf  = (unsigned short*)(ws + off); off += 1048576 / 2;
    unsigned short* xsbf = (unsigned short*)(ws + off); off += 1048576 / 2;

    k_prep<<<10912, 256, 0, stream>>>(x, pos_phases,
        w_pv, w_kv, w_vg1, w_bg1, w_r1, w_r2, w_out, w_key,
        wq, xbf, xsbf, cpos, spos);

    k_proj<<<B_ * 128, 512, 0, stream>>>(wq,
        b_pv, b_kv, b_vg1, w_vg2, b_vg2, b_bg1, w_bg2, b_bg2, b_key,
        xbf, xsbf,
        pv, kvv, ck, sk, vg, blend0, blend1);

    k_scan1<<<dim3(NC_, B_, 5), 128, 0, stream>>>(cpos, spos, ck, sk, pv, kvv, vg,
                                                  posSr, posSi, kvSr, kvSi, rnorm);

    k_prefix<<<256, 256, 0, stream>>>(posSr, posSi, kvSr, kvSi);

    k_retrieve<<<dim3(NC_, B_, 4), 128, 0, stream>>>(cpos, spos, ck, sk, pv, kvv,
                                                     vg, rnorm,
                                                     posSr, posSi, kvSr, kvSi,
                                                     posret, kvret);

    k_final<<<B_ * 128, 512, 0, stream>>>(x, posret, kvret, blend0, blend1, wq,
        ln_r_g, ln_r_b, b_r1, b_r2, ln_o_g, ln_o_b, b_out, out);
}

// Round 5
// 94.199 us; speedup vs baseline: 3.2164x; 1.2403x over previous
//
#include <hip/hip_runtime.h>
#include <math.h>

#define B_ 2
#define L_ 2048
#define D_ 256
#define P_ 32
#define NC_ 64
#define CL_ 32

#define INV_SQRT_P 0.17677669529663687f   // 1/sqrt(32)
#define PI_F 3.14159265358979323846f

typedef __attribute__((ext_vector_type(8))) short bf16x8;
typedef __attribute__((ext_vector_type(4))) float f32x4;

__device__ __forceinline__ float gelu_exact(float x){
    return 0.5f * x * (1.0f + erff(x * 0.70710678118654752f));
}

__device__ __forceinline__ unsigned short f2bf(float f){
    unsigned int u = __float_as_uint(f);
    u += 0x7FFFu + ((u >> 16) & 1u);     // round-to-nearest-even
    return (unsigned short)(u >> 16);
}

// ---------------- K_prep: all bf16 repacks + pos sincos, one launch ----------
__global__ __launch_bounds__(256) void k_prep(
    const float* __restrict__ x, const float* __restrict__ pos_phases,
    const float* __restrict__ w_pv, const float* __restrict__ w_kv,
    const float* __restrict__ w_vg1, const float* __restrict__ w_bg1,
    const float* __restrict__ w_r1, const float* __restrict__ w_r2,
    const float* __restrict__ w_out, const float* __restrict__ w_key,
    unsigned short* __restrict__ wq, unsigned short* __restrict__ xbf,
    unsigned short* __restrict__ xsbf,
    float* __restrict__ cpos, float* __restrict__ spos)
{
    int id = blockIdx.x * 256 + threadIdx.x;   // 0..2793471
    if (id < 630784){
        const float* src; int N; int local;
        if (id < 65536)       { src = w_pv;  N = 256; local = id; }
        else if (id < 131072) { src = w_kv;  N = 256; local = id - 65536; }
        else if (id < 262144) { src = w_vg1; N = 256; local = id - 131072; }
        else if (id < 294912) { src = w_bg1; N = 128; local = id - 262144; }
        else if (id < 425984) { src = w_r1;  N = 512; local = id - 294912; }
        else if (id < 557056) { src = w_r2;  N = 256; local = id - 425984; }
        else if (id < 622592) { src = w_out; N = 256; local = id - 557056; }
        else                  { src = w_key; N = 32;  local = id - 622592; }
        int j = local & 7, lane = (local >> 3) & 63, tile = local >> 9;
        int NT = N >> 4;
        int nt = tile % NT, kt = tile / NT;
        int row = kt * 32 + ((lane >> 4) << 3) + j;
        int col = nt * 16 + (lane & 15);
        wq[id] = f2bf(src[(size_t)row * N + col]);
    } else if (id < 2727936){
        int id2 = id - 630784;
        int shifted = id2 >> 20;
        int local = id2 & 1048575;
        int j = local & 7, lane = (local >> 3) & 63;
        int kt = (local >> 9) & 7, lt = (local >> 12) & 127, b = local >> 19;
        int k = kt * 32 + ((lane >> 4) << 3) + j;
        int l = lt * 16 + (lane & 15);
        float v;
        if (shifted) v = (l >= 1) ? x[(size_t)(b * L_ + l - 1) * D_ + k] : 0.0f;
        else         v = x[(size_t)(b * L_ + l) * D_ + k];
        (shifted ? xsbf : xbf)[local] = f2bf(v);
    } else {
        int idx = id - 2727936;                // 0..65535 = L*P
        float s, c;
        sincosf(pos_phases[idx], &s, &c);
        cpos[idx] = c;
        spos[idx] = s;
    }
}

// ---------------- K1: fused projections via MFMA, 16 tokens/block, 8 waves ----
__global__ __launch_bounds__(512) void k_proj(
    const unsigned short* __restrict__ wq,
    const float* __restrict__ b_pv, const float* __restrict__ b_kv,
    const float* __restrict__ b_vg1,
    const float* __restrict__ w_vg2, const float* __restrict__ b_vg2,
    const float* __restrict__ b_bg1,
    const float* __restrict__ w_bg2, const float* __restrict__ b_bg2,
    const float* __restrict__ b_key,
    const unsigned short* __restrict__ xbf, const unsigned short* __restrict__ xsbf,
    float* __restrict__ pv, float* __restrict__ kvv,
    float* __restrict__ ck, float* __restrict__ sk,
    float* __restrict__ vg, float* __restrict__ blend0, float* __restrict__ blend1)
{
    __shared__ float hbuf[16][257];
    __shared__ float bhbuf[16][129];
    __shared__ float kph[16][33];
    __shared__ float red[16][17], red2[16][17], red3[16][17];

    const int i = threadIdx.x;
    const int lane = i & 63, w = i >> 6;
    const int b = blockIdx.x >> 7, lt = blockIdx.x & 127, l0 = lt * 16;
    const int g = lane >> 4, c = lane & 15;

    bf16x8 xa[8], xs[8];
    {
        const unsigned short* base  = xbf  + (size_t)((b * 128 + lt) * 8) * 512 + lane * 8;
        const unsigned short* bases = xsbf + (size_t)((b * 128 + lt) * 8) * 512 + lane * 8;
        #pragma unroll
        for (int kt = 0; kt < 8; ++kt){
            xa[kt] = *(const bf16x8*)(base  + kt * 512);
            xs[kt] = *(const bf16x8*)(bases + kt * 512);
        }
    }

    const unsigned short* wpv  = wq;
    const unsigned short* wkv  = wq + 65536;
    const unsigned short* wvg1 = wq + 131072;
    const unsigned short* wbg1 = wq + 262144;
    const unsigned short* wkey = wq + 622592;

    for (int jb = w; jb < 58; jb += 8){
        f32x4 acc = {0.f, 0.f, 0.f, 0.f};
        if (jb < 2){
            int nt = jb;
            #pragma unroll
            for (int kt = 0; kt < 8; ++kt){
                bf16x8 bf = *(const bf16x8*)(wkey + (kt * 2 + nt) * 512 + lane * 8);
                acc = __builtin_amdgcn_mfma_f32_16x16x32_bf16(xa[kt], bf, acc, 0, 0, 0);
            }
            float bb = b_key[nt * 16 + c];
            #pragma unroll
            for (int r = 0; r < 4; ++r)
                kph[4 * g + r][nt * 16 + c] = acc[r] + bb;
        } else if (jb < 18){
            int nt = jb - 2;
            #pragma unroll
            for (int kt = 0; kt < 8; ++kt){
                bf16x8 bf = *(const bf16x8*)(wpv + (kt * 16 + nt) * 512 + lane * 8);
                acc = __builtin_amdgcn_mfma_f32_16x16x32_bf16(xa[kt], bf, acc, 0, 0, 0);
            }
            float bb = b_pv[nt * 16 + c];
            #pragma unroll
            for (int r = 0; r < 4; ++r)
                pv[(size_t)(b * L_ + l0 + 4 * g + r) * D_ + nt * 16 + c] = acc[r] + bb;
        } else if (jb < 34){
            int nt = jb - 18;
            #pragma unroll
            for (int kt = 0; kt < 8; ++kt){
                bf16x8 bf = *(const bf16x8*)(wkv + (kt * 16 + nt) * 512 + lane * 8);
                acc = __builtin_amdgcn_mfma_f32_16x16x32_bf16(xa[kt], bf, acc, 0, 0, 0);
            }
            float bb = b_kv[nt * 16 + c];
            #pragma unroll
            for (int r = 0; r < 4; ++r)
                kvv[(size_t)(b * L_ + l0 + 4 * g + r) * D_ + nt * 16 + c] = acc[r] + bb;
        } else if (jb < 50){
            int nt = jb - 34;
            #pragma unroll
            for (int kt = 0; kt < 8; ++kt){
                bf16x8 bf = *(const bf16x8*)(wvg1 + (kt * 16 + nt) * 512 + lane * 8);
                acc = __builtin_amdgcn_mfma_f32_16x16x32_bf16(xa[kt], bf, acc, 0, 0, 0);
            }
            #pragma unroll
            for (int kt = 8; kt < 16; ++kt){
                bf16x8 bf = *(const bf16x8*)(wvg1 + (kt * 16 + nt) * 512 + lane * 8);
                acc = __builtin_amdgcn_mfma_f32_16x16x32_bf16(xs[kt - 8], bf, acc, 0, 0, 0);
            }
            float bb = b_vg1[nt * 16 + c];
            #pragma unroll
            for (int r = 0; r < 4; ++r)
                hbuf[4 * g + r][nt * 16 + c] = gelu_exact(acc[r] + bb);
        } else {
            int nt = jb - 50;
            #pragma unroll
            for (int kt = 0; kt < 8; ++kt){
                bf16x8 bf = *(const bf16x8*)(wbg1 + (kt * 8 + nt) * 512 + lane * 8);
                acc = __builtin_amdgcn_mfma_f32_16x16x32_bf16(xa[kt], bf, acc, 0, 0, 0);
            }
            float bb = b_bg1[nt * 16 + c];
            #pragma unroll
            for (int r = 0; r < 4; ++r)
                bhbuf[4 * g + r][nt * 16 + c] = gelu_exact(acc[r] + bb);
        }
    }
    __syncthreads();

    {
        int t = i >> 5, p = i & 31;
        float a = tanhf(kph[t][p]) * PI_F;
        float s, cc;
        sincosf(a, &s, &cc);
        ck[(size_t)(b * L_ + l0 + t) * P_ + p] = cc;
        sk[(size_t)(b * L_ + l0 + t) * P_ + p] = s;
    }

    if (i < 256){
        int t = i >> 4, c2 = i & 15;
        float s = 0.f;
        #pragma unroll
        for (int m = 0; m < 16; ++m){ int dd = c2 + 16 * m; s += hbuf[t][dd] * w_vg2[dd]; }
        red[t][c2] = s;
    } else {
        int ii = i - 256;
        int t = ii >> 4, c2 = ii & 15;
        float s0 = 0.f, s1 = 0.f;
        #pragma unroll
        for (int m = 0; m < 8; ++m){
            int jj = c2 + 16 * m;
            float v = bhbuf[t][jj];
            s0 += v * w_bg2[jj * 2 + 0];
            s1 += v * w_bg2[jj * 2 + 1];
        }
        red2[t][c2] = s0; red3[t][c2] = s1;
    }
    __syncthreads();
    if (i < 16){
        float s = 0.f;
        #pragma unroll
        for (int c2 = 0; c2 < 16; ++c2) s += red[i][c2];
        s += b_vg2[0];
        vg[b * L_ + l0 + i] = 1.0f / (1.0f + expf(-s));
    } else if (i < 32){
        int t = i - 16;
        float s0 = 0.f, s1 = 0.f;
        #pragma unroll
        for (int c2 = 0; c2 < 16; ++c2){ s0 += red2[t][c2]; s1 += red3[t][c2]; }
        s0 += b_bg2[0]; s1 += b_bg2[1];
        float mx = fmaxf(s0, s1);
        float e0 = expf(s0 - mx), e1 = expf(s1 - mx);
        float inv = 1.0f / (e0 + e1);
        blend0[b * L_ + l0 + t] = e0 * inv;
        blend1[b * L_ + l0 + t] = e1 * inv;
    }
}

// ---------------- K_scan1: chunk sums, P split 4-way ----------------
// z in [0,16): type=z>>3 (0=pos,1=kv), pg=(z>>1)&3, dhalf=z&1 ; z==16: gatecum
__global__ __launch_bounds__(128) void k_scan1(
    const float* __restrict__ cpos, const float* __restrict__ spos,
    const float* __restrict__ ck, const float* __restrict__ sk,
    const float* __restrict__ pv, const float* __restrict__ kvv,
    const float* __restrict__ vg,
    float* __restrict__ posSr, float* __restrict__ posSi,
    float* __restrict__ kvSr, float* __restrict__ kvSi,
    float* __restrict__ rnorm)
{
    const int z = blockIdx.z;
    const int c = blockIdx.x, b = blockIdx.y;
    const int i = threadIdx.x;
    if (z == 16){
        if (c != 0) return;
        float loc[16];
        float run = 0.f;
        #pragma unroll
        for (int m = 0; m < 16; ++m){ run += vg[b * L_ + i * 16 + m]; loc[m] = run; }
        __shared__ float part[128];
        part[i] = run;
        __syncthreads();
        for (int off = 1; off < 128; off <<= 1){
            float t = (i >= off) ? part[i - off] : 0.0f;
            __syncthreads();
            part[i] += t;
            __syncthreads();
        }
        float excl = part[i] - run;
        #pragma unroll
        for (int m = 0; m < 16; ++m){
            float gc = fmaxf(excl + loc[m], 1.0f);
            rnorm[b * L_ + i * 16 + m] = rsqrtf(gc) * INV_SQRT_P;
        }
        return;
    }
    const int type = z >> 3, pg = (z >> 1) & 3, dhalf = z & 1;
    const int d = dhalf * 128 + i;
    const int p0 = pg * 8;
    float Sr[8], Si[8];
    #pragma unroll
    for (int j = 0; j < 8; ++j){ Sr[j] = 0.f; Si[j] = 0.f; }

    if (type == 0){
        for (int l = 0; l < CL_; ++l){
            int row = c * CL_ + l;
            float v = pv[(size_t)(b * L_ + row) * D_ + d];
            float4 c0 = *(const float4*)(cpos + row * P_ + p0);
            float4 c1 = *(const float4*)(cpos + row * P_ + p0 + 4);
            float4 s0 = *(const float4*)(spos + row * P_ + p0);
            float4 s1 = *(const float4*)(spos + row * P_ + p0 + 4);
            Sr[0] = fmaf(c0.x, v, Sr[0]); Si[0] = fmaf(s0.x, v, Si[0]);
            Sr[1] = fmaf(c0.y, v, Sr[1]); Si[1] = fmaf(s0.y, v, Si[1]);
            Sr[2] = fmaf(c0.z, v, Sr[2]); Si[2] = fmaf(s0.z, v, Si[2]);
            Sr[3] = fmaf(c0.w, v, Sr[3]); Si[3] = fmaf(s0.w, v, Si[3]);
            Sr[4] = fmaf(c1.x, v, Sr[4]); Si[4] = fmaf(s1.x, v, Si[4]);
            Sr[5] = fmaf(c1.y, v, Sr[5]); Si[5] = fmaf(s1.y, v, Si[5]);
            Sr[6] = fmaf(c1.z, v, Sr[6]); Si[6] = fmaf(s1.z, v, Si[6]);
            Sr[7] = fmaf(c1.w, v, Sr[7]); Si[7] = fmaf(s1.w, v, Si[7]);
        }
        #pragma unroll
        for (int j = 0; j < 8; ++j){
            size_t o = (size_t)((b * NC_ + c) * P_ + p0 + j) * D_ + d;
            posSr[o] = Sr[j]; posSi[o] = Si[j];
        }
    } else {
        // shifted phasors kept in registers (prev = phasor of row-1)
        float pc[8], ps[8];
        int srow = c * CL_ - 1;
        if (srow >= 0){
            float4 c0 = *(const float4*)(ck + ((size_t)b * L_ + srow) * P_ + p0);
            float4 c1 = *(const float4*)(ck + ((size_t)b * L_ + srow) * P_ + p0 + 4);
            float4 s0 = *(const float4*)(sk + ((size_t)b * L_ + srow) * P_ + p0);
            float4 s1 = *(const float4*)(sk + ((size_t)b * L_ + srow) * P_ + p0 + 4);
            pc[0]=c0.x; pc[1]=c0.y; pc[2]=c0.z; pc[3]=c0.w;
            pc[4]=c1.x; pc[5]=c1.y; pc[6]=c1.z; pc[7]=c1.w;
            ps[0]=s0.x; ps[1]=s0.y; ps[2]=s0.z; ps[3]=s0.w;
            ps[4]=s1.x; ps[5]=s1.y; ps[6]=s1.z; ps[7]=s1.w;
        } else {
            #pragma unroll
            for (int j = 0; j < 8; ++j){ pc[j] = 0.f; ps[j] = 0.f; }
        }
        for (int l = 0; l < CL_; ++l){
            int row = c * CL_ + l;
            float vv = kvv[(size_t)(b * L_ + row) * D_ + d] * vg[b * L_ + row];
            float4 c0 = *(const float4*)(ck + ((size_t)b * L_ + row) * P_ + p0);
            float4 c1 = *(const float4*)(ck + ((size_t)b * L_ + row) * P_ + p0 + 4);
            float4 s0 = *(const float4*)(sk + ((size_t)b * L_ + row) * P_ + p0);
            float4 s1 = *(const float4*)(sk + ((size_t)b * L_ + row) * P_ + p0 + 4);
            #pragma unroll
            for (int j = 0; j < 8; ++j){
                Sr[j] = fmaf(pc[j], vv, Sr[j]);
                Si[j] = fmaf(ps[j], vv, Si[j]);
            }
            pc[0]=c0.x; pc[1]=c0.y; pc[2]=c0.z; pc[3]=c0.w;
            pc[4]=c1.x; pc[5]=c1.y; pc[6]=c1.z; pc[7]=c1.w;
            ps[0]=s0.x; ps[1]=s0.y; ps[2]=s0.z; ps[3]=s0.w;
            ps[4]=s1.x; ps[5]=s1.y; ps[6]=s1.z; ps[7]=s1.w;
        }
        #pragma unroll
        for (int j = 0; j < 8; ++j){
            size_t o = (size_t)((b * NC_ + c) * P_ + p0 + j) * D_ + d;
            kvSr[o] = Sr[j]; kvSi[o] = Si[j];
        }
    }
}

// ---------------- K_prefix: in-place exclusive prefix over chunks, 4 arrays ---
__global__ __launch_bounds__(256) void k_prefix(
    float* __restrict__ posSr, float* __restrict__ posSi,
    float* __restrict__ kvSr, float* __restrict__ kvSi)
{
    int gid = blockIdx.x * 256 + threadIdx.x;   // 0..65535
    float* A = (gid < 16384) ? posSr : (gid < 32768) ? posSi
             : (gid < 49152) ? kvSr : kvSi;
    int g = gid & 16383;
    int b = g >> 13;
    int pd = g & 8191;
    float run = 0.f;
    #pragma unroll 4
    for (int cc = 0; cc < NC_; ++cc){
        size_t idx = (size_t)(b * NC_ + cc) * (P_ * D_) + pd;
        float t = A[idx];
        A[idx] = run;
        run += t;
    }
}

// ---------------- K_retrieve: P split 4-way across lanes, shfl reduce --------
// z = type*4 + dquad ; block 256 thr = 4 waves; lane = pg*16 + dl
__global__ __launch_bounds__(256) void k_retrieve(
    const float* __restrict__ cpos, const float* __restrict__ spos,
    const float* __restrict__ ck, const float* __restrict__ sk,
    const float* __restrict__ pv, const float* __restrict__ kvv,
    const float* __restrict__ vg, const float* __restrict__ rnorm,
    const float* __restrict__ posSr, const float* __restrict__ posSi,
    const float* __restrict__ kvSr, const float* __restrict__ kvSi,
    float* __restrict__ posret, float* __restrict__ kvret)
{
    const int z = blockIdx.z;
    const int c = blockIdx.x, b = blockIdx.y;
    const int type = z >> 2, dquad = z & 3;
    const int lane = threadIdx.x & 63, wv = threadIdx.x >> 6;
    const int pg = lane >> 4, dl = lane & 15;
    const int d = dquad * 64 + wv * 16 + dl;
    const int p0 = pg * 8;

    float Sr[8], Si[8];

    if (type == 0){
        #pragma unroll
        for (int j = 0; j < 8; ++j){
            size_t o = (size_t)((b * NC_ + c) * P_ + p0 + j) * D_ + d;
            Sr[j] = posSr[o]; Si[j] = posSi[o];
        }
        for (int l = 0; l < CL_; ++l){
            int row = c * CL_ + l;
            float v = pv[(size_t)(b * L_ + row) * D_ + d];
            float4 c0 = *(const float4*)(cpos + row * P_ + p0);
            float4 c1 = *(const float4*)(cpos + row * P_ + p0 + 4);
            float4 s0 = *(const float4*)(spos + row * P_ + p0);
            float4 s1 = *(const float4*)(spos + row * P_ + p0 + 4);
            float r0 = 0.f, r1 = 0.f, r2 = 0.f, r3 = 0.f;
            Sr[0] = fmaf(c0.x, v, Sr[0]); r0 = fmaf(c0.x, Sr[0], r0);
            Si[0] = fmaf(s0.x, v, Si[0]); r1 = fmaf(s0.x, Si[0], r1);
            Sr[1] = fmaf(c0.y, v, Sr[1]); r2 = fmaf(c0.y, Sr[1], r2);
            Si[1] = fmaf(s0.y, v, Si[1]); r3 = fmaf(s0.y, Si[1], r3);
            Sr[2] = fmaf(c0.z, v, Sr[2]); r0 = fmaf(c0.z, Sr[2], r0);
            Si[2] = fmaf(s0.z, v, Si[2]); r1 = fmaf(s0.z, Si[2], r1);
            Sr[3] = fmaf(c0.w, v, Sr[3]); r2 = fmaf(c0.w, Sr[3], r2);
            Si[3] = fmaf(s0.w, v, Si[3]); r3 = fmaf(s0.w, Si[3], r3);
            Sr[4] = fmaf(c1.x, v, Sr[4]); r0 = fmaf(c1.x, Sr[4], r0);
            Si[4] = fmaf(s1.x, v, Si[4]); r1 = fmaf(s1.x, Si[4], r1);
            Sr[5] = fmaf(c1.y, v, Sr[5]); r2 = fmaf(c1.y, Sr[5], r2);
            Si[5] = fmaf(s1.y, v, Si[5]); r3 = fmaf(s1.y, Si[5], r3);
            Sr[6] = fmaf(c1.z, v, Sr[6]); r0 = fmaf(c1.z, Sr[6], r0);
            Si[6] = fmaf(s1.z, v, Si[6]); r1 = fmaf(s1.z, Si[6], r1);
            Sr[7] = fmaf(c1.w, v, Sr[7]); r2 = fmaf(c1.w, Sr[7], r2);
            Si[7] = fmaf(s1.w, v, Si[7]); r3 = fmaf(s1.w, Si[7], r3);
            float r = (r0 + r1) + (r2 + r3);
            r += __shfl_xor(r, 16, 64);
            r += __shfl_xor(r, 32, 64);
            if (pg == 0)
                posret[(size_t)(b * L_ + row) * D_ + d] = r * INV_SQRT_P;
        }
    } else {
        #pragma unroll
        for (int j = 0; j < 8; ++j){
            size_t o = (size_t)((b * NC_ + c) * P_ + p0 + j) * D_ + d;
            Sr[j] = kvSr[o]; Si[j] = kvSi[o];
        }
        float pc[8], ps[8];
        int srow = c * CL_ - 1;
        if (srow >= 0){
            float4 c0 = *(const float4*)(ck + ((size_t)b * L_ + srow) * P_ + p0);
            float4 c1 = *(const float4*)(ck + ((size_t)b * L_ + srow) * P_ + p0 + 4);
            float4 s0 = *(const float4*)(sk + ((size_t)b * L_ + srow) * P_ + p0);
            float4 s1 = *(const float4*)(sk + ((size_t)b * L_ + srow) * P_ + p0 + 4);
            pc[0]=c0.x; pc[1]=c0.y; pc[2]=c0.z; pc[3]=c0.w;
            pc[4]=c1.x; pc[5]=c1.y; pc[6]=c1.z; pc[7]=c1.w;
            ps[0]=s0.x; ps[1]=s0.y; ps[2]=s0.z; ps[3]=s0.w;
            ps[4]=s1.x; ps[5]=s1.y; ps[6]=s1.z; ps[7]=s1.w;
        } else {
            #pragma unroll
            for (int j = 0; j < 8; ++j){ pc[j] = 0.f; ps[j] = 0.f; }
        }
        for (int l = 0; l < CL_; ++l){
            int row = c * CL_ + l;
            float vv = kvv[(size_t)(b * L_ + row) * D_ + d] * vg[b * L_ + row];
            float rn = rnorm[b * L_ + row];
            float4 c0 = *(const float4*)(ck + ((size_t)b * L_ + row) * P_ + p0);
            float4 c1 = *(const float4*)(ck + ((size_t)b * L_ + row) * P_ + p0 + 4);
            float4 s0 = *(const float4*)(sk + ((size_t)b * L_ + row) * P_ + p0);
            float4 s1 = *(const float4*)(sk + ((size_t)b * L_ + row) * P_ + p0 + 4);
            float qc[8], qs[8];
            qc[0]=c0.x; qc[1]=c0.y; qc[2]=c0.z; qc[3]=c0.w;
            qc[4]=c1.x; qc[5]=c1.y; qc[6]=c1.z; qc[7]=c1.w;
            qs[0]=s0.x; qs[1]=s0.y; qs[2]=s0.z; qs[3]=s0.w;
            qs[4]=s1.x; qs[5]=s1.y; qs[6]=s1.z; qs[7]=s1.w;
            float r0 = 0.f, r1 = 0.f, r2 = 0.f, r3 = 0.f;
            #pragma unroll
            for (int j = 0; j < 8; ++j){
                Sr[j] = fmaf(pc[j], vv, Sr[j]);
                Si[j] = fmaf(ps[j], vv, Si[j]);
                if (j & 1){ r2 = fmaf(qc[j], Sr[j], r2); r3 = fmaf(qs[j], Si[j], r3); }
                else      { r0 = fmaf(qc[j], Sr[j], r0); r1 = fmaf(qs[j], Si[j], r1); }
                pc[j] = qc[j]; ps[j] = qs[j];
            }
            float r = (r0 + r1) + (r2 + r3);
            r += __shfl_xor(r, 16, 64);
            r += __shfl_xor(r, 32, 64);
            if (pg == 0)
                kvret[(size_t)(b * L_ + row) * D_ + d] = r * rn;
        }
    }
}

// ---------------- K9: blend -> LN -> r1 -> r2 -> LN -> out via MFMA ----------
__global__ __launch_bounds__(512) void k_final(
    const float* __restrict__ x,
    const float* __restrict__ posret, const float* __restrict__ kvret,
    const float* __restrict__ blend0, const float* __restrict__ blend1,
    const unsigned short* __restrict__ wq,
    const float* __restrict__ ln_r_g, const float* __restrict__ ln_r_b,
    const float* __restrict__ b_r1, const float* __restrict__ b_r2,
    const float* __restrict__ ln_o_g, const float* __restrict__ ln_o_b,
    const float* __restrict__ b_out,
    float* __restrict__ out)
{
    __shared__ float zbuf[16][257];
    __shared__ __align__(16) unsigned short aA[8][512];
    __shared__ __align__(16) unsigned short aH[16][512];
    __shared__ float red[16][17], red2[16][17];
    __shared__ float mu[16], rs[16];

    const int i = threadIdx.x, lane = i & 63, w = i >> 6;
    const int b = blockIdx.x >> 7, l0 = (blockIdx.x & 127) * 16;
    const int g = lane >> 4, c = lane & 15;
    const unsigned short* wr1  = wq + 294912;
    const unsigned short* wr2  = wq + 425984;
    const unsigned short* wout = wq + 557056;

    {
        int t = i >> 5, c0 = (i & 31) * 8;
        size_t base = (size_t)(b * L_ + l0 + t) * D_ + c0;
        float w0 = blend0[b * L_ + l0 + t], w1 = blend1[b * L_ + l0 + t];
        #pragma unroll
        for (int m = 0; m < 8; ++m)
            zbuf[t][c0 + m] = w0 * posret[base + m] + w1 * kvret[base + m];
    }
    __syncthreads();

    if (i < 256){
        int t = i >> 4, c2 = i & 15;
        float s = 0.f, s2 = 0.f;
        #pragma unroll
        for (int m = 0; m < 16; ++m){ float v = zbuf[t][c2 + 16 * m]; s += v; s2 += v * v; }
        red[t][c2] = s; red2[t][c2] = s2;
    }
    __syncthreads();
    if (i < 16){
        float s = 0.f, s2 = 0.f;
        #pragma unroll
        for (int c2 = 0; c2 < 16; ++c2){ s += red[i][c2]; s2 += red2[i][c2]; }
        float mean = s * (1.0f / 256.0f);
        float var  = s2 * (1.0f / 256.0f) - mean * mean;
        mu[i] = mean; rs[i] = rsqrtf(var + 1e-5f);
    }
    __syncthreads();

    {
        int kt = i >> 6;
        int t2 = lane & 15, kb = kt * 32 + ((lane >> 4) << 3);
        float m_ = mu[t2], r_ = rs[t2];
        bf16x8 v8;
        #pragma unroll
        for (int j = 0; j < 8; ++j){
            int k = kb + j;
            float v = (zbuf[t2][k] - m_) * r_ * ln_r_g[k] + ln_r_b[k];
            v8[j] = (short)f2bf(v);
        }
        *(bf16x8*)&aA[kt][lane * 8] = v8;
    }
    __syncthreads();

    {
        bf16x8 afr[8];
        #pragma unroll
        for (int kt = 0; kt < 8; ++kt) afr[kt] = *(const bf16x8*)&aA[kt][lane * 8];
        for (int q = 0; q < 4; ++q){
            int nt = w + 8 * q;
            f32x4 acc = {0.f, 0.f, 0.f, 0.f};
            #pragma unroll
            for (int kt = 0; kt < 8; ++kt){
                bf16x8 bf = *(const bf16x8*)(wr1 + (kt * 32 + nt) * 512 + lane * 8);
                acc = __builtin_amdgcn_mfma_f32_16x16x32_bf16(afr[kt], bf, acc, 0, 0, 0);
            }
            float bb = b_r1[nt * 16 + c];
            #pragma unroll
            for (int r = 0; r < 4; ++r){
                float hv = gelu_exact(acc[r] + bb);
                int t = 4 * g + r, hcol = nt * 16 + c;
                int kt2 = hcol >> 5, kk = hcol & 31;
                int lane2 = ((kk >> 3) << 4) + t, j2 = kk & 7;
                aH[kt2][lane2 * 8 + j2] = f2bf(hv);
            }
        }
    }
    __syncthreads();

    {
        bf16x8 hfr[16];
        #pragma unroll
        for (int kt = 0; kt < 16; ++kt) hfr[kt] = *(const bf16x8*)&aH[kt][lane * 8];
        for (int q = 0; q < 2; ++q){
            int nt = w + 8 * q;
            f32x4 acc = {0.f, 0.f, 0.f, 0.f};
            #pragma unroll
            for (int kt = 0; kt < 16; ++kt){
                bf16x8 bf = *(const bf16x8*)(wr2 + (kt * 16 + nt) * 512 + lane * 8);
                acc = __builtin_amdgcn_mfma_f32_16x16x32_bf16(hfr[kt], bf, acc, 0, 0, 0);
            }
            float bb = b_r2[nt * 16 + c];
            #pragma unroll
            for (int r = 0; r < 4; ++r)
                zbuf[4 * g + r][nt * 16 + c] = acc[r] + bb;
        }
    }
    __syncthreads();

    if (i < 256){
        int t = i >> 4, c2 = i & 15;
        float s = 0.f, s2 = 0.f;
        #pragma unroll
        for (int m = 0; m < 16; ++m){ float v = zbuf[t][c2 + 16 * m]; s += v; s2 += v * v; }
        red[t][c2] = s; red2[t][c2] = s2;
    }
    __syncthreads();
    if (i < 16){
        float s = 0.f, s2 = 0.f;
        #pragma unroll
        for (int c2 = 0; c2 < 16; ++c2){ s += red[i][c2]; s2 += red2[i][c2]; }
        float mean = s * (1.0f / 256.0f);
        float var  = s2 * (1.0f / 256.0f) - mean * mean;
        mu[i] = mean; rs[i] = rsqrtf(var + 1e-5f);
    }
    __syncthreads();

    {
        int kt = i >> 6;
        int t2 = lane & 15, kb = kt * 32 + ((lane >> 4) << 3);
        float m_ = mu[t2], r_ = rs[t2];
        bf16x8 v8;
        #pragma unroll
        for (int j = 0; j < 8; ++j){
            int k = kb + j;
            float v = (zbuf[t2][k] - m_) * r_ * ln_o_g[k] + ln_o_b[k];
            v8[j] = (short)f2bf(v);
        }
        *(bf16x8*)&aA[kt][lane * 8] = v8;
    }
    __syncthreads();

    {
        bf16x8 azr[8];
        #pragma unroll
        for (int kt = 0; kt < 8; ++kt) azr[kt] = *(const bf16x8*)&aA[kt][lane * 8];
        for (int q = 0; q < 2; ++q){
            int nt = w + 8 * q;
            f32x4 acc = {0.f, 0.f, 0.f, 0.f};
            #pragma unroll
            for (int kt = 0; kt < 8; ++kt){
                bf16x8 bf = *(const bf16x8*)(wout + (kt * 16 + nt) * 512 + lane * 8);
                acc = __builtin_amdgcn_mfma_f32_16x16x32_bf16(azr[kt], bf, acc, 0, 0, 0);
            }
            float bb = b_out[nt * 16 + c];
            #pragma unroll
            for (int r = 0; r < 4; ++r){
                size_t o = (size_t)(b * L_ + l0 + 4 * g + r) * D_ + nt * 16 + c;
                out[o] = x[o] + acc[r] + bb;
            }
        }
    }
}

extern "C" void kernel_launch(void* const* d_in, const int* in_sizes, int n_in,
                              void* d_out, int out_size, void* d_ws, size_t ws_size,
                              hipStream_t stream) {
    const float* x          = (const float*)d_in[0];
    const float* pos_phases = (const float*)d_in[1];
    const float* w_pv       = (const float*)d_in[2];
    const float* b_pv       = (const float*)d_in[3];
    const float* w_key      = (const float*)d_in[4];
    const float* b_key      = (const float*)d_in[5];
    const float* w_kv       = (const float*)d_in[6];
    const float* b_kv       = (const float*)d_in[7];
    const float* w_vg1      = (const float*)d_in[8];
    const float* b_vg1      = (const float*)d_in[9];
    const float* w_vg2      = (const float*)d_in[10];
    const float* b_vg2      = (const float*)d_in[11];
    const float* w_bg1      = (const float*)d_in[12];
    const float* b_bg1      = (const float*)d_in[13];
    const float* w_bg2      = (const float*)d_in[14];
    const float* b_bg2      = (const float*)d_in[15];
    const float* ln_r_g     = (const float*)d_in[16];
    const float* ln_r_b     = (const float*)d_in[17];
    const float* w_r1       = (const float*)d_in[18];
    const float* b_r1       = (const float*)d_in[19];
    const float* w_r2       = (const float*)d_in[20];
    const float* b_r2       = (const float*)d_in[21];
    const float* ln_o_g     = (const float*)d_in[22];
    const float* ln_o_b     = (const float*)d_in[23];
    const float* w_out      = (const float*)d_in[24];
    const float* b_out      = (const float*)d_in[25];
    float* out = (float*)d_out;

    float* ws = (float*)d_ws;
    size_t off = 0;
    float* cpos   = ws + off; off += (size_t)L_ * P_;
    float* spos   = ws + off; off += (size_t)L_ * P_;
    float* pv     = ws + off; off += (size_t)B_ * L_ * D_;
    float* kvv    = ws + off; off += (size_t)B_ * L_ * D_;
    float* ck     = ws + off; off += (size_t)B_ * L_ * P_;
    float* sk     = ws + off; off += (size_t)B_ * L_ * P_;
    float* vg     = ws + off; off += (size_t)B_ * L_;
    float* rnorm  = ws + off; off += (size_t)B_ * L_;
    float* blend0 = ws + off; off += (size_t)B_ * L_;
    float* blend1 = ws + off; off += (size_t)B_ * L_;
    float* posret = ws + off; off += (size_t)B_ * L_ * D_;
    float* kvret  = ws + off; off += (size_t)B_ * L_ * D_;
    float* posSr  = ws + off; off += (size_t)B_ * NC_ * P_ * D_;
    float* posSi  = ws + off; off += (size_t)B_ * NC_ * P_ * D_;
    float* kvSr   = ws + off; off += (size_t)B_ * NC_ * P_ * D_;
    float* kvSi   = ws + off; off += (size_t)B_ * NC_ * P_ * D_;
    unsigned short* wq   = (unsigned short*)(ws + off); off += 630784 / 2;
    unsigned short* xbf  = (unsigned short*)(ws + off); off += 1048576 / 2;
    unsigned short* xsbf = (unsigned short*)(ws + off); off += 1048576 / 2;

    k_prep<<<10912, 256, 0, stream>>>(x, pos_phases,
        w_pv, w_kv, w_vg1, w_bg1, w_r1, w_r2, w_out, w_key,
        wq, xbf, xsbf, cpos, spos);

    k_proj<<<B_ * 128, 512, 0, stream>>>(wq,
        b_pv, b_kv, b_vg1, w_vg2, b_vg2, b_bg1, w_bg2, b_bg2, b_key,
        xbf, xsbf,
        pv, kvv, ck, sk, vg, blend0, blend1);

    k_scan1<<<dim3(NC_, B_, 17), 128, 0, stream>>>(cpos, spos, ck, sk, pv, kvv, vg,
                                                   posSr, posSi, kvSr, kvSi, rnorm);

    k_prefix<<<256, 256, 0, stream>>>(posSr, posSi, kvSr, kvSi);

    k_retrieve<<<dim3(NC_, B_, 8), 256, 0, stream>>>(cpos, spos, ck, sk, pv, kvv,
                                                     vg, rnorm,
                                                     posSr, posSi, kvSr, kvSi,
                                                     posret, kvret);

    k_final<<<B_ * 128, 512, 0, stream>>>(x, posret, kvret, blend0, blend1, wq,
        ln_r_g, ln_r_b, b_r1, b_r2, ln_o_g, ln_o_b, b_out, out);
}

// Round 6
// 89.068 us; speedup vs baseline: 3.4017x; 1.0576x over previous
//
#include <hip/hip_runtime.h>
#include <math.h>

#define B_ 2
#define L_ 2048
#define D_ 256
#define P_ 32
#define NC_ 64
#define CL_ 32

#define INV_SQRT_P 0.17677669529663687f   // 1/sqrt(32)
#define PI_F 3.14159265358979323846f

typedef __attribute__((ext_vector_type(8))) short bf16x8;
typedef __attribute__((ext_vector_type(4))) float f32x4;

__device__ __forceinline__ float gelu_exact(float x){
    return 0.5f * x * (1.0f + erff(x * 0.70710678118654752f));
}

__device__ __forceinline__ unsigned short f2bf(float f){
    unsigned int u = __float_as_uint(f);
    u += 0x7FFFu + ((u >> 16) & 1u);     // round-to-nearest-even
    return (unsigned short)(u >> 16);
}

// ---------------- K_prep: weight bf16 repacks + pos sincos ----------
// wq segments (ushort offsets):
//   wpv 0, wkv 65536, wvg1 131072, wbg1 262144, wr1 294912, wr2 425984,
//   wout 557056, wkey 622592 ; total 630784
// B-frag layout per matrix: ((kt*NT + nt)*64 + lane)*8 + j
//   element = W[kt*32 + 8*(lane>>4) + j][nt*16 + (lane&15)]
__global__ __launch_bounds__(256) void k_prep(
    const float* __restrict__ pos_phases,
    const float* __restrict__ w_pv, const float* __restrict__ w_kv,
    const float* __restrict__ w_vg1, const float* __restrict__ w_bg1,
    const float* __restrict__ w_r1, const float* __restrict__ w_r2,
    const float* __restrict__ w_out, const float* __restrict__ w_key,
    unsigned short* __restrict__ wq,
    float* __restrict__ cpos, float* __restrict__ spos)
{
    int id = blockIdx.x * 256 + threadIdx.x;   // 0..696319
    if (id < 630784){
        const float* src; int N; int local;
        if (id < 65536)       { src = w_pv;  N = 256; local = id; }
        else if (id < 131072) { src = w_kv;  N = 256; local = id - 65536; }
        else if (id < 262144) { src = w_vg1; N = 256; local = id - 131072; }
        else if (id < 294912) { src = w_bg1; N = 128; local = id - 262144; }
        else if (id < 425984) { src = w_r1;  N = 512; local = id - 294912; }
        else if (id < 557056) { src = w_r2;  N = 256; local = id - 425984; }
        else if (id < 622592) { src = w_out; N = 256; local = id - 557056; }
        else                  { src = w_key; N = 32;  local = id - 622592; }
        int j = local & 7, lane = (local >> 3) & 63, tile = local >> 9;
        int NT = N >> 4;
        int nt = tile % NT, kt = tile / NT;
        int row = kt * 32 + ((lane >> 4) << 3) + j;
        int col = nt * 16 + (lane & 15);
        wq[id] = f2bf(src[(size_t)row * N + col]);
    } else {
        int idx = id - 630784;                 // 0..65535 = L*P
        float s, c;
        sincosf(pos_phases[idx], &s, &c);
        cpos[idx] = c;
        spos[idx] = s;
    }
}

// ---------------- K1: fused projections via MFMA, 16 tokens/block, 8 waves ----
// A-frags packed in-kernel from x (float4 loads + cvt)
__global__ __launch_bounds__(512) void k_proj(
    const float* __restrict__ x,
    const unsigned short* __restrict__ wq,
    const float* __restrict__ b_pv, const float* __restrict__ b_kv,
    const float* __restrict__ b_vg1,
    const float* __restrict__ w_vg2, const float* __restrict__ b_vg2,
    const float* __restrict__ b_bg1,
    const float* __restrict__ w_bg2, const float* __restrict__ b_bg2,
    const float* __restrict__ b_key,
    float* __restrict__ pv, float* __restrict__ kvv,
    float* __restrict__ ck, float* __restrict__ sk,
    float* __restrict__ vg, float* __restrict__ blend0, float* __restrict__ blend1)
{
    __shared__ float hbuf[16][257];
    __shared__ float bhbuf[16][129];
    __shared__ float kph[16][33];
    __shared__ float red[16][17], red2[16][17], red3[16][17];

    const int i = threadIdx.x;
    const int lane = i & 63, w = i >> 6;
    const int b = blockIdx.x >> 7, lt = blockIdx.x & 127, l0 = lt * 16;
    const int g = lane >> 4, c = lane & 15;

    // pack A fragments (x and shifted-x) directly from x
    bf16x8 xa[8], xs[8];
    {
        int row  = l0 + (lane & 15);
        int rowp = row - 1;
        const float* xr = x + (size_t)(b * L_ + row) * D_ + ((lane >> 4) << 3);
        #pragma unroll
        for (int kt = 0; kt < 8; ++kt){
            float4 a0 = *(const float4*)(xr + kt * 32);
            float4 a1 = *(const float4*)(xr + kt * 32 + 4);
            bf16x8 v;
            v[0] = (short)f2bf(a0.x); v[1] = (short)f2bf(a0.y);
            v[2] = (short)f2bf(a0.z); v[3] = (short)f2bf(a0.w);
            v[4] = (short)f2bf(a1.x); v[5] = (short)f2bf(a1.y);
            v[6] = (short)f2bf(a1.z); v[7] = (short)f2bf(a1.w);
            xa[kt] = v;
        }
        if (rowp >= 0){
            const float* xp = x + (size_t)(b * L_ + rowp) * D_ + ((lane >> 4) << 3);
            #pragma unroll
            for (int kt = 0; kt < 8; ++kt){
                float4 a0 = *(const float4*)(xp + kt * 32);
                float4 a1 = *(const float4*)(xp + kt * 32 + 4);
                bf16x8 v;
                v[0] = (short)f2bf(a0.x); v[1] = (short)f2bf(a0.y);
                v[2] = (short)f2bf(a0.z); v[3] = (short)f2bf(a0.w);
                v[4] = (short)f2bf(a1.x); v[5] = (short)f2bf(a1.y);
                v[6] = (short)f2bf(a1.z); v[7] = (short)f2bf(a1.w);
                xs[kt] = v;
            }
        } else {
            #pragma unroll
            for (int kt = 0; kt < 8; ++kt){
                bf16x8 v;
                #pragma unroll
                for (int j = 0; j < 8; ++j) v[j] = 0;
                xs[kt] = v;
            }
        }
    }

    const unsigned short* wpv  = wq;
    const unsigned short* wkv  = wq + 65536;
    const unsigned short* wvg1 = wq + 131072;
    const unsigned short* wbg1 = wq + 262144;
    const unsigned short* wkey = wq + 622592;

    for (int jb = w; jb < 58; jb += 8){
        f32x4 acc = {0.f, 0.f, 0.f, 0.f};
        if (jb < 2){
            int nt = jb;
            #pragma unroll
            for (int kt = 0; kt < 8; ++kt){
                bf16x8 bf = *(const bf16x8*)(wkey + (kt * 2 + nt) * 512 + lane * 8);
                acc = __builtin_amdgcn_mfma_f32_16x16x32_bf16(xa[kt], bf, acc, 0, 0, 0);
            }
            float bb = b_key[nt * 16 + c];
            #pragma unroll
            for (int r = 0; r < 4; ++r)
                kph[4 * g + r][nt * 16 + c] = acc[r] + bb;
        } else if (jb < 18){
            int nt = jb - 2;
            #pragma unroll
            for (int kt = 0; kt < 8; ++kt){
                bf16x8 bf = *(const bf16x8*)(wpv + (kt * 16 + nt) * 512 + lane * 8);
                acc = __builtin_amdgcn_mfma_f32_16x16x32_bf16(xa[kt], bf, acc, 0, 0, 0);
            }
            float bb = b_pv[nt * 16 + c];
            #pragma unroll
            for (int r = 0; r < 4; ++r)
                pv[(size_t)(b * L_ + l0 + 4 * g + r) * D_ + nt * 16 + c] = acc[r] + bb;
        } else if (jb < 34){
            int nt = jb - 18;
            #pragma unroll
            for (int kt = 0; kt < 8; ++kt){
                bf16x8 bf = *(const bf16x8*)(wkv + (kt * 16 + nt) * 512 + lane * 8);
                acc = __builtin_amdgcn_mfma_f32_16x16x32_bf16(xa[kt], bf, acc, 0, 0, 0);
            }
            float bb = b_kv[nt * 16 + c];
            #pragma unroll
            for (int r = 0; r < 4; ++r)
                kvv[(size_t)(b * L_ + l0 + 4 * g + r) * D_ + nt * 16 + c] = acc[r] + bb;
        } else if (jb < 50){
            int nt = jb - 34;
            #pragma unroll
            for (int kt = 0; kt < 8; ++kt){
                bf16x8 bf = *(const bf16x8*)(wvg1 + (kt * 16 + nt) * 512 + lane * 8);
                acc = __builtin_amdgcn_mfma_f32_16x16x32_bf16(xa[kt], bf, acc, 0, 0, 0);
            }
            #pragma unroll
            for (int kt = 8; kt < 16; ++kt){
                bf16x8 bf = *(const bf16x8*)(wvg1 + (kt * 16 + nt) * 512 + lane * 8);
                acc = __builtin_amdgcn_mfma_f32_16x16x32_bf16(xs[kt - 8], bf, acc, 0, 0, 0);
            }
            float bb = b_vg1[nt * 16 + c];
            #pragma unroll
            for (int r = 0; r < 4; ++r)
                hbuf[4 * g + r][nt * 16 + c] = gelu_exact(acc[r] + bb);
        } else {
            int nt = jb - 50;
            #pragma unroll
            for (int kt = 0; kt < 8; ++kt){
                bf16x8 bf = *(const bf16x8*)(wbg1 + (kt * 8 + nt) * 512 + lane * 8);
                acc = __builtin_amdgcn_mfma_f32_16x16x32_bf16(xa[kt], bf, acc, 0, 0, 0);
            }
            float bb = b_bg1[nt * 16 + c];
            #pragma unroll
            for (int r = 0; r < 4; ++r)
                bhbuf[4 * g + r][nt * 16 + c] = gelu_exact(acc[r] + bb);
        }
    }
    __syncthreads();

    {
        int t = i >> 5, p = i & 31;
        float a = tanhf(kph[t][p]) * PI_F;
        float s, cc;
        sincosf(a, &s, &cc);
        ck[(size_t)(b * L_ + l0 + t) * P_ + p] = cc;
        sk[(size_t)(b * L_ + l0 + t) * P_ + p] = s;
    }

    if (i < 256){
        int t = i >> 4, c2 = i & 15;
        float s = 0.f;
        #pragma unroll
        for (int m = 0; m < 16; ++m){ int dd = c2 + 16 * m; s += hbuf[t][dd] * w_vg2[dd]; }
        red[t][c2] = s;
    } else {
        int ii = i - 256;
        int t = ii >> 4, c2 = ii & 15;
        float s0 = 0.f, s1 = 0.f;
        #pragma unroll
        for (int m = 0; m < 8; ++m){
            int jj = c2 + 16 * m;
            float v = bhbuf[t][jj];
            s0 += v * w_bg2[jj * 2 + 0];
            s1 += v * w_bg2[jj * 2 + 1];
        }
        red2[t][c2] = s0; red3[t][c2] = s1;
    }
    __syncthreads();
    if (i < 16){
        float s = 0.f;
        #pragma unroll
        for (int c2 = 0; c2 < 16; ++c2) s += red[i][c2];
        s += b_vg2[0];
        vg[b * L_ + l0 + i] = 1.0f / (1.0f + expf(-s));
    } else if (i < 32){
        int t = i - 16;
        float s0 = 0.f, s1 = 0.f;
        #pragma unroll
        for (int c2 = 0; c2 < 16; ++c2){ s0 += red2[t][c2]; s1 += red3[t][c2]; }
        s0 += b_bg2[0]; s1 += b_bg2[1];
        float mx = fmaxf(s0, s1);
        float e0 = expf(s0 - mx), e1 = expf(s1 - mx);
        float inv = 1.0f / (e0 + e1);
        blend0[b * L_ + l0 + t] = e0 * inv;
        blend1[b * L_ + l0 + t] = e1 * inv;
    }
}

// ---------------- K_scan1: chunk sums, 256-thread blocks ----------------
// z in [0,8): type=z>>2 (0=pos,1=kv), pg=z&3 ; z==8: gatecum
__global__ __launch_bounds__(256) void k_scan1(
    const float* __restrict__ cpos, const float* __restrict__ spos,
    const float* __restrict__ ck, const float* __restrict__ sk,
    const float* __restrict__ pv, const float* __restrict__ kvv,
    const float* __restrict__ vg,
    float* __restrict__ posSr, float* __restrict__ posSi,
    float* __restrict__ kvSr, float* __restrict__ kvSi,
    float* __restrict__ rnorm)
{
    const int z = blockIdx.z;
    const int c = blockIdx.x, b = blockIdx.y;
    const int i = threadIdx.x;
    if (z == 8){
        if (c != 0) return;
        float loc[8];
        float run = 0.f;
        #pragma unroll
        for (int m = 0; m < 8; ++m){ run += vg[b * L_ + i * 8 + m]; loc[m] = run; }
        __shared__ float part[256];
        part[i] = run;
        __syncthreads();
        for (int off = 1; off < 256; off <<= 1){
            float t = (i >= off) ? part[i - off] : 0.0f;
            __syncthreads();
            part[i] += t;
            __syncthreads();
        }
        float excl = part[i] - run;
        #pragma unroll
        for (int m = 0; m < 8; ++m){
            float gc = fmaxf(excl + loc[m], 1.0f);
            rnorm[b * L_ + i * 8 + m] = rsqrtf(gc) * INV_SQRT_P;
        }
        return;
    }
    const int type = z >> 2, pg = z & 3;
    const int d = i;
    const int p0 = pg * 8;
    float Sr[8], Si[8];
    #pragma unroll
    for (int j = 0; j < 8; ++j){ Sr[j] = 0.f; Si[j] = 0.f; }

    if (type == 0){
        for (int l = 0; l < CL_; ++l){
            int row = c * CL_ + l;
            float v = pv[(size_t)(b * L_ + row) * D_ + d];
            float4 c0 = *(const float4*)(cpos + row * P_ + p0);
            float4 c1 = *(const float4*)(cpos + row * P_ + p0 + 4);
            float4 s0 = *(const float4*)(spos + row * P_ + p0);
            float4 s1 = *(const float4*)(spos + row * P_ + p0 + 4);
            Sr[0] = fmaf(c0.x, v, Sr[0]); Si[0] = fmaf(s0.x, v, Si[0]);
            Sr[1] = fmaf(c0.y, v, Sr[1]); Si[1] = fmaf(s0.y, v, Si[1]);
            Sr[2] = fmaf(c0.z, v, Sr[2]); Si[2] = fmaf(s0.z, v, Si[2]);
            Sr[3] = fmaf(c0.w, v, Sr[3]); Si[3] = fmaf(s0.w, v, Si[3]);
            Sr[4] = fmaf(c1.x, v, Sr[4]); Si[4] = fmaf(s1.x, v, Si[4]);
            Sr[5] = fmaf(c1.y, v, Sr[5]); Si[5] = fmaf(s1.y, v, Si[5]);
            Sr[6] = fmaf(c1.z, v, Sr[6]); Si[6] = fmaf(s1.z, v, Si[6]);
            Sr[7] = fmaf(c1.w, v, Sr[7]); Si[7] = fmaf(s1.w, v, Si[7]);
        }
        #pragma unroll
        for (int j = 0; j < 8; ++j){
            size_t o = (size_t)((b * NC_ + c) * P_ + p0 + j) * D_ + d;
            posSr[o] = Sr[j]; posSi[o] = Si[j];
        }
    } else {
        float pc[8], ps[8];
        int srow = c * CL_ - 1;
        if (srow >= 0){
            float4 c0 = *(const float4*)(ck + ((size_t)b * L_ + srow) * P_ + p0);
            float4 c1 = *(const float4*)(ck + ((size_t)b * L_ + srow) * P_ + p0 + 4);
            float4 s0 = *(const float4*)(sk + ((size_t)b * L_ + srow) * P_ + p0);
            float4 s1 = *(const float4*)(sk + ((size_t)b * L_ + srow) * P_ + p0 + 4);
            pc[0]=c0.x; pc[1]=c0.y; pc[2]=c0.z; pc[3]=c0.w;
            pc[4]=c1.x; pc[5]=c1.y; pc[6]=c1.z; pc[7]=c1.w;
            ps[0]=s0.x; ps[1]=s0.y; ps[2]=s0.z; ps[3]=s0.w;
            ps[4]=s1.x; ps[5]=s1.y; ps[6]=s1.z; ps[7]=s1.w;
        } else {
            #pragma unroll
            for (int j = 0; j < 8; ++j){ pc[j] = 0.f; ps[j] = 0.f; }
        }
        for (int l = 0; l < CL_; ++l){
            int row = c * CL_ + l;
            float vv = kvv[(size_t)(b * L_ + row) * D_ + d] * vg[b * L_ + row];
            float4 c0 = *(const float4*)(ck + ((size_t)b * L_ + row) * P_ + p0);
            float4 c1 = *(const float4*)(ck + ((size_t)b * L_ + row) * P_ + p0 + 4);
            float4 s0 = *(const float4*)(sk + ((size_t)b * L_ + row) * P_ + p0);
            float4 s1 = *(const float4*)(sk + ((size_t)b * L_ + row) * P_ + p0 + 4);
            #pragma unroll
            for (int j = 0; j < 8; ++j){
                Sr[j] = fmaf(pc[j], vv, Sr[j]);
                Si[j] = fmaf(ps[j], vv, Si[j]);
            }
            pc[0]=c0.x; pc[1]=c0.y; pc[2]=c0.z; pc[3]=c0.w;
            pc[4]=c1.x; pc[5]=c1.y; pc[6]=c1.z; pc[7]=c1.w;
            ps[0]=s0.x; ps[1]=s0.y; ps[2]=s0.z; ps[3]=s0.w;
            ps[4]=s1.x; ps[5]=s1.y; ps[6]=s1.z; ps[7]=s1.w;
        }
        #pragma unroll
        for (int j = 0; j < 8; ++j){
            size_t o = (size_t)((b * NC_ + c) * P_ + p0 + j) * D_ + d;
            kvSr[o] = Sr[j]; kvSi[o] = Si[j];
        }
    }
}

// ---------------- K_prefix: exclusive prefix over chunks, float4 + 4-seg -----
// 256 blocks x 256 threads; thread = (quadcol, seg); 16 chunks per seg.
__global__ __launch_bounds__(256) void k_prefix(
    float* __restrict__ posSr, float* __restrict__ posSi,
    float* __restrict__ kvSr, float* __restrict__ kvSi)
{
    __shared__ float4 tot_s[64][4];
    const int colLocal = threadIdx.x >> 2, seg = threadIdx.x & 3;
    const int col = blockIdx.x * 64 + colLocal;   // 0..16383 quad-columns
    const int a = col >> 12;                       // array id
    const int rem = col & 4095;
    const int b = rem >> 11;                       // batch
    const int pd = (rem & 2047) * 4;
    float* A = (a == 0) ? posSr : (a == 1) ? posSi : (a == 2) ? kvSr : kvSi;
    float* base = A + (size_t)b * NC_ * (P_ * D_) + pd;

    float4 t[16];
    #pragma unroll
    for (int k = 0; k < 16; ++k)
        t[k] = *(const float4*)(base + (size_t)(seg * 16 + k) * (P_ * D_));
    float4 tot = {0.f, 0.f, 0.f, 0.f};
    #pragma unroll
    for (int k = 0; k < 16; ++k){
        tot.x += t[k].x; tot.y += t[k].y; tot.z += t[k].z; tot.w += t[k].w;
    }
    tot_s[colLocal][seg] = tot;
    __syncthreads();
    float4 run = {0.f, 0.f, 0.f, 0.f};
    #pragma unroll
    for (int s = 0; s < 3; ++s){
        if (s < seg){
            float4 v = tot_s[colLocal][s];
            run.x += v.x; run.y += v.y; run.z += v.z; run.w += v.w;
        }
    }
    #pragma unroll
    for (int k = 0; k < 16; ++k){
        float4 cur = t[k];
        *(float4*)(base + (size_t)(seg * 16 + k) * (P_ * D_)) = run;
        run.x += cur.x; run.y += cur.y; run.z += cur.z; run.w += cur.w;
    }
}

// ---------------- K_retrieve: P split 4-way across lanes, shfl reduce --------
__global__ __launch_bounds__(256) void k_retrieve(
    const float* __restrict__ cpos, const float* __restrict__ spos,
    const float* __restrict__ ck, const float* __restrict__ sk,
    const float* __restrict__ pv, const float* __restrict__ kvv,
    const float* __restrict__ vg, const float* __restrict__ rnorm,
    const float* __restrict__ posSr, const float* __restrict__ posSi,
    const float* __restrict__ kvSr, const float* __restrict__ kvSi,
    float* __restrict__ posret, float* __restrict__ kvret)
{
    const int z = blockIdx.z;
    const int c = blockIdx.x, b = blockIdx.y;
    const int type = z >> 2, dquad = z & 3;
    const int lane = threadIdx.x & 63, wv = threadIdx.x >> 6;
    const int pg = lane >> 4, dl = lane & 15;
    const int d = dquad * 64 + wv * 16 + dl;
    const int p0 = pg * 8;

    float Sr[8], Si[8];

    if (type == 0){
        #pragma unroll
        for (int j = 0; j < 8; ++j){
            size_t o = (size_t)((b * NC_ + c) * P_ + p0 + j) * D_ + d;
            Sr[j] = posSr[o]; Si[j] = posSi[o];
        }
        for (int l = 0; l < CL_; ++l){
            int row = c * CL_ + l;
            float v = pv[(size_t)(b * L_ + row) * D_ + d];
            float4 c0 = *(const float4*)(cpos + row * P_ + p0);
            float4 c1 = *(const float4*)(cpos + row * P_ + p0 + 4);
            float4 s0 = *(const float4*)(spos + row * P_ + p0);
            float4 s1 = *(const float4*)(spos + row * P_ + p0 + 4);
            float r0 = 0.f, r1 = 0.f, r2 = 0.f, r3 = 0.f;
            Sr[0] = fmaf(c0.x, v, Sr[0]); r0 = fmaf(c0.x, Sr[0], r0);
            Si[0] = fmaf(s0.x, v, Si[0]); r1 = fmaf(s0.x, Si[0], r1);
            Sr[1] = fmaf(c0.y, v, Sr[1]); r2 = fmaf(c0.y, Sr[1], r2);
            Si[1] = fmaf(s0.y, v, Si[1]); r3 = fmaf(s0.y, Si[1], r3);
            Sr[2] = fmaf(c0.z, v, Sr[2]); r0 = fmaf(c0.z, Sr[2], r0);
            Si[2] = fmaf(s0.z, v, Si[2]); r1 = fmaf(s0.z, Si[2], r1);
            Sr[3] = fmaf(c0.w, v, Sr[3]); r2 = fmaf(c0.w, Sr[3], r2);
            Si[3] = fmaf(s0.w, v, Si[3]); r3 = fmaf(s0.w, Si[3], r3);
            Sr[4] = fmaf(c1.x, v, Sr[4]); r0 = fmaf(c1.x, Sr[4], r0);
            Si[4] = fmaf(s1.x, v, Si[4]); r1 = fmaf(s1.x, Si[4], r1);
            Sr[5] = fmaf(c1.y, v, Sr[5]); r2 = fmaf(c1.y, Sr[5], r2);
            Si[5] = fmaf(s1.y, v, Si[5]); r3 = fmaf(s1.y, Si[5], r3);
            Sr[6] = fmaf(c1.z, v, Sr[6]); r0 = fmaf(c1.z, Sr[6], r0);
            Si[6] = fmaf(s1.z, v, Si[6]); r1 = fmaf(s1.z, Si[6], r1);
            Sr[7] = fmaf(c1.w, v, Sr[7]); r2 = fmaf(c1.w, Sr[7], r2);
            Si[7] = fmaf(s1.w, v, Si[7]); r3 = fmaf(s1.w, Si[7], r3);
            float r = (r0 + r1) + (r2 + r3);
            r += __shfl_xor(r, 16, 64);
            r += __shfl_xor(r, 32, 64);
            if (pg == 0)
                posret[(size_t)(b * L_ + row) * D_ + d] = r * INV_SQRT_P;
        }
    } else {
        #pragma unroll
        for (int j = 0; j < 8; ++j){
            size_t o = (size_t)((b * NC_ + c) * P_ + p0 + j) * D_ + d;
            Sr[j] = kvSr[o]; Si[j] = kvSi[o];
        }
        float pc[8], ps[8];
        int srow = c * CL_ - 1;
        if (srow >= 0){
            float4 c0 = *(const float4*)(ck + ((size_t)b * L_ + srow) * P_ + p0);
            float4 c1 = *(const float4*)(ck + ((size_t)b * L_ + srow) * P_ + p0 + 4);
            float4 s0 = *(const float4*)(sk + ((size_t)b * L_ + srow) * P_ + p0);
            float4 s1 = *(const float4*)(sk + ((size_t)b * L_ + srow) * P_ + p0 + 4);
            pc[0]=c0.x; pc[1]=c0.y; pc[2]=c0.z; pc[3]=c0.w;
            pc[4]=c1.x; pc[5]=c1.y; pc[6]=c1.z; pc[7]=c1.w;
            ps[0]=s0.x; ps[1]=s0.y; ps[2]=s0.z; ps[3]=s0.w;
            ps[4]=s1.x; ps[5]=s1.y; ps[6]=s1.z; ps[7]=s1.w;
        } else {
            #pragma unroll
            for (int j = 0; j < 8; ++j){ pc[j] = 0.f; ps[j] = 0.f; }
        }
        for (int l = 0; l < CL_; ++l){
            int row = c * CL_ + l;
            float vv = kvv[(size_t)(b * L_ + row) * D_ + d] * vg[b * L_ + row];
            float rn = rnorm[b * L_ + row];
            float4 c0 = *(const float4*)(ck + ((size_t)b * L_ + row) * P_ + p0);
            float4 c1 = *(const float4*)(ck + ((size_t)b * L_ + row) * P_ + p0 + 4);
            float4 s0 = *(const float4*)(sk + ((size_t)b * L_ + row) * P_ + p0);
            float4 s1 = *(const float4*)(sk + ((size_t)b * L_ + row) * P_ + p0 + 4);
            float qc[8], qs[8];
            qc[0]=c0.x; qc[1]=c0.y; qc[2]=c0.z; qc[3]=c0.w;
            qc[4]=c1.x; qc[5]=c1.y; qc[6]=c1.z; qc[7]=c1.w;
            qs[0]=s0.x; qs[1]=s0.y; qs[2]=s0.z; qs[3]=s0.w;
            qs[4]=s1.x; qs[5]=s1.y; qs[6]=s1.z; qs[7]=s1.w;
            float r0 = 0.f, r1 = 0.f, r2 = 0.f, r3 = 0.f;
            #pragma unroll
            for (int j = 0; j < 8; ++j){
                Sr[j] = fmaf(pc[j], vv, Sr[j]);
                Si[j] = fmaf(ps[j], vv, Si[j]);
                if (j & 1){ r2 = fmaf(qc[j], Sr[j], r2); r3 = fmaf(qs[j], Si[j], r3); }
                else      { r0 = fmaf(qc[j], Sr[j], r0); r1 = fmaf(qs[j], Si[j], r1); }
                pc[j] = qc[j]; ps[j] = qs[j];
            }
            float r = (r0 + r1) + (r2 + r3);
            r += __shfl_xor(r, 16, 64);
            r += __shfl_xor(r, 32, 64);
            if (pg == 0)
                kvret[(size_t)(b * L_ + row) * D_ + d] = r * rn;
        }
    }
}

// ---------------- K9: blend -> LN -> r1 -> r2 -> LN -> out via MFMA ----------
__global__ __launch_bounds__(512) void k_final(
    const float* __restrict__ x,
    const float* __restrict__ posret, const float* __restrict__ kvret,
    const float* __restrict__ blend0, const float* __restrict__ blend1,
    const unsigned short* __restrict__ wq,
    const float* __restrict__ ln_r_g, const float* __restrict__ ln_r_b,
    const float* __restrict__ b_r1, const float* __restrict__ b_r2,
    const float* __restrict__ ln_o_g, const float* __restrict__ ln_o_b,
    const float* __restrict__ b_out,
    float* __restrict__ out)
{
    __shared__ float zbuf[16][257];
    __shared__ __align__(16) unsigned short aA[8][512];
    __shared__ __align__(16) unsigned short aH[16][512];
    __shared__ float red[16][17], red2[16][17];
    __shared__ float mu[16], rs[16];

    const int i = threadIdx.x, lane = i & 63, w = i >> 6;
    const int b = blockIdx.x >> 7, l0 = (blockIdx.x & 127) * 16;
    const int g = lane >> 4, c = lane & 15;
    const unsigned short* wr1  = wq + 294912;
    const unsigned short* wr2  = wq + 425984;
    const unsigned short* wout = wq + 557056;

    {
        int t = i >> 5, c0 = (i & 31) * 8;
        size_t base = (size_t)(b * L_ + l0 + t) * D_ + c0;
        float w0 = blend0[b * L_ + l0 + t], w1 = blend1[b * L_ + l0 + t];
        #pragma unroll
        for (int m = 0; m < 8; ++m)
            zbuf[t][c0 + m] = w0 * posret[base + m] + w1 * kvret[base + m];
    }
    __syncthreads();

    if (i < 256){
        int t = i >> 4, c2 = i & 15;
        float s = 0.f, s2 = 0.f;
        #pragma unroll
        for (int m = 0; m < 16; ++m){ float v = zbuf[t][c2 + 16 * m]; s += v; s2 += v * v; }
        red[t][c2] = s; red2[t][c2] = s2;
    }
    __syncthreads();
    if (i < 16){
        float s = 0.f, s2 = 0.f;
        #pragma unroll
        for (int c2 = 0; c2 < 16; ++c2){ s += red[i][c2]; s2 += red2[i][c2]; }
        float mean = s * (1.0f / 256.0f);
        float var  = s2 * (1.0f / 256.0f) - mean * mean;
        mu[i] = mean; rs[i] = rsqrtf(var + 1e-5f);
    }
    __syncthreads();

    {
        int kt = i >> 6;
        int t2 = lane & 15, kb = kt * 32 + ((lane >> 4) << 3);
        float m_ = mu[t2], r_ = rs[t2];
        bf16x8 v8;
        #pragma unroll
        for (int j = 0; j < 8; ++j){
            int k = kb + j;
            float v = (zbuf[t2][k] - m_) * r_ * ln_r_g[k] + ln_r_b[k];
            v8[j] = (short)f2bf(v);
        }
        *(bf16x8*)&aA[kt][lane * 8] = v8;
    }
    __syncthreads();

    {
        bf16x8 afr[8];
        #pragma unroll
        for (int kt = 0; kt < 8; ++kt) afr[kt] = *(const bf16x8*)&aA[kt][lane * 8];
        for (int q = 0; q < 4; ++q){
            int nt = w + 8 * q;
            f32x4 acc = {0.f, 0.f, 0.f, 0.f};
            #pragma unroll
            for (int kt = 0; kt < 8; ++kt){
                bf16x8 bf = *(const bf16x8*)(wr1 + (kt * 32 + nt) * 512 + lane * 8);
                acc = __builtin_amdgcn_mfma_f32_16x16x32_bf16(afr[kt], bf, acc, 0, 0, 0);
            }
            float bb = b_r1[nt * 16 + c];
            #pragma unroll
            for (int r = 0; r < 4; ++r){
                float hv = gelu_exact(acc[r] + bb);
                int t = 4 * g + r, hcol = nt * 16 + c;
                int kt2 = hcol >> 5, kk = hcol & 31;
                int lane2 = ((kk >> 3) << 4) + t, j2 = kk & 7;
                aH[kt2][lane2 * 8 + j2] = f2bf(hv);
            }
        }
    }
    __syncthreads();

    {
        bf16x8 hfr[16];
        #pragma unroll
        for (int kt = 0; kt < 16; ++kt) hfr[kt] = *(const bf16x8*)&aH[kt][lane * 8];
        for (int q = 0; q < 2; ++q){
            int nt = w + 8 * q;
            f32x4 acc = {0.f, 0.f, 0.f, 0.f};
            #pragma unroll
            for (int kt = 0; kt < 16; ++kt){
                bf16x8 bf = *(const bf16x8*)(wr2 + (kt * 16 + nt) * 512 + lane * 8);
                acc = __builtin_amdgcn_mfma_f32_16x16x32_bf16(hfr[kt], bf, acc, 0, 0, 0);
            }
            float bb = b_r2[nt * 16 + c];
            #pragma unroll
            for (int r = 0; r < 4; ++r)
                zbuf[4 * g + r][nt * 16 + c] = acc[r] + bb;
        }
    }
    __syncthreads();

    if (i < 256){
        int t = i >> 4, c2 = i & 15;
        float s = 0.f, s2 = 0.f;
        #pragma unroll
        for (int m = 0; m < 16; ++m){ float v = zbuf[t][c2 + 16 * m]; s += v; s2 += v * v; }
        red[t][c2] = s; red2[t][c2] = s2;
    }
    __syncthreads();
    if (i < 16){
        float s = 0.f, s2 = 0.f;
        #pragma unroll
        for (int c2 = 0; c2 < 16; ++c2){ s += red[i][c2]; s2 += red2[i][c2]; }
        float mean = s * (1.0f / 256.0f);
        float var  = s2 * (1.0f / 256.0f) - mean * mean;
        mu[i] = mean; rs[i] = rsqrtf(var + 1e-5f);
    }
    __syncthreads();

    {
        int kt = i >> 6;
        int t2 = lane & 15, kb = kt * 32 + ((lane >> 4) << 3);
        float m_ = mu[t2], r_ = rs[t2];
        bf16x8 v8;
        #pragma unroll
        for (int j = 0; j < 8; ++j){
            int k = kb + j;
            float v = (zbuf[t2][k] - m_) * r_ * ln_o_g[k] + ln_o_b[k];
            v8[j] = (short)f2bf(v);
        }
        *(bf16x8*)&aA[kt][lane * 8] = v8;
    }
    __syncthreads();

    {
        bf16x8 azr[8];
        #pragma unroll
        for (int kt = 0; kt < 8; ++kt) azr[kt] = *(const bf16x8*)&aA[kt][lane * 8];
        for (int q = 0; q < 2; ++q){
            int nt = w + 8 * q;
            f32x4 acc = {0.f, 0.f, 0.f, 0.f};
            #pragma unroll
            for (int kt = 0; kt < 8; ++kt){
                bf16x8 bf = *(const bf16x8*)(wout + (kt * 16 + nt) * 512 + lane * 8);
                acc = __builtin_amdgcn_mfma_f32_16x16x32_bf16(azr[kt], bf, acc, 0, 0, 0);
            }
            float bb = b_out[nt * 16 + c];
            #pragma unroll
            for (int r = 0; r < 4; ++r){
                size_t o = (size_t)(b * L_ + l0 + 4 * g + r) * D_ + nt * 16 + c;
                out[o] = x[o] + acc[r] + bb;
            }
        }
    }
}

extern "C" void kernel_launch(void* const* d_in, const int* in_sizes, int n_in,
                              void* d_out, int out_size, void* d_ws, size_t ws_size,
                              hipStream_t stream) {
    const float* x          = (const float*)d_in[0];
    const float* pos_phases = (const float*)d_in[1];
    const float* w_pv       = (const float*)d_in[2];
    const float* b_pv       = (const float*)d_in[3];
    const float* w_key      = (const float*)d_in[4];
    const float* b_key      = (const float*)d_in[5];
    const float* w_kv       = (const float*)d_in[6];
    const float* b_kv       = (const float*)d_in[7];
    const float* w_vg1      = (const float*)d_in[8];
    const float* b_vg1      = (const float*)d_in[9];
    const float* w_vg2      = (const float*)d_in[10];
    const float* b_vg2      = (const float*)d_in[11];
    const float* w_bg1      = (const float*)d_in[12];
    const float* b_bg1      = (const float*)d_in[13];
    const float* w_bg2      = (const float*)d_in[14];
    const float* b_bg2      = (const float*)d_in[15];
    const float* ln_r_g     = (const float*)d_in[16];
    const float* ln_r_b     = (const float*)d_in[17];
    const float* w_r1       = (const float*)d_in[18];
    const float* b_r1       = (const float*)d_in[19];
    const float* w_r2       = (const float*)d_in[20];
    const float* b_r2       = (const float*)d_in[21];
    const float* ln_o_g     = (const float*)d_in[22];
    const float* ln_o_b     = (const float*)d_in[23];
    const float* w_out      = (const float*)d_in[24];
    const float* b_out      = (const float*)d_in[25];
    float* out = (float*)d_out;

    float* ws = (float*)d_ws;
    size_t off = 0;
    float* cpos   = ws + off; off += (size_t)L_ * P_;
    float* spos   = ws + off; off += (size_t)L_ * P_;
    float* pv     = ws + off; off += (size_t)B_ * L_ * D_;
    float* kvv    = ws + off; off += (size_t)B_ * L_ * D_;
    float* ck     = ws + off; off += (size_t)B_ * L_ * P_;
    float* sk     = ws + off; off += (size_t)B_ * L_ * P_;
    float* vg     = ws + off; off += (size_t)B_ * L_;
    float* rnorm  = ws + off; off += (size_t)B_ * L_;
    float* blend0 = ws + off; off += (size_t)B_ * L_;
    float* blend1 = ws + off; off += (size_t)B_ * L_;
    float* posret = ws + off; off += (size_t)B_ * L_ * D_;
    float* kvret  = ws + off; off += (size_t)B_ * L_ * D_;
    float* posSr  = ws + off; off += (size_t)B_ * NC_ * P_ * D_;
    float* posSi  = ws + off; off += (size_t)B_ * NC_ * P_ * D_;
    float* kvSr   = ws + off; off += (size_t)B_ * NC_ * P_ * D_;
    float* kvSi   = ws + off; off += (size_t)B_ * NC_ * P_ * D_;
    unsigned short* wq = (unsigned short*)(ws + off); off += 630784 / 2;

    k_prep<<<2720, 256, 0, stream>>>(pos_phases,
        w_pv, w_kv, w_vg1, w_bg1, w_r1, w_r2, w_out, w_key,
        wq, cpos, spos);

    k_proj<<<B_ * 128, 512, 0, stream>>>(x, wq,
        b_pv, b_kv, b_vg1, w_vg2, b_vg2, b_bg1, w_bg2, b_bg2, b_key,
        pv, kvv, ck, sk, vg, blend0, blend1);

    k_scan1<<<dim3(NC_, B_, 9), 256, 0, stream>>>(cpos, spos, ck, sk, pv, kvv, vg,
                                                  posSr, posSi, kvSr, kvSi, rnorm);

    k_prefix<<<256, 256, 0, stream>>>(posSr, posSi, kvSr, kvSi);

    k_retrieve<<<dim3(NC_, B_, 8), 256, 0, stream>>>(cpos, spos, ck, sk, pv, kvv,
                                                     vg, rnorm,
                                                     posSr, posSi, kvSr, kvSi,
                                                     posret, kvret);

    k_final<<<B_ * 128, 512, 0, stream>>>(x, posret, kvret, blend0, blend1, wq,
        ln_r_g, ln_r_b, b_r1, b_r2, ln_o_g, ln_o_b, b_out, out);
}